// Round 12
// baseline (242.626 us; speedup 1.0000x reference)
//
#include <hip/hip_runtime.h>

typedef unsigned short u16;
typedef unsigned int   u32;
typedef unsigned char  u8;
typedef unsigned long long u64;

#define B_TOT 512
#define L_SEQ 256
#define D_IN  64
#define HIDN  256
#define TOPK  128
#define CAP   160              // candidate cap per unit
#define NWT   32               // units per batch
#define FLDS  76304            // fused dynamic LDS bytes (XH/XL + STS/STT/SUV; no Y bounce)

typedef float  f32x4  __attribute__((ext_vector_type(4)));
typedef __bf16 bf16x8 __attribute__((ext_vector_type(8)));

// ---------- helpers ----------
__device__ __forceinline__ u16 f2bf(float f){
  u32 u = __float_as_uint(f);
  u32 r = u + 0x7fffu + ((u>>16)&1u);   // RNE
  return (u16)(r>>16);
}
__device__ __forceinline__ u32 sortKey(float f){
  u32 b = __float_as_uint(f);
  return (b & 0x80000000u) ? ~b : (b | 0x80000000u);
}
__device__ __forceinline__ float unKey(u32 u){
  u32 b = (u & 0x80000000u) ? (u & 0x7fffffffu) : ~u;
  return __uint_as_float(b);
}
__device__ __forceinline__ void cvt8(const float* v, u32* hp, u32* lp){
  #pragma unroll
  for (int i=0;i<4;++i){
    float v0 = v[2*i], v1 = v[2*i+1];
    u16 h0 = f2bf(v0); float h0f = __uint_as_float(((u32)h0)<<16); u16 l0 = f2bf(v0 - h0f);
    u16 h1 = f2bf(v1); float h1f = __uint_as_float(((u32)h1)<<16); u16 l1 = f2bf(v1 - h1f);
    hp[i] = (u32)h0 | ((u32)h1<<16);
    lp[i] = (u32)l0 | ((u32)l1<<16);
  }
}

// ---------- K0: fused weight prep (uvc via wave reductions, no serial tails) ----------
__global__ __launch_bounds__(256) void k_wprep(
    const float* __restrict__ Wq, const float* __restrict__ bq,
    const float* __restrict__ Wk, const float* __restrict__ bk,
    const float* __restrict__ xi_w1, const float* __restrict__ phi_w1,
    u16* __restrict__ MtH, u16* __restrict__ MtL, float* __restrict__ uvc,
    u16* __restrict__ xiH, u16* __restrict__ xiL,
    u16* __restrict__ phiH, u16* __restrict__ phiL)
{
  int bid = blockIdx.x, tid = threadIdx.x;
  if (bid < 64){
    __shared__ float wq[HIDN];
    __shared__ float part[256];
    int a = bid;
    wq[tid] = Wq[a*HIDN + tid];
    __syncthreads();
    int bcol = tid & 63, q = tid >> 6;
    float s = 0.f;
    for (int h = q*64; h < q*64 + 64; ++h)
      s = fmaf(wq[h], Wk[bcol*HIDN + h], s);
    part[tid] = s;
    __syncthreads();
    if (tid < 64){
      float mv = part[tid] + part[64+tid] + part[128+tid] + part[192+tid];
      u16 hh = f2bf(mv); float hf = __uint_as_float(((u32)hh)<<16);
      u16 ll = f2bf(mv - hf);
      MtH[tid*64 + a] = hh;          // Mt[c][a] = M[a][c]
      MtL[tid*64 + a] = ll;
    }
    // uvc via per-wave shuffle reductions (4 elems/lane)
    int wv = tid >> 6, ln = tid & 63;
    if (wv == 0){
      float s2 = 0.f;
      #pragma unroll
      for (int i=0;i<4;++i){ int h = ln*4+i; s2 = fmaf(wq[h], bk[h], s2); }
      #pragma unroll
      for (int off=1; off<64; off<<=1) s2 += __shfl_xor(s2, off);
      if (ln == 0) uvc[a] = s2;
    } else if (wv == 1){
      float s2 = 0.f;
      #pragma unroll
      for (int i=0;i<4;++i){ int h = ln*4+i; s2 = fmaf(Wk[a*HIDN + h], bq[h], s2); }
      #pragma unroll
      for (int off=1; off<64; off<<=1) s2 += __shfl_xor(s2, off);
      if (ln == 0) uvc[64 + a] = s2;
    } else if (wv == 2 && a == 0){
      float s2 = 0.f;
      #pragma unroll
      for (int i=0;i<4;++i){ int h = ln*4+i; s2 = fmaf(bq[h], bk[h], s2); }
      #pragma unroll
      for (int off=1; off<64; off<<=1) s2 += __shfl_xor(s2, off);
      if (ln == 0) uvc[128] = s2;
    }
  } else {
    int t = (bid-64)*256 + tid;
    if (t < 256*128){
      int h = t >> 7, d = t & 127;
      float v = xi_w1[d*HIDN + h];
      u16 hh = f2bf(v); float hf = __uint_as_float(((u32)hh)<<16);
      u16 ll = f2bf(v - hf);
      xiH[h*128 + d] = hh; xiL[h*128 + d] = ll;
    } else {
      int t2 = t - 256*128;
      int h = t2 >> 6, d = t2 & 63;
      float v = phi_w1[d*HIDN + h];
      u16 hh = f2bf(v); float hf = __uint_as_float(((u32)hh)<<16);
      u16 ll = f2bf(v - hf);
      phiH[h*64 + d] = hh; phiL[h*64 + d] = ll;
    }
  }
}

// ---------- K-FUSED (1024 threads / 16 waves): split + y-MFMA + scoring + per-unit top-k ----------
// grid 512 (1 batch/block), ~76 KB LDS (no Y bounce; swapped-MFMA y with permuted Mt).
// Round-11 single-class fast path retained. NEW: 6-byte split cand format
// (u32 candK + u16 candI; flat < 65536 so the u64's top idx bytes were always 0)
// cuts the cand HBM stream 25% on write (here) and read (k_merge); emission
// within-lane offset via __popc(m & (1<<i)-1) -- no serial 32-step chain.
__global__ void __launch_bounds__(1024) __attribute__((amdgpu_waves_per_eu(4,4))) k_fused(
    const float* __restrict__ x, const u16* __restrict__ MtH, const u16* __restrict__ MtL,
    const float* __restrict__ uvc,
    u32* __restrict__ candK, u16* __restrict__ candI,
    int* __restrict__ cand_n, u32* __restrict__ uthr)
{
  extern __shared__ __align__(16) u16 smem[];
  u16* XH = smem;                       // [256][72]
  u16* XL = XH + 256*72;                // [256][72]
  float* STS = (float*)(XL + 256*72);   // [256] s_i + c (pad -> -1e38)
  float* STT = STS + 256;               // [256] t_j   (pad -> -1e38)
  float* SUV = STT + 256;               // [129]

  int tid = threadIdx.x;
  int b = blockIdx.x;
  const float* xb = x + (size_t)b*(L_SEQ*D_IN);

  if (tid < 129) SUV[tid] = uvc[tid];

  // ---- Phase A: load + split x into LDS (quarter-row per thread) ----
  int ar = tid >> 2, aq = tid & 3;
  float v[16];
  {
    const float* src = xb + (size_t)ar*D_IN + aq*16;
    #pragma unroll
    for (int i=0;i<4;++i) *(float4*)&v[i*4] = *(const float4*)(src + i*4);
    u32 hpA[4],lpA[4],hpB[4],lpB[4];
    cvt8(&v[0], hpA, lpA); cvt8(&v[8], hpB, lpB);
    u16* dh = XH + ar*72 + aq*16;
    u16* dl = XL + ar*72 + aq*16;
    *(uint4*)(dh)     = make_uint4(hpA[0],hpA[1],hpA[2],hpA[3]);
    *(uint4*)(dh + 8) = make_uint4(hpB[0],hpB[1],hpB[2],hpB[3]);
    *(uint4*)(dl)     = make_uint4(lpA[0],lpA[1],lpA[2],lpA[3]);
    *(uint4*)(dl + 8) = make_uint4(lpB[0],lpB[1],lpB[2],lpB[3]);
  }
  __syncthreads();   // SUV + XH/XL visible

  // ---- s_i, t_j, pad (4-lane group reduction) ----
  {
    float su=0.f, tv=0.f, pa=0.f;
    #pragma unroll
    for (int d=0; d<16; ++d){
      float xa = v[d];
      su = fmaf(xa, SUV[aq*16+d], su);
      tv = fmaf(xa, SUV[64+aq*16+d], tv);
      pa += fabsf(xa);
    }
    su += __shfl_xor(su,1); su += __shfl_xor(su,2);
    tv += __shfl_xor(tv,1); tv += __shfl_xor(tv,2);
    pa += __shfl_xor(pa,1); pa += __shfl_xor(pa,2);
    if (aq == 0){
      bool pad = (pa != 0.f);
      STS[ar] = pad ? (su + SUV[128]) : -1e38f;
      STT[ar] = pad ? tv : -1e38f;
    }
  }
  __syncthreads();   // STS/STT visible

  int w = tid >> 6, lane = tid & 63, lm = lane & 15, quad = lane >> 4;
  int u  = w;               // one row-unit per wave: rows [16u, 16u+16)
  int r0 = u*16;

  // ---- y = x M directly into scoring A-frag layout (swapped MFMA, permuted Mt) ----
  bf16x8 Yh0, Yh1, Yl0, Yl1;
  {
    const u16* xh_ = XH + (r0+lm)*72;
    const u16* xl_ = XL + (r0+lm)*72;
    bf16x8 Xh0 = *(const bf16x8*)(xh_ + quad*8);
    bf16x8 Xh1 = *(const bf16x8*)(xh_ + 32 + quad*8);
    bf16x8 Xl0 = *(const bf16x8*)(xl_ + quad*8);
    bf16x8 Xl1 = *(const bf16x8*)(xl_ + 32 + quad*8);
    u32 yh[8], yl[8];     // packed col-pairs; slot = (ct>>1)*4 + (ct&1)*2 + pr
    #pragma unroll
    for (int ct=0; ct<4; ++ct){
      int srow = 8*(lm>>2) + 4*(ct&1) + (lm&3) + 32*(ct>>1);   // sigma(ct,lm)
      const u16* mth = MtH + srow*64 + quad*8;
      const u16* mtl = MtL + srow*64 + quad*8;
      bf16x8 Mh0 = *(const bf16x8*)(mth);
      bf16x8 Mh1 = *(const bf16x8*)(mth + 32);
      bf16x8 Ml0 = *(const bf16x8*)(mtl);
      bf16x8 Ml1 = *(const bf16x8*)(mtl + 32);
      f32x4 a1 = {0.f,0.f,0.f,0.f}, a2 = {0.f,0.f,0.f,0.f};
      a1 = __builtin_amdgcn_mfma_f32_16x16x32_bf16(Mh0, Xh0, a1, 0,0,0);
      a2 = __builtin_amdgcn_mfma_f32_16x16x32_bf16(Mh1, Xh1, a2, 0,0,0);
      a1 = __builtin_amdgcn_mfma_f32_16x16x32_bf16(Ml0, Xh0, a1, 0,0,0);
      a2 = __builtin_amdgcn_mfma_f32_16x16x32_bf16(Ml1, Xh1, a2, 0,0,0);
      a1 = __builtin_amdgcn_mfma_f32_16x16x32_bf16(Mh0, Xl0, a1, 0,0,0);
      a2 = __builtin_amdgcn_mfma_f32_16x16x32_bf16(Mh1, Xl1, a2, 0,0,0);
      #pragma unroll
      for (int pr=0; pr<2; ++pr){
        float v0 = a1[2*pr]   + a2[2*pr];
        float v1 = a1[2*pr+1] + a2[2*pr+1];
        u16 h0 = f2bf(v0); u16 h1 = f2bf(v1);
        u16 l0 = f2bf(v0 - __uint_as_float(((u32)h0)<<16));
        u16 l1 = f2bf(v1 - __uint_as_float(((u32)h1)<<16));
        int slot = (ct>>1)*4 + (ct&1)*2 + pr;
        yh[slot] = (u32)h0 | ((u32)h1<<16);
        yl[slot] = (u32)l0 | ((u32)l1<<16);
      }
    }
    uint4 t0 = make_uint4(yh[0],yh[1],yh[2],yh[3]);
    uint4 t1 = make_uint4(yh[4],yh[5],yh[6],yh[7]);
    uint4 t2 = make_uint4(yl[0],yl[1],yl[2],yl[3]);
    uint4 t3 = make_uint4(yl[4],yl[5],yl[6],yl[7]);
    Yh0 = *(const bf16x8*)&t0;
    Yh1 = *(const bf16x8*)&t1;
    Yl0 = *(const bf16x8*)&t2;
    Yl1 = *(const bf16x8*)&t3;
  }

  float sr[4];
  #pragma unroll
  for (int r=0;r<4;++r) sr[r] = STS[r0 + quad*4 + r];

  // ---- two column-halves: score 16x128, select, emit (kv[32] per lane) ----
  for (int ch=0; ch<2; ++ch){
    int j0 = ch*128;
    u32 kv[32];
    #pragma unroll
    for (int ct=0; ct<8; ++ct){
      const u16* bh = XH + (j0 + ct*16+lm)*72;
      const u16* bl = XL + (j0 + ct*16+lm)*72;
      bf16x8 Bh0 = *(const bf16x8*)(bh + quad*8);
      bf16x8 Bh1 = *(const bf16x8*)(bh + 32 + quad*8);
      bf16x8 Bl0 = *(const bf16x8*)(bl + quad*8);
      bf16x8 Bl1 = *(const bf16x8*)(bl + 32 + quad*8);
      f32x4 a1 = {0.f,0.f,0.f,0.f}, a2 = {0.f,0.f,0.f,0.f};
      a1 = __builtin_amdgcn_mfma_f32_16x16x32_bf16(Yh0, Bh0, a1, 0,0,0);
      a2 = __builtin_amdgcn_mfma_f32_16x16x32_bf16(Yh1, Bh1, a2, 0,0,0);
      a1 = __builtin_amdgcn_mfma_f32_16x16x32_bf16(Yl0, Bh0, a1, 0,0,0);
      a2 = __builtin_amdgcn_mfma_f32_16x16x32_bf16(Yl1, Bh1, a2, 0,0,0);
      a1 = __builtin_amdgcn_mfma_f32_16x16x32_bf16(Yh0, Bl0, a1, 0,0,0);
      a2 = __builtin_amdgcn_mfma_f32_16x16x32_bf16(Yh1, Bl1, a2, 0,0,0);
      float tc = STT[j0 + ct*16 + lm];
      #pragma unroll
      for (int r=0;r<4;++r)
        kv[ct*4 + r] = sortKey(a1[r] + a2[r] + sr[r] + tc);
    }

    // 16-bit-prefix threshold (top-128 of 2048), early-exit in [TOPK, CAP];
    // two independent popcount accumulators halve the serial SALU chain.
    u32 T = 0;
    int cfin = -1;                 // >=0 iff early-exit fired (count known <= CAP)
    for (int bit=15; bit>=0; --bit){
      u32 th2 = (T | (1u<<bit)) << 16;
      int c0 = 0, c1 = 0;
      #pragma unroll
      for (int i=0;i<32;i+=2){
        c0 += (int)__popcll(__ballot(kv[i]   >= th2));
        c1 += (int)__popcll(__ballot(kv[i+1] >= th2));
      }
      int c = c0 + c1;
      if (c >= TOPK){
        T |= (1u<<bit);
        if (c <= CAP){ cfin = c; break; }
      }
    }
    u32 thr = T << 16;

    int wt = u*2 + ch;
    size_t base = ((size_t)b*NWT + wt)*CAP;
    // hoisted emission row bases: flat = rb[r] + (i>>2)*16
    int rb0 = (r0 + quad*4 + 0)*L_SEQ + j0 + lm;
    int rb1 = rb0 + L_SEQ, rb2 = rb1 + L_SEQ, rb3 = rb2 + L_SEQ;

    if (cfin >= 0){
      // ---- fast path (dominant): everything >= thr fits; single mask + single scan ----
      u32 m = 0;
      #pragma unroll
      for (int i=0;i<32;++i) m |= (kv[i] >= thr ? 1u : 0u) << i;
      int n = __popc(m);
      int p = n;
      #pragma unroll
      for (int off=1; off<64; off<<=1){
        int a = __shfl_up(p, off); if (lane >= off) p += a;
      }
      int pos = p - n;
      if (lane == 0){
        cand_n[b*NWT + wt] = cfin;    // ballot count, wave-uniform, <= CAP
        uthr[b*NWT + wt] = thr;
      }
      #pragma unroll
      for (int i=0;i<32;++i){
        if ((m >> i) & 1u){
          int pp2 = pos + __popc(m & ((1u<<i)-1u));   // within-lane offset, no serial chain
          int flat = ((i&3)==0 ? rb0 : (i&3)==1 ? rb1 : (i&3)==2 ? rb2 : rb3) + (i>>2)*16;
          candK[base + pp2] = kv[i];
          candI[base + pp2] = (u16)flat;
        }
      }
    } else {
      // ---- rare fallback: count at final T may exceed CAP; two-class priority emission ----
      u32 up  = (T < 0xffffu) ? ((T+1u) << 16) : 0xffffffffu;
      u32 m1 = 0, m2 = 0;
      #pragma unroll
      for (int i=0;i<32;++i){
        bool ge = kv[i] >= thr;
        bool c1 = ge && (kv[i] >= up);
        m1 |= (c1 ? 1u : 0u) << i;
        m2 |= ((ge && !c1) ? 1u : 0u) << i;
      }
      int n1 = __popc(m1), n2 = __popc(m2);
      int p1 = n1, p2 = n2;
      #pragma unroll
      for (int off=1; off<64; off<<=1){
        int a = __shfl_up(p1, off); if (lane >= off) p1 += a;
        int c = __shfl_up(p2, off); if (lane >= off) p2 += c;
      }
      int tot1 = __shfl(p1, 63), tot2 = __shfl(p2, 63);
      int pos1 = p1 - n1;
      int pos2 = tot1 + (p2 - n2);
      int total = tot1 + tot2;
      if (lane == 0){
        cand_n[b*NWT + wt] = (total < CAP) ? total : CAP;
        uthr[b*NWT + wt] = thr;
      }
      int o1=0, o2=0;
      #pragma unroll
      for (int i=0;i<32;++i){
        bool c1 = (m1 >> i) & 1u, c2v = (m2 >> i) & 1u;
        if (c1 | c2v){
          int p = c1 ? (pos1 + o1) : (pos2 + o2);
          int flat = ((i&3)==0 ? rb0 : (i&3)==1 ? rb1 : (i&3)==2 ? rb2 : rb3) + (i>>2)*16;
          if (p < CAP){ candK[base + p] = kv[i]; candI[base + p] = (u16)flat; }
        }
        o1 += c1; o2 += c2v;
      }
    }
  }
}

// ---------- FALLBACK K1: split x; st; y via MFMA ----------
__global__ __launch_bounds__(256) void k_pre(
    const float* __restrict__ x, const u16* __restrict__ MtH, const u16* __restrict__ MtL,
    const float* __restrict__ uvc,
    u16* __restrict__ xh, u16* __restrict__ xl,
    u16* __restrict__ yh, u16* __restrict__ yl,
    float* __restrict__ st)
{
  __shared__ __align__(16) u16 sh[64][72];
  __shared__ __align__(16) u16 sl[64][72];
  __shared__ float sUV[132];
  int tid = threadIdx.x;
  int g0 = blockIdx.x * 64;
  int b  = g0 >> 8, l0 = g0 & 255;
  int r = tid >> 2, q = tid & 3;

  if (tid < 129) sUV[tid] = uvc[tid];

  float v[16];
  {
    const float* xr = x + (size_t)(g0 + r)*D_IN + q*16;
    #pragma unroll
    for (int i=0;i<4;++i) *(float4*)&v[i*4] = *(const float4*)(xr + i*4);
  }
  {
    u32 hpA[4],lpA[4],hpB[4],lpB[4];
    cvt8(&v[0], hpA, lpA); cvt8(&v[8], hpB, lpB);
    size_t xo = (size_t)(g0 + r)*D_IN + q*16;
    *(uint4*)(xh + xo)     = make_uint4(hpA[0],hpA[1],hpA[2],hpA[3]);
    *(uint4*)(xh + xo + 8) = make_uint4(hpB[0],hpB[1],hpB[2],hpB[3]);
    *(uint4*)(xl + xo)     = make_uint4(lpA[0],lpA[1],lpA[2],lpA[3]);
    *(uint4*)(xl + xo + 8) = make_uint4(lpB[0],lpB[1],lpB[2],lpB[3]);
    *(uint4*)&sh[r][q*16]   = make_uint4(hpA[0],hpA[1],hpA[2],hpA[3]);
    *(uint4*)&sh[r][q*16+8] = make_uint4(hpB[0],hpB[1],hpB[2],hpB[3]);
    *(uint4*)&sl[r][q*16]   = make_uint4(lpA[0],lpA[1],lpA[2],lpA[3]);
    *(uint4*)&sl[r][q*16+8] = make_uint4(lpB[0],lpB[1],lpB[2],lpB[3]);
  }
  __syncthreads();

  {
    float su=0.f, tv=0.f, pa=0.f;
    #pragma unroll
    for (int d=0; d<16; ++d){
      float xa = v[d];
      su = fmaf(xa, sUV[q*16+d], su);
      tv = fmaf(xa, sUV[64+q*16+d], tv);
      pa += fabsf(xa);
    }
    su += __shfl_xor(su,1); su += __shfl_xor(su,2);
    tv += __shfl_xor(tv,1); tv += __shfl_xor(tv,2);
    pa += __shfl_xor(pa,1); pa += __shfl_xor(pa,2);
    if (q == 0){
      bool pad = (pa != 0.f);
      st[(size_t)b*L_SEQ + l0 + r]          = pad ? (su + sUV[128]) : -1e38f;
      st[(size_t)(B_TOT+b)*L_SEQ + l0 + r]  = pad ? tv : -1e38f;
    }
  }

  int w = tid >> 6, lane = tid & 63, lm = lane & 15, quad = lane >> 4;
  bf16x8 Ah0 = *(const bf16x8*)&sh[w*16+lm][quad*8];
  bf16x8 Ah1 = *(const bf16x8*)&sh[w*16+lm][32 + quad*8];
  bf16x8 Al0 = *(const bf16x8*)&sl[w*16+lm][quad*8];
  bf16x8 Al1 = *(const bf16x8*)&sl[w*16+lm][32 + quad*8];
  #pragma unroll
  for (int ct=0; ct<4; ++ct){
    const u16* mth = MtH + (ct*16+lm)*64 + quad*8;
    const u16* mtl = MtL + (ct*16+lm)*64 + quad*8;
    bf16x8 Bh0 = *(const bf16x8*)(mth);
    bf16x8 Bh1 = *(const bf16x8*)(mth + 32);
    bf16x8 Bl0 = *(const bf16x8*)(mtl);
    bf16x8 Bl1 = *(const bf16x8*)(mtl + 32);
    f32x4 a1 = {0.f,0.f,0.f,0.f}, a2 = {0.f,0.f,0.f,0.f};
    a1 = __builtin_amdgcn_mfma_f32_16x16x32_bf16(Ah0, Bh0, a1, 0,0,0);
    a2 = __builtin_amdgcn_mfma_f32_16x16x32_bf16(Ah1, Bh1, a2, 0,0,0);
    a1 = __builtin_amdgcn_mfma_f32_16x16x32_bf16(Al0, Bh0, a1, 0,0,0);
    a2 = __builtin_amdgcn_mfma_f32_16x16x32_bf16(Al1, Bh1, a2, 0,0,0);
    a1 = __builtin_amdgcn_mfma_f32_16x16x32_bf16(Ah0, Bl0, a1, 0,0,0);
    a2 = __builtin_amdgcn_mfma_f32_16x16x32_bf16(Ah1, Bl1, a2, 0,0,0);
    #pragma unroll
    for (int rg=0; rg<4; ++rg){
      float vy = a1[rg] + a2[rg];
      u16 hh = f2bf(vy); float hf = __uint_as_float(((u32)hh)<<16);
      u16 ll = f2bf(vy - hf);
      sh[w*16 + quad*4 + rg][ct*16 + lm] = hh;
      sl[w*16 + quad*4 + rg][ct*16 + lm] = ll;
    }
  }
  {
    size_t yo = (size_t)(g0 + r)*D_IN + q*16;
    *(uint4*)(yh + yo)     = *(uint4*)&sh[r][q*16];
    *(uint4*)(yh + yo + 8) = *(uint4*)&sh[r][q*16+8];
    *(uint4*)(yl + yo)     = *(uint4*)&sl[r][q*16];
    *(uint4*)(yl + yo + 8) = *(uint4*)&sl[r][q*16+8];
  }
}

// ---------- FALLBACK K2: k_score ----------
__global__ __launch_bounds__(256) void k_score(
    const u16* __restrict__ xh, const u16* __restrict__ xl,
    const u16* __restrict__ yh, const u16* __restrict__ yl,
    const float* __restrict__ st,
    u32* __restrict__ candK, u16* __restrict__ candI,
    int* __restrict__ cand_n, u32* __restrict__ uthr)
{
  int tid = threadIdx.x;
  int lin = blockIdx.x;
  int b    = ((lin >> 6) << 3) | (lin & 7);
  int tile = (lin >> 3) & 7;
  int cb = tile & 1, rb = tile >> 1;
  int r0 = rb*64, j0 = cb*128;
  int w = tid >> 6, lane = tid & 63, lm = lane & 15, quad = lane >> 4;

  size_t rowA = ((size_t)b*L_SEQ + r0 + w*16 + lm)*D_IN;
  bf16x8 A_h0 = *(const bf16x8*)(yh + rowA + quad*8);
  bf16x8 A_h1 = *(const bf16x8*)(yh + rowA + 32 + quad*8);
  bf16x8 A_l0 = *(const bf16x8*)(yl + rowA + quad*8);
  bf16x8 A_l1 = *(const bf16x8*)(yl + rowA + 32 + quad*8);

  float4 s4 = *(const float4*)(st + (size_t)b*L_SEQ + r0 + w*16 + quad*4);
  float sr[4] = {s4.x, s4.y, s4.z, s4.w};
  float tc[8];
  #pragma unroll
  for (int ct=0;ct<8;++ct)
    tc[ct] = st[(size_t)(B_TOT + b)*L_SEQ + j0 + ct*16 + lm];

  u32 kv[32];
  #pragma unroll
  for (int ct=0; ct<8; ++ct){
    size_t rowB = ((size_t)b*L_SEQ + j0 + ct*16 + lm)*D_IN;
    bf16x8 B_h0 = *(const bf16x8*)(xh + rowB + quad*8);
    bf16x8 B_h1 = *(const bf16x8*)(xh + rowB + 32 + quad*8);
    bf16x8 B_l0 = *(const bf16x8*)(xl + rowB + quad*8);
    bf16x8 B_l1 = *(const bf16x8*)(xl + rowB + 32 + quad*8);
    f32x4 a1 = {0.f,0.f,0.f,0.f}, a2 = {0.f,0.f,0.f,0.f};
    a1 = __builtin_amdgcn_mfma_f32_16x16x32_bf16(A_h0, B_h0, a1, 0,0,0);
    a2 = __builtin_amdgcn_mfma_f32_16x16x32_bf16(A_h1, B_h1, a2, 0,0,0);
    a1 = __builtin_amdgcn_mfma_f32_16x16x32_bf16(A_l0, B_h0, a1, 0,0,0);
    a2 = __builtin_amdgcn_mfma_f32_16x16x32_bf16(A_l1, B_h1, a2, 0,0,0);
    a1 = __builtin_amdgcn_mfma_f32_16x16x32_bf16(A_h0, B_l0, a1, 0,0,0);
    a2 = __builtin_amdgcn_mfma_f32_16x16x32_bf16(A_h1, B_l1, a2, 0,0,0);
    #pragma unroll
    for (int r=0;r<4;++r)
      kv[ct*4 + r] = sortKey(a1[r] + a2[r] + sr[r] + tc[ct]);
  }

  u32 T = 0;
  for (int bit=15; bit>=0; --bit){
    u32 th2 = (T | (1u<<bit)) << 16;
    int c = 0;
    #pragma unroll
    for (int i=0;i<32;++i)
      c += (int)__popcll(__ballot(kv[i] >= th2));
    if (c >= TOPK){
      T |= (1u<<bit);
      if (c <= CAP) break;
    }
  }
  u32 thr = T << 16;

  u32 hm = 0;
  #pragma unroll
  for (int i=0;i<32;++i) hm |= (kv[i] >= thr ? 1u : 0u) << i;
  int myc = __popc(hm);
  int pre = myc;
  #pragma unroll
  for (int off=1; off<64; off<<=1){
    int n = __shfl_up(pre, off);
    if (lane >= off) pre += n;
  }
  int total = __shfl(pre, 63);
  int pos = pre - myc;
  int wt = tile*4 + w;
  size_t base = ((size_t)b*NWT + wt)*CAP;
  if (lane == 0){
    cand_n[b*NWT + wt] = (total < CAP) ? total : CAP;
    uthr[b*NWT + wt] = thr;
  }
  while (hm){
    int i = __ffs(hm) - 1; hm &= hm - 1;
    if (pos < CAP){
      int r = i & 3, ct = i >> 2;
      int flat = (r0 + w*16 + quad*4 + r)*L_SEQ + (j0 + ct*16 + lm);
      candK[base + pos] = kv[i];
      candI[base + pos] = (u16)flat;
    }
    ++pos;
  }
}

// ---------- K3: two-stage ballot merge -> exact top-128 + softmax ----------
// LB trick: any candidate threshold <= max(per-unit thr) provably has count >= TOPK.
// Kept as a SEPARATE 256-thread kernel (rounds 7/9: fusing serializes it at low
// occupancy). Reads the 6-byte split cand format (25% less HBM traffic).
__global__ __launch_bounds__(256) void k_merge(
    const u32* __restrict__ candK, const u16* __restrict__ candI,
    const int* __restrict__ cand_n, const u32* __restrict__ uthr,
    int* __restrict__ selidx, float* __restrict__ selw)
{
  const int SL   = NWT/4;           // 8 slots per wave
  const int NSW  = SL*CAP/64;       // 20 keys per lane
  const int WCAP = 192;
  __shared__ u64 wbuf[4][WCAP];
  __shared__ int wcnt[4];
  __shared__ int scnt[NWT];
  __shared__ u32 wT[4];
  __shared__ int cm, eqc;
  __shared__ int eqi[256];
  __shared__ float sv[TOPK]; __shared__ int si[TOPK];
  __shared__ float fred[8];
  int b = blockIdx.x, tid = threadIdx.x;
  int w = tid >> 6, lane = tid & 63;
  if (tid < NWT) scnt[tid] = cand_n[b*NWT + tid];
  if (tid == 0){ cm = 0; eqc = 0; }
  __syncthreads();

  u32 key[NSW]; int idx[NSW];
  size_t bb = (size_t)b*NWT*CAP + (size_t)(w*SL)*CAP;
  #pragma unroll
  for (int s=0;s<NSW;++s){
    int e = lane + 64*s;
    int slot = e / CAP, p = e - slot*CAP;
    bool ok = p < scnt[w*SL + slot];
    key[s] = ok ? candK[bb + e] : 0u;
    idx[s] = ok ? (int)candI[bb + e] : 0x7fffffff;
  }

  // wave lower bound = max over this wave's 8 unit thresholds
  u32 lb = uthr[b*NWT + w*SL + (lane & 7)];
  #pragma unroll
  for (int off=1; off<8; off<<=1){
    u32 o = (u32)__shfl_xor((int)lb, off);
    lb = lb > o ? lb : o;
  }

  u32 T = 0;
  for (int bit=31; bit>=0; --bit){
    u32 c2 = T | (1u<<bit);
    if (c2 <= lb){ T = c2; continue; }   // provable accept, no count
    int c = 0;
    #pragma unroll
    for (int s=0;s<NSW;++s) c += (int)__popcll(__ballot(key[s] >= c2));
    if (c >= TOPK){
      T = c2;
      if (c <= WCAP) break;
    }
  }
  if (lane == 0) wT[w] = T;
  {
    int myc = 0;
    #pragma unroll
    for (int s=0;s<NSW;++s) myc += (key[s] >= T) ? 1 : 0;
    int pre = myc;
    #pragma unroll
    for (int off=1; off<64; off<<=1){
      int n = __shfl_up(pre, off);
      if (lane >= off) pre += n;
    }
    int total = __shfl(pre, 63);
    int pos = pre - myc;
    if (lane == 0) wcnt[w] = (total < WCAP) ? total : WCAP;
    #pragma unroll
    for (int s=0;s<NSW;++s){
      if (key[s] >= T){
        if (pos < WCAP) wbuf[w][pos] = ((u64)key[s] << 32) | (u32)idx[s];
        ++pos;
      }
    }
  }
  __syncthreads();

  if (w == 0){
    const int NS2 = 4*WCAP/64;   // 12
    u32 k2[NS2]; int i2[NS2];
    #pragma unroll
    for (int s=0;s<NS2;++s){
      int e = lane + 64*s;
      int slot = e / WCAP, p = e - slot*WCAP;
      bool ok = p < wcnt[slot];
      u64 v = ok ? wbuf[slot][p] : 0ull;
      k2[s] = (u32)(v >> 32);
      i2[s] = ok ? (int)(u32)v : 0x7fffffff;
    }
    u32 lb2 = wT[0];
    lb2 = lb2 > wT[1] ? lb2 : wT[1];
    lb2 = lb2 > wT[2] ? lb2 : wT[2];
    lb2 = lb2 > wT[3] ? lb2 : wT[3];
    u32 T2 = 0;
    for (int bit=31; bit>=0; --bit){
      u32 c2 = T2 | (1u<<bit);
      if (c2 <= lb2){ T2 = c2; continue; }   // provable accept, exactness preserved
      int c = 0;
      #pragma unroll
      for (int s=0;s<NS2;++s) c += (int)__popcll(__ballot(k2[s] >= c2));
      if (c >= TOPK) T2 = c2;
    }
    int m = 0;
    #pragma unroll
    for (int s=0;s<NS2;++s) m += (int)__popcll(__ballot(k2[s] > T2));
    #pragma unroll
    for (int s=0;s<NS2;++s){
      if (k2[s] > T2){
        int p = atomicAdd(&cm, 1);
        sv[p] = unKey(k2[s]) * 0.0625f; si[p] = i2[s];
      } else if (k2[s] == T2 && i2[s] != 0x7fffffff){
        int q = atomicAdd(&eqc, 1);
        if (q < 256) eqi[q] = i2[s];
      }
    }
    if (lane == 0){
      int need = TOPK - m;
      int n = eqc < 256 ? eqc : 256;
      float tv = unKey(T2) * 0.0625f;
      for (int s2=0; s2<need; ++s2){
        int bi = s2;
        for (int j=s2+1;j<n;++j) if (eqi[j] < eqi[bi]) bi = j;
        int t2 = eqi[s2]; eqi[s2] = eqi[bi]; eqi[bi] = t2;
        sv[m+s2] = tv; si[m+s2] = eqi[s2];
      }
    }
  }
  __syncthreads();

  float v = (tid < TOPK) ? sv[tid] : -3.4e38f;
  float mx = v;
  #pragma unroll
  for (int off=1; off<64; off<<=1) mx = fmaxf(mx, __shfl_xor(mx, off));
  if ((tid&63)==0) fred[tid>>6] = mx;
  __syncthreads();
  mx = fmaxf(fred[0], fred[1]);
  float e = (tid < TOPK) ? expf(v - mx) : 0.f;
  float s = e;
  #pragma unroll
  for (int off=1; off<64; off<<=1) s += __shfl_xor(s, off);
  if ((tid&63)==0) fred[4 + (tid>>6)] = s;
  __syncthreads();
  s = fred[4] + fred[5];
  if (tid < TOPK){
    selw[(size_t)b*TOPK + tid]   = e / s;
    selidx[(size_t)b*TOPK + tid] = si[tid];
  }
}

// ---------- K4: gather + split-bf16 MFMA MLP1 + pooling + rho (512-thread / 8-wave) ----------
__global__ __launch_bounds__(512) void k_mlp(
    const float* __restrict__ x, const int* __restrict__ selidx, const float* __restrict__ selw,
    const u16* __restrict__ xiH, const u16* __restrict__ xiL,
    const u16* __restrict__ phiH, const u16* __restrict__ phiL,
    const float* __restrict__ phi_b1, const float* __restrict__ phi_w2, const float* __restrict__ phi_b2,
    const float* __restrict__ xi_b1,  const float* __restrict__ xi_w2,  const float* __restrict__ xi_b2,
    const float* __restrict__ rho_w1, const float* __restrict__ rho_b1,
    const float* __restrict__ rho_w2, const float* __restrict__ rho_b2,
    float* __restrict__ out)
{
  __shared__ __align__(16) u16 AFh[8][4][64][8];
  __shared__ __align__(16) u16 AFl[8][4][64][8];
  __shared__ int   sidx[TOPK];
  __shared__ float swp[TOPK], swd[TOPK];
  __shared__ float gpL[256], gsL[256];
  __shared__ float pooled[256], t1[256];
  __shared__ float pp[512];
  __shared__ float wsums[2];
  int b = blockIdx.x, tid = threadIdx.x;
  int w = tid >> 6, lane = tid & 63;

  if (tid < TOPK){
    int fl = selidx[(size_t)b*TOPK + tid];
    sidx[tid] = fl;
    float wv = selw[(size_t)b*TOPK + tid];
    bool dg = ((fl>>8) == (fl&255));
    swp[tid] = dg ? 0.f : wv;
    swd[tid] = dg ? wv  : 0.f;
  }
  __syncthreads();

  // wsums via 2 wave reductions (parallel with gather on other waves)
  if (w == 0){
    float a = swp[lane] + swp[64 + lane];
    #pragma unroll
    for (int off=1; off<64; off<<=1) a += __shfl_xor(a, off);
    if (lane == 0) wsums[0] = a;
  } else if (w == 1){
    float a = swd[lane] + swd[64 + lane];
    #pragma unroll
    for (int off=1; off<64; off<<=1) a += __shfl_xor(a, off);
    if (lane == 0) wsums[1] = a;
  }

  // gather: thread = (m, qq); qq selects 32 of the 128 concat dims
  {
    int m = tid >> 2, qq = tid & 3;
    int fl = sidx[m];
    int rc = (qq < 2) ? (fl >> 8) : (fl & 255);
    const float* src = x + ((size_t)b*L_SEQ + rc)*D_IN + (qq & 1)*32;
    int kt = m >> 4, l16 = m & 15;
    #pragma unroll
    for (int g=0; g<4; ++g){
      float v[8];
      *(float4*)&v[0] = *(const float4*)(src + g*8);
      *(float4*)&v[4] = *(const float4*)(src + g*8 + 4);
      u32 hp[4], lp[4];
      cvt8(v, hp, lp);
      *(uint4*)&AFh[kt][qq][l16 + 16*g][0] = make_uint4(hp[0],hp[1],hp[2],hp[3]);
      *(uint4*)&AFl[kt][qq][l16 + 16*g][0] = make_uint4(lp[0],lp[1],lp[2],lp[3]);
    }
  }
  __syncthreads();

  int lm = lane & 15, quad = lane >> 4;

  #pragma unroll
  for (int hi2=0; hi2<2; ++hi2){
    int ht = w + 8*hi2;
    int h  = ht*16 + lm;
    bf16x8 BXh[4], BXl[4], BPh[2], BPl[2];
    #pragma unroll
    for (int c=0;c<4;++c){
      BXh[c] = *(const bf16x8*)(xiH + h*128 + c*32 + quad*8);
      BXl[c] = *(const bf16x8*)(xiL + h*128 + c*32 + quad*8);
    }
    #pragma unroll
    for (int c=0;c<2;++c){
      BPh[c] = *(const bf16x8*)(phiH + h*64 + c*32 + quad*8);
      BPl[c] = *(const bf16x8*)(phiL + h*64 + c*32 + quad*8);
    }
    float bxi = xi_b1[h], bph = phi_b1[h];
    float gp = 0.f, gs = 0.f;
    for (int kt=0; kt<8; ++kt){
      bf16x8 Ah_[4], Al_[4];
      #pragma unroll
      for (int c=0;c<4;++c){
        Ah_[c] = *(const bf16x8*)&AFh[kt][c][lane][0];
        Al_[c] = *(const bf16x8*)&AFl[kt][c][lane][0];
      }
      f32x4 cx = {0.f,0.f,0.f,0.f}, cp = {0.f,0.f,0.f,0.f};
      #pragma unroll
      for (int c=0;c<4;++c){
        cx = __builtin_amdgcn_mfma_f32_16x16x32_bf16(Ah_[c], BXh[c], cx, 0,0,0);
        cx = __builtin_amdgcn_mfma_f32_16x16x32_bf16(Al_[c], BXh[c], cx, 0,0,0);
        cx = __builtin_amdgcn_mfma_f32_16x16x32_bf16(Ah_[c], BXl[c], cx, 0,0,0);
      }
      #pragma unroll
      for (int c=0;c<2;++c){
        cp = __builtin_amdgcn_mfma_f32_16x16x32_bf16(Ah_[c], BPh[c], cp, 0,0,0);
        cp = __builtin_amdgcn_mfma_f32_16x16x32_bf16(Al_[c], BPh[c], cp, 0,0,0);
        cp = __builtin_amdgcn_mfma_f32_16x16x32_bf16(Ah_[c], BPl[c], cp, 0,0,0);
      }
      #pragma unroll
      for (int r=0;r<4;++r){
        int kk = kt*16 + quad*4 + r;
        gp = fmaf(swp[kk], fmaxf(cx[r] + bxi, 0.f), gp);
        gs = fmaf(swd[kk], fmaxf(cp[r] + bph, 0.f), gs);
      }
    }
    gp += __shfl_xor(gp, 16); gp += __shfl_xor(gp, 32);
    gs += __shfl_xor(gs, 16); gs += __shfl_xor(gs, 32);
    if (quad == 0){ gpL[h] = gp; gsL[h] = gs; }
  }
  __syncthreads();

  // pooled: 2-way split over d
  {
    int h = tid & 255, half = tid >> 8;
    float wsp = wsums[0], wss = wsums[1];
    float po = (half == 0) ? (wsp*xi_b2[h] + wss*phi_b2[h]) : 0.f;
    int dd0 = half*128;
    for (int d=dd0; d<dd0+128; ++d){
      po = fmaf(gpL[d], xi_w2[d*HIDN + h], po);
      po = fmaf(gsL[d], phi_w2[d*HIDN + h], po);
    }
    pp[half*256 + h] = po;
  }
  __syncthreads();
  if (tid < 256) pooled[tid] = pp[tid] + pp[256 + tid];
  __syncthreads();
  // t1: 2-way split over d
  {
    int h = tid & 255, half = tid >> 8;
    float a = (half == 0) ? rho_b1[h] : 0.f;
    int dd0 = half*128;
    for (int d=dd0; d<dd0+128; ++d) a = fmaf(pooled[d], rho_w1[d*HIDN + h], a);
    pp[half*256 + h] = a;
  }
  __syncthreads();
  if (tid < 256) t1[tid] = fmaxf(pp[tid] + pp[256 + tid], 0.f);
  __syncthreads();
  // out: 4-way split over d
  {
    int h = tid & 127, part = tid >> 7;
    float o = (part == 0) ? rho_b2[h] : 0.f;
    int dd0 = part*64;
    for (int d=dd0; d<dd0+64; ++d) o = fmaf(t1[d], rho_w2[d*128 + h], o);
    pp[part*128 + h] = o;
  }
  __syncthreads();
  if (tid < 128)
    out[(size_t)b*128 + tid] = pp[tid] + pp[128+tid] + pp[256+tid] + pp[384+tid];
}

// ---------- host ----------
extern "C" void kernel_launch(void* const* d_in, const int* in_sizes, int n_in,
                              void* d_out, int out_size, void* d_ws, size_t ws_size,
                              hipStream_t stream)
{
  (void)in_sizes; (void)n_in; (void)out_size; (void)ws_size;
  const float* x      = (const float*)d_in[0];
  const float* Wq     = (const float*)d_in[1];
  const float* bq     = (const float*)d_in[2];
  const float* Wk     = (const float*)d_in[3];
  const float* bk     = (const float*)d_in[4];
  const float* phi_w1 = (const float*)d_in[5];
  const float* phi_b1 = (const float*)d_in[6];
  const float* phi_w2 = (const float*)d_in[7];
  const float* phi_b2 = (const float*)d_in[8];
  const float* xi_w1  = (const float*)d_in[9];
  const float* xi_b1  = (const float*)d_in[10];
  const float* xi_w2  = (const float*)d_in[11];
  const float* xi_b2  = (const float*)d_in[12];
  const float* rho_w1 = (const float*)d_in[13];
  const float* rho_b1 = (const float*)d_in[14];
  const float* rho_w2 = (const float*)d_in[15];
  const float* rho_b2 = (const float*)d_in[16];
  float* out = (float*)d_out;

  const size_t NX = (size_t)B_TOT*L_SEQ*D_IN;      // 8,388,608
  const size_t NC = (size_t)B_TOT*NWT*CAP;         // 2,621,440 cand slots
  float* uvc    = (float*)d_ws;                    // 256
  float* st     = uvc + 256;                       // 2*512*256
  float* selw   = st + (size_t)2*B_TOT*L_SEQ;      // 512*128
  int*   selidx = (int*)(selw + (size_t)B_TOT*TOPK);
  int*   cand_n = selidx + (size_t)B_TOT*TOPK;     // 512*32
  u32*   uthr   = (u32*)(cand_n + (size_t)B_TOT*NWT); // 512*32
  u32*   candK  = uthr + (size_t)B_TOT*NWT;        // NC u32
  u16*   candI  = (u16*)(candK + NC);              // NC u16 (16B-aligned: NC*4 % 16 == 0)
  u16*   MtH    = candI + NC;                      // (NC*2 % 16 == 0)
  u16*   MtL    = MtH + 64*64;
  u16*   xiH    = MtL + 64*64;
  u16*   xiL    = xiH + 256*128;
  u16*   phiH   = xiL + 256*128;
  u16*   phiL   = phiH + 256*64;
  u16*   xh     = phiL + 256*64;
  u16*   xl     = xh + NX;
  u16*   yh     = xl + NX;
  u16*   yl     = yh + NX;

  // deterministic per-device check (same result every call -> graph-safe)
  hipError_t aerr = hipFuncSetAttribute((const void*)k_fused,
                      hipFuncAttributeMaxDynamicSharedMemorySize, FLDS);

  k_wprep<<<dim3(256),  dim3(256), 0, stream>>>(Wq, bq, Wk, bk, xi_w1, phi_w1,
                                                MtH, MtL, uvc, xiH, xiL, phiH, phiL);
  if (aerr == hipSuccess){
    k_fused<<<dim3(B_TOT), dim3(1024), FLDS, stream>>>(x, MtH, MtL, uvc,
                                                       candK, candI, cand_n, uthr);
  } else {
    k_pre  <<<dim3(2048), dim3(256), 0, stream>>>(x, MtH, MtL, uvc, xh, xl, yh, yl, st);
    k_score<<<dim3(4096), dim3(256), 0, stream>>>(xh, xl, yh, yl, st,
                                                  candK, candI, cand_n, uthr);
  }
  k_merge<<<dim3(B_TOT), dim3(256), 0, stream>>>(candK, candI, cand_n, uthr, selidx, selw);
  k_mlp  <<<dim3(B_TOT), dim3(512), 0, stream>>>(x, selidx, selw,
            xiH, xiL, phiH, phiL,
            phi_b1, phi_w2, phi_b2,
            xi_b1, xi_w2, xi_b2,
            rho_w1, rho_b1, rho_w2, rho_b2, out);
}

// Round 13
// 235.306 us; speedup vs baseline: 1.0311x; 1.0311x over previous
//
#include <hip/hip_runtime.h>

typedef unsigned short u16;
typedef unsigned int   u32;
typedef unsigned char  u8;
typedef unsigned long long u64;

#define B_TOT 512
#define L_SEQ 256
#define D_IN  64
#define HIDN  256
#define TOPK  128
#define CAP   160              // candidate cap per unit
#define NWT   32               // units per batch
#define FLDS  76304            // fused dynamic LDS bytes (XH/XL + STS/STT/SUV; no Y bounce)

typedef float  f32x4  __attribute__((ext_vector_type(4)));
typedef __bf16 bf16x8 __attribute__((ext_vector_type(8)));

// ---------- helpers ----------
__device__ __forceinline__ u16 f2bf(float f){
  u32 u = __float_as_uint(f);
  u32 r = u + 0x7fffu + ((u>>16)&1u);   // RNE
  return (u16)(r>>16);
}
__device__ __forceinline__ u32 sortKey(float f){
  u32 b = __float_as_uint(f);
  return (b & 0x80000000u) ? ~b : (b | 0x80000000u);
}
__device__ __forceinline__ float unKey(u32 u){
  u32 b = (u & 0x80000000u) ? (u & 0x7fffffffu) : ~u;
  return __uint_as_float(b);
}
__device__ __forceinline__ void cvt8(const float* v, u32* hp, u32* lp){
  #pragma unroll
  for (int i=0;i<4;++i){
    float v0 = v[2*i], v1 = v[2*i+1];
    u16 h0 = f2bf(v0); float h0f = __uint_as_float(((u32)h0)<<16); u16 l0 = f2bf(v0 - h0f);
    u16 h1 = f2bf(v1); float h1f = __uint_as_float(((u32)h1)<<16); u16 l1 = f2bf(v1 - h1f);
    hp[i] = (u32)h0 | ((u32)h1<<16);
    lp[i] = (u32)l0 | ((u32)l1<<16);
  }
}

// ---------- K0: fused weight prep (uvc via wave reductions, no serial tails) ----------
__global__ __launch_bounds__(256) void k_wprep(
    const float* __restrict__ Wq, const float* __restrict__ bq,
    const float* __restrict__ Wk, const float* __restrict__ bk,
    const float* __restrict__ xi_w1, const float* __restrict__ phi_w1,
    u16* __restrict__ MtH, u16* __restrict__ MtL, float* __restrict__ uvc,
    u16* __restrict__ xiH, u16* __restrict__ xiL,
    u16* __restrict__ phiH, u16* __restrict__ phiL)
{
  int bid = blockIdx.x, tid = threadIdx.x;
  if (bid < 64){
    __shared__ float wq[HIDN];
    __shared__ float part[256];
    int a = bid;
    wq[tid] = Wq[a*HIDN + tid];
    __syncthreads();
    int bcol = tid & 63, q = tid >> 6;
    float s = 0.f;
    for (int h = q*64; h < q*64 + 64; ++h)
      s = fmaf(wq[h], Wk[bcol*HIDN + h], s);
    part[tid] = s;
    __syncthreads();
    if (tid < 64){
      float mv = part[tid] + part[64+tid] + part[128+tid] + part[192+tid];
      u16 hh = f2bf(mv); float hf = __uint_as_float(((u32)hh)<<16);
      u16 ll = f2bf(mv - hf);
      MtH[tid*64 + a] = hh;          // Mt[c][a] = M[a][c]
      MtL[tid*64 + a] = ll;
    }
    // uvc via per-wave shuffle reductions (4 elems/lane)
    int wv = tid >> 6, ln = tid & 63;
    if (wv == 0){
      float s2 = 0.f;
      #pragma unroll
      for (int i=0;i<4;++i){ int h = ln*4+i; s2 = fmaf(wq[h], bk[h], s2); }
      #pragma unroll
      for (int off=1; off<64; off<<=1) s2 += __shfl_xor(s2, off);
      if (ln == 0) uvc[a] = s2;
    } else if (wv == 1){
      float s2 = 0.f;
      #pragma unroll
      for (int i=0;i<4;++i){ int h = ln*4+i; s2 = fmaf(Wk[a*HIDN + h], bq[h], s2); }
      #pragma unroll
      for (int off=1; off<64; off<<=1) s2 += __shfl_xor(s2, off);
      if (ln == 0) uvc[64 + a] = s2;
    } else if (wv == 2 && a == 0){
      float s2 = 0.f;
      #pragma unroll
      for (int i=0;i<4;++i){ int h = ln*4+i; s2 = fmaf(bq[h], bk[h], s2); }
      #pragma unroll
      for (int off=1; off<64; off<<=1) s2 += __shfl_xor(s2, off);
      if (ln == 0) uvc[128] = s2;
    }
  } else {
    int t = (bid-64)*256 + tid;
    if (t < 256*128){
      int h = t >> 7, d = t & 127;
      float v = xi_w1[d*HIDN + h];
      u16 hh = f2bf(v); float hf = __uint_as_float(((u32)hh)<<16);
      u16 ll = f2bf(v - hf);
      xiH[h*128 + d] = hh; xiL[h*128 + d] = ll;
    } else {
      int t2 = t - 256*128;
      int h = t2 >> 6, d = t2 & 63;
      float v = phi_w1[d*HIDN + h];
      u16 hh = f2bf(v); float hf = __uint_as_float(((u32)hh)<<16);
      u16 ll = f2bf(v - hf);
      phiH[h*64 + d] = hh; phiL[h*64 + d] = ll;
    }
  }
}

// ---------- K-FUSED (1024 threads / 16 waves): split + y-MFMA + scoring + per-unit top-k ----------
// grid 512 (1 batch/block), ~76 KB LDS (no Y bounce; swapped-MFMA y with permuted Mt).
// ROUND-11 structure restored (best: 234.2 us). Round-12's split u32+u16 cand format
// REGRESSED (+2.8 MB WRITE, +2.1 MB FETCH): two scattered store streams with partial-
// line u16 stores beat the byte-count savings -- u64 single-stream restored. Kept from
// round 12: emission within-lane offset via __popc(m & (1<<i)-1) (pure ILP, no format
// dependence). VGPR hard-pinned at 64 for 1024-thread blocks (rounds 6/8/10).
__global__ void __launch_bounds__(1024) __attribute__((amdgpu_waves_per_eu(4,4))) k_fused(
    const float* __restrict__ x, const u16* __restrict__ MtH, const u16* __restrict__ MtL,
    const float* __restrict__ uvc,
    u64* __restrict__ cand, int* __restrict__ cand_n, u32* __restrict__ uthr)
{
  extern __shared__ __align__(16) u16 smem[];
  u16* XH = smem;                       // [256][72]
  u16* XL = XH + 256*72;                // [256][72]
  float* STS = (float*)(XL + 256*72);   // [256] s_i + c (pad -> -1e38)
  float* STT = STS + 256;               // [256] t_j   (pad -> -1e38)
  float* SUV = STT + 256;               // [129]

  int tid = threadIdx.x;
  int b = blockIdx.x;
  const float* xb = x + (size_t)b*(L_SEQ*D_IN);

  if (tid < 129) SUV[tid] = uvc[tid];

  // ---- Phase A: load + split x into LDS (quarter-row per thread) ----
  int ar = tid >> 2, aq = tid & 3;
  float v[16];
  {
    const float* src = xb + (size_t)ar*D_IN + aq*16;
    #pragma unroll
    for (int i=0;i<4;++i) *(float4*)&v[i*4] = *(const float4*)(src + i*4);
    u32 hpA[4],lpA[4],hpB[4],lpB[4];
    cvt8(&v[0], hpA, lpA); cvt8(&v[8], hpB, lpB);
    u16* dh = XH + ar*72 + aq*16;
    u16* dl = XL + ar*72 + aq*16;
    *(uint4*)(dh)     = make_uint4(hpA[0],hpA[1],hpA[2],hpA[3]);
    *(uint4*)(dh + 8) = make_uint4(hpB[0],hpB[1],hpB[2],hpB[3]);
    *(uint4*)(dl)     = make_uint4(lpA[0],lpA[1],lpA[2],lpA[3]);
    *(uint4*)(dl + 8) = make_uint4(lpB[0],lpB[1],lpB[2],lpB[3]);
  }
  __syncthreads();   // SUV + XH/XL visible

  // ---- s_i, t_j, pad (4-lane group reduction) ----
  {
    float su=0.f, tv=0.f, pa=0.f;
    #pragma unroll
    for (int d=0; d<16; ++d){
      float xa = v[d];
      su = fmaf(xa, SUV[aq*16+d], su);
      tv = fmaf(xa, SUV[64+aq*16+d], tv);
      pa += fabsf(xa);
    }
    su += __shfl_xor(su,1); su += __shfl_xor(su,2);
    tv += __shfl_xor(tv,1); tv += __shfl_xor(tv,2);
    pa += __shfl_xor(pa,1); pa += __shfl_xor(pa,2);
    if (aq == 0){
      bool pad = (pa != 0.f);
      STS[ar] = pad ? (su + SUV[128]) : -1e38f;
      STT[ar] = pad ? tv : -1e38f;
    }
  }
  __syncthreads();   // STS/STT visible

  int w = tid >> 6, lane = tid & 63, lm = lane & 15, quad = lane >> 4;
  int u  = w;               // one row-unit per wave: rows [16u, 16u+16)
  int r0 = u*16;

  // ---- y = x M directly into scoring A-frag layout (swapped MFMA, permuted Mt) ----
  bf16x8 Yh0, Yh1, Yl0, Yl1;
  {
    const u16* xh_ = XH + (r0+lm)*72;
    const u16* xl_ = XL + (r0+lm)*72;
    bf16x8 Xh0 = *(const bf16x8*)(xh_ + quad*8);
    bf16x8 Xh1 = *(const bf16x8*)(xh_ + 32 + quad*8);
    bf16x8 Xl0 = *(const bf16x8*)(xl_ + quad*8);
    bf16x8 Xl1 = *(const bf16x8*)(xl_ + 32 + quad*8);
    u32 yh[8], yl[8];     // packed col-pairs; slot = (ct>>1)*4 + (ct&1)*2 + pr
    #pragma unroll
    for (int ct=0; ct<4; ++ct){
      int srow = 8*(lm>>2) + 4*(ct&1) + (lm&3) + 32*(ct>>1);   // sigma(ct,lm)
      const u16* mth = MtH + srow*64 + quad*8;
      const u16* mtl = MtL + srow*64 + quad*8;
      bf16x8 Mh0 = *(const bf16x8*)(mth);
      bf16x8 Mh1 = *(const bf16x8*)(mth + 32);
      bf16x8 Ml0 = *(const bf16x8*)(mtl);
      bf16x8 Ml1 = *(const bf16x8*)(mtl + 32);
      f32x4 a1 = {0.f,0.f,0.f,0.f}, a2 = {0.f,0.f,0.f,0.f};
      a1 = __builtin_amdgcn_mfma_f32_16x16x32_bf16(Mh0, Xh0, a1, 0,0,0);
      a2 = __builtin_amdgcn_mfma_f32_16x16x32_bf16(Mh1, Xh1, a2, 0,0,0);
      a1 = __builtin_amdgcn_mfma_f32_16x16x32_bf16(Ml0, Xh0, a1, 0,0,0);
      a2 = __builtin_amdgcn_mfma_f32_16x16x32_bf16(Ml1, Xh1, a2, 0,0,0);
      a1 = __builtin_amdgcn_mfma_f32_16x16x32_bf16(Mh0, Xl0, a1, 0,0,0);
      a2 = __builtin_amdgcn_mfma_f32_16x16x32_bf16(Mh1, Xl1, a2, 0,0,0);
      #pragma unroll
      for (int pr=0; pr<2; ++pr){
        float v0 = a1[2*pr]   + a2[2*pr];
        float v1 = a1[2*pr+1] + a2[2*pr+1];
        u16 h0 = f2bf(v0); u16 h1 = f2bf(v1);
        u16 l0 = f2bf(v0 - __uint_as_float(((u32)h0)<<16));
        u16 l1 = f2bf(v1 - __uint_as_float(((u32)h1)<<16));
        int slot = (ct>>1)*4 + (ct&1)*2 + pr;
        yh[slot] = (u32)h0 | ((u32)h1<<16);
        yl[slot] = (u32)l0 | ((u32)l1<<16);
      }
    }
    uint4 t0 = make_uint4(yh[0],yh[1],yh[2],yh[3]);
    uint4 t1 = make_uint4(yh[4],yh[5],yh[6],yh[7]);
    uint4 t2 = make_uint4(yl[0],yl[1],yl[2],yl[3]);
    uint4 t3 = make_uint4(yl[4],yl[5],yl[6],yl[7]);
    Yh0 = *(const bf16x8*)&t0;
    Yh1 = *(const bf16x8*)&t1;
    Yl0 = *(const bf16x8*)&t2;
    Yl1 = *(const bf16x8*)&t3;
  }

  float sr[4];
  #pragma unroll
  for (int r=0;r<4;++r) sr[r] = STS[r0 + quad*4 + r];

  // ---- two column-halves: score 16x128, select, emit (kv[32] per lane) ----
  for (int ch=0; ch<2; ++ch){
    int j0 = ch*128;
    u32 kv[32];
    #pragma unroll
    for (int ct=0; ct<8; ++ct){
      const u16* bh = XH + (j0 + ct*16+lm)*72;
      const u16* bl = XL + (j0 + ct*16+lm)*72;
      bf16x8 Bh0 = *(const bf16x8*)(bh + quad*8);
      bf16x8 Bh1 = *(const bf16x8*)(bh + 32 + quad*8);
      bf16x8 Bl0 = *(const bf16x8*)(bl + quad*8);
      bf16x8 Bl1 = *(const bf16x8*)(bl + 32 + quad*8);
      f32x4 a1 = {0.f,0.f,0.f,0.f}, a2 = {0.f,0.f,0.f,0.f};
      a1 = __builtin_amdgcn_mfma_f32_16x16x32_bf16(Yh0, Bh0, a1, 0,0,0);
      a2 = __builtin_amdgcn_mfma_f32_16x16x32_bf16(Yh1, Bh1, a2, 0,0,0);
      a1 = __builtin_amdgcn_mfma_f32_16x16x32_bf16(Yl0, Bh0, a1, 0,0,0);
      a2 = __builtin_amdgcn_mfma_f32_16x16x32_bf16(Yl1, Bh1, a2, 0,0,0);
      a1 = __builtin_amdgcn_mfma_f32_16x16x32_bf16(Yh0, Bl0, a1, 0,0,0);
      a2 = __builtin_amdgcn_mfma_f32_16x16x32_bf16(Yh1, Bl1, a2, 0,0,0);
      float tc = STT[j0 + ct*16 + lm];
      #pragma unroll
      for (int r=0;r<4;++r)
        kv[ct*4 + r] = sortKey(a1[r] + a2[r] + sr[r] + tc);
    }

    // 16-bit-prefix threshold (top-128 of 2048), early-exit in [TOPK, CAP];
    // two independent popcount accumulators halve the serial SALU chain.
    u32 T = 0;
    int cfin = -1;                 // >=0 iff early-exit fired (count known <= CAP)
    for (int bit=15; bit>=0; --bit){
      u32 th2 = (T | (1u<<bit)) << 16;
      int c0 = 0, c1 = 0;
      #pragma unroll
      for (int i=0;i<32;i+=2){
        c0 += (int)__popcll(__ballot(kv[i]   >= th2));
        c1 += (int)__popcll(__ballot(kv[i+1] >= th2));
      }
      int c = c0 + c1;
      if (c >= TOPK){
        T |= (1u<<bit);
        if (c <= CAP){ cfin = c; break; }
      }
    }
    u32 thr = T << 16;

    int wt = u*2 + ch;
    size_t base = ((size_t)b*NWT + wt)*CAP;
    // hoisted emission row bases: flat = rb[r] + (i>>2)*16
    int rb0 = (r0 + quad*4 + 0)*L_SEQ + j0 + lm;
    int rb1 = rb0 + L_SEQ, rb2 = rb1 + L_SEQ, rb3 = rb2 + L_SEQ;

    if (cfin >= 0){
      // ---- fast path (dominant): everything >= thr fits; single mask + single scan ----
      u32 m = 0;
      #pragma unroll
      for (int i=0;i<32;++i) m |= (kv[i] >= thr ? 1u : 0u) << i;
      int n = __popc(m);
      int p = n;
      #pragma unroll
      for (int off=1; off<64; off<<=1){
        int a = __shfl_up(p, off); if (lane >= off) p += a;
      }
      int pos = p - n;
      if (lane == 0){
        cand_n[b*NWT + wt] = cfin;    // ballot count, wave-uniform, <= CAP
        uthr[b*NWT + wt] = thr;
      }
      #pragma unroll
      for (int i=0;i<32;++i){
        if ((m >> i) & 1u){
          int pp2 = pos + __popc(m & ((1u<<i)-1u));   // within-lane offset, no serial chain
          int flat = ((i&3)==0 ? rb0 : (i&3)==1 ? rb1 : (i&3)==2 ? rb2 : rb3) + (i>>2)*16;
          cand[base + pp2] = ((u64)kv[i] << 32) | (u32)flat;
        }
      }
    } else {
      // ---- rare fallback: count at final T may exceed CAP; two-class priority emission ----
      u32 up  = (T < 0xffffu) ? ((T+1u) << 16) : 0xffffffffu;
      u32 m1 = 0, m2 = 0;
      #pragma unroll
      for (int i=0;i<32;++i){
        bool ge = kv[i] >= thr;
        bool c1 = ge && (kv[i] >= up);
        m1 |= (c1 ? 1u : 0u) << i;
        m2 |= ((ge && !c1) ? 1u : 0u) << i;
      }
      int n1 = __popc(m1), n2 = __popc(m2);
      int p1 = n1, p2 = n2;
      #pragma unroll
      for (int off=1; off<64; off<<=1){
        int a = __shfl_up(p1, off); if (lane >= off) p1 += a;
        int c = __shfl_up(p2, off); if (lane >= off) p2 += c;
      }
      int tot1 = __shfl(p1, 63), tot2 = __shfl(p2, 63);
      int pos1 = p1 - n1;
      int pos2 = tot1 + (p2 - n2);
      int total = tot1 + tot2;
      if (lane == 0){
        cand_n[b*NWT + wt] = (total < CAP) ? total : CAP;
        uthr[b*NWT + wt] = thr;
      }
      int o1=0, o2=0;
      #pragma unroll
      for (int i=0;i<32;++i){
        bool c1 = (m1 >> i) & 1u, c2v = (m2 >> i) & 1u;
        if (c1 | c2v){
          int p = c1 ? (pos1 + o1) : (pos2 + o2);
          int flat = ((i&3)==0 ? rb0 : (i&3)==1 ? rb1 : (i&3)==2 ? rb2 : rb3) + (i>>2)*16;
          if (p < CAP) cand[base + p] = ((u64)kv[i] << 32) | (u32)flat;
        }
        o1 += c1; o2 += c2v;
      }
    }
  }
}

// ---------- FALLBACK K1: split x; st; y via MFMA ----------
__global__ __launch_bounds__(256) void k_pre(
    const float* __restrict__ x, const u16* __restrict__ MtH, const u16* __restrict__ MtL,
    const float* __restrict__ uvc,
    u16* __restrict__ xh, u16* __restrict__ xl,
    u16* __restrict__ yh, u16* __restrict__ yl,
    float* __restrict__ st)
{
  __shared__ __align__(16) u16 sh[64][72];
  __shared__ __align__(16) u16 sl[64][72];
  __shared__ float sUV[132];
  int tid = threadIdx.x;
  int g0 = blockIdx.x * 64;
  int b  = g0 >> 8, l0 = g0 & 255;
  int r = tid >> 2, q = tid & 3;

  if (tid < 129) sUV[tid] = uvc[tid];

  float v[16];
  {
    const float* xr = x + (size_t)(g0 + r)*D_IN + q*16;
    #pragma unroll
    for (int i=0;i<4;++i) *(float4*)&v[i*4] = *(const float4*)(xr + i*4);
  }
  {
    u32 hpA[4],lpA[4],hpB[4],lpB[4];
    cvt8(&v[0], hpA, lpA); cvt8(&v[8], hpB, lpB);
    size_t xo = (size_t)(g0 + r)*D_IN + q*16;
    *(uint4*)(xh + xo)     = make_uint4(hpA[0],hpA[1],hpA[2],hpA[3]);
    *(uint4*)(xh + xo + 8) = make_uint4(hpB[0],hpB[1],hpB[2],hpB[3]);
    *(uint4*)(xl + xo)     = make_uint4(lpA[0],lpA[1],lpA[2],lpA[3]);
    *(uint4*)(xl + xo + 8) = make_uint4(lpB[0],lpB[1],lpB[2],lpB[3]);
    *(uint4*)&sh[r][q*16]   = make_uint4(hpA[0],hpA[1],hpA[2],hpA[3]);
    *(uint4*)&sh[r][q*16+8] = make_uint4(hpB[0],hpB[1],hpB[2],hpB[3]);
    *(uint4*)&sl[r][q*16]   = make_uint4(lpA[0],lpA[1],lpA[2],lpA[3]);
    *(uint4*)&sl[r][q*16+8] = make_uint4(lpB[0],lpB[1],lpB[2],lpB[3]);
  }
  __syncthreads();

  {
    float su=0.f, tv=0.f, pa=0.f;
    #pragma unroll
    for (int d=0; d<16; ++d){
      float xa = v[d];
      su = fmaf(xa, sUV[q*16+d], su);
      tv = fmaf(xa, sUV[64+q*16+d], tv);
      pa += fabsf(xa);
    }
    su += __shfl_xor(su,1); su += __shfl_xor(su,2);
    tv += __shfl_xor(tv,1); tv += __shfl_xor(tv,2);
    pa += __shfl_xor(pa,1); pa += __shfl_xor(pa,2);
    if (q == 0){
      bool pad = (pa != 0.f);
      st[(size_t)b*L_SEQ + l0 + r]          = pad ? (su + sUV[128]) : -1e38f;
      st[(size_t)(B_TOT+b)*L_SEQ + l0 + r]  = pad ? tv : -1e38f;
    }
  }

  int w = tid >> 6, lane = tid & 63, lm = lane & 15, quad = lane >> 4;
  bf16x8 Ah0 = *(const bf16x8*)&sh[w*16+lm][quad*8];
  bf16x8 Ah1 = *(const bf16x8*)&sh[w*16+lm][32 + quad*8];
  bf16x8 Al0 = *(const bf16x8*)&sl[w*16+lm][quad*8];
  bf16x8 Al1 = *(const bf16x8*)&sl[w*16+lm][32 + quad*8];
  #pragma unroll
  for (int ct=0; ct<4; ++ct){
    const u16* mth = MtH + (ct*16+lm)*64 + quad*8;
    const u16* mtl = MtL + (ct*16+lm)*64 + quad*8;
    bf16x8 Bh0 = *(const bf16x8*)(mth);
    bf16x8 Bh1 = *(const bf16x8*)(mth + 32);
    bf16x8 Bl0 = *(const bf16x8*)(mtl);
    bf16x8 Bl1 = *(const bf16x8*)(mtl + 32);
    f32x4 a1 = {0.f,0.f,0.f,0.f}, a2 = {0.f,0.f,0.f,0.f};
    a1 = __builtin_amdgcn_mfma_f32_16x16x32_bf16(Ah0, Bh0, a1, 0,0,0);
    a2 = __builtin_amdgcn_mfma_f32_16x16x32_bf16(Ah1, Bh1, a2, 0,0,0);
    a1 = __builtin_amdgcn_mfma_f32_16x16x32_bf16(Al0, Bh0, a1, 0,0,0);
    a2 = __builtin_amdgcn_mfma_f32_16x16x32_bf16(Al1, Bh1, a2, 0,0,0);
    a1 = __builtin_amdgcn_mfma_f32_16x16x32_bf16(Ah0, Bl0, a1, 0,0,0);
    a2 = __builtin_amdgcn_mfma_f32_16x16x32_bf16(Ah1, Bl1, a2, 0,0,0);
    #pragma unroll
    for (int rg=0; rg<4; ++rg){
      float vy = a1[rg] + a2[rg];
      u16 hh = f2bf(vy); float hf = __uint_as_float(((u32)hh)<<16);
      u16 ll = f2bf(vy - hf);
      sh[w*16 + quad*4 + rg][ct*16 + lm] = hh;
      sl[w*16 + quad*4 + rg][ct*16 + lm] = ll;
    }
  }
  {
    size_t yo = (size_t)(g0 + r)*D_IN + q*16;
    *(uint4*)(yh + yo)     = *(uint4*)&sh[r][q*16];
    *(uint4*)(yh + yo + 8) = *(uint4*)&sh[r][q*16+8];
    *(uint4*)(yl + yo)     = *(uint4*)&sl[r][q*16];
    *(uint4*)(yl + yo + 8) = *(uint4*)&sl[r][q*16+8];
  }
}

// ---------- FALLBACK K2: k_score ----------
__global__ __launch_bounds__(256) void k_score(
    const u16* __restrict__ xh, const u16* __restrict__ xl,
    const u16* __restrict__ yh, const u16* __restrict__ yl,
    const float* __restrict__ st,
    u64* __restrict__ cand, int* __restrict__ cand_n, u32* __restrict__ uthr)
{
  int tid = threadIdx.x;
  int lin = blockIdx.x;
  int b    = ((lin >> 6) << 3) | (lin & 7);
  int tile = (lin >> 3) & 7;
  int cb = tile & 1, rb = tile >> 1;
  int r0 = rb*64, j0 = cb*128;
  int w = tid >> 6, lane = tid & 63, lm = lane & 15, quad = lane >> 4;

  size_t rowA = ((size_t)b*L_SEQ + r0 + w*16 + lm)*D_IN;
  bf16x8 A_h0 = *(const bf16x8*)(yh + rowA + quad*8);
  bf16x8 A_h1 = *(const bf16x8*)(yh + rowA + 32 + quad*8);
  bf16x8 A_l0 = *(const bf16x8*)(yl + rowA + quad*8);
  bf16x8 A_l1 = *(const bf16x8*)(yl + rowA + 32 + quad*8);

  float4 s4 = *(const float4*)(st + (size_t)b*L_SEQ + r0 + w*16 + quad*4);
  float sr[4] = {s4.x, s4.y, s4.z, s4.w};
  float tc[8];
  #pragma unroll
  for (int ct=0;ct<8;++ct)
    tc[ct] = st[(size_t)(B_TOT + b)*L_SEQ + j0 + ct*16 + lm];

  u32 kv[32];
  #pragma unroll
  for (int ct=0; ct<8; ++ct){
    size_t rowB = ((size_t)b*L_SEQ + j0 + ct*16 + lm)*D_IN;
    bf16x8 B_h0 = *(const bf16x8*)(xh + rowB + quad*8);
    bf16x8 B_h1 = *(const bf16x8*)(xh + rowB + 32 + quad*8);
    bf16x8 B_l0 = *(const bf16x8*)(xl + rowB + quad*8);
    bf16x8 B_l1 = *(const bf16x8*)(xl + rowB + 32 + quad*8);
    f32x4 a1 = {0.f,0.f,0.f,0.f}, a2 = {0.f,0.f,0.f,0.f};
    a1 = __builtin_amdgcn_mfma_f32_16x16x32_bf16(A_h0, B_h0, a1, 0,0,0);
    a2 = __builtin_amdgcn_mfma_f32_16x16x32_bf16(A_h1, B_h1, a2, 0,0,0);
    a1 = __builtin_amdgcn_mfma_f32_16x16x32_bf16(A_l0, B_h0, a1, 0,0,0);
    a2 = __builtin_amdgcn_mfma_f32_16x16x32_bf16(A_l1, B_h1, a2, 0,0,0);
    a1 = __builtin_amdgcn_mfma_f32_16x16x32_bf16(A_h0, B_l0, a1, 0,0,0);
    a2 = __builtin_amdgcn_mfma_f32_16x16x32_bf16(A_h1, B_l1, a2, 0,0,0);
    #pragma unroll
    for (int r=0;r<4;++r)
      kv[ct*4 + r] = sortKey(a1[r] + a2[r] + sr[r] + tc[ct]);
  }

  u32 T = 0;
  for (int bit=15; bit>=0; --bit){
    u32 th2 = (T | (1u<<bit)) << 16;
    int c = 0;
    #pragma unroll
    for (int i=0;i<32;++i)
      c += (int)__popcll(__ballot(kv[i] >= th2));
    if (c >= TOPK){
      T |= (1u<<bit);
      if (c <= CAP) break;
    }
  }
  u32 thr = T << 16;

  u32 hm = 0;
  #pragma unroll
  for (int i=0;i<32;++i) hm |= (kv[i] >= thr ? 1u : 0u) << i;
  int myc = __popc(hm);
  int pre = myc;
  #pragma unroll
  for (int off=1; off<64; off<<=1){
    int n = __shfl_up(pre, off);
    if (lane >= off) pre += n;
  }
  int total = __shfl(pre, 63);
  int pos = pre - myc;
  int wt = tile*4 + w;
  size_t base = ((size_t)b*NWT + wt)*CAP;
  if (lane == 0){
    cand_n[b*NWT + wt] = (total < CAP) ? total : CAP;
    uthr[b*NWT + wt] = thr;
  }
  while (hm){
    int i = __ffs(hm) - 1; hm &= hm - 1;
    if (pos < CAP){
      int r = i & 3, ct = i >> 2;
      int flat = (r0 + w*16 + quad*4 + r)*L_SEQ + (j0 + ct*16 + lm);
      cand[base + pos] = ((u64)kv[i] << 32) | (u32)flat;
    }
    ++pos;
  }
}

// ---------- K3: two-stage ballot merge -> exact top-128 + softmax ----------
// LB trick: any candidate threshold <= max(per-unit thr) provably has count >= TOPK
// (the max-thr unit alone stored >=128 keys >= its thr), so accept without counting.
// Kept as a SEPARATE 256-thread kernel (rounds 7/9: fusing serializes it at low
// occupancy; standalone, small LDS lets many blocks/CU hide scattered cand reads).
__global__ __launch_bounds__(256) void k_merge(
    const u64* __restrict__ cand, const int* __restrict__ cand_n, const u32* __restrict__ uthr,
    int* __restrict__ selidx, float* __restrict__ selw)
{
  const int SL   = NWT/4;           // 8 slots per wave
  const int NSW  = SL*CAP/64;       // 20 keys per lane
  const int WCAP = 192;
  __shared__ u64 wbuf[4][WCAP];
  __shared__ int wcnt[4];
  __shared__ int scnt[NWT];
  __shared__ u32 wT[4];
  __shared__ int cm, eqc;
  __shared__ int eqi[256];
  __shared__ float sv[TOPK]; __shared__ int si[TOPK];
  __shared__ float fred[8];
  int b = blockIdx.x, tid = threadIdx.x;
  int w = tid >> 6, lane = tid & 63;
  if (tid < NWT) scnt[tid] = cand_n[b*NWT + tid];
  if (tid == 0){ cm = 0; eqc = 0; }
  __syncthreads();

  u32 key[NSW]; int idx[NSW];
  size_t bb = (size_t)b*NWT*CAP + (size_t)(w*SL)*CAP;
  #pragma unroll
  for (int s=0;s<NSW;++s){
    int e = lane + 64*s;
    int slot = e / CAP, p = e - slot*CAP;
    bool ok = p < scnt[w*SL + slot];
    u64 v = ok ? cand[bb + e] : 0ull;
    key[s] = (u32)(v >> 32);
    idx[s] = ok ? (int)(u32)v : 0x7fffffff;
  }

  // wave lower bound = max over this wave's 8 unit thresholds
  u32 lb = uthr[b*NWT + w*SL + (lane & 7)];
  #pragma unroll
  for (int off=1; off<8; off<<=1){
    u32 o = (u32)__shfl_xor((int)lb, off);
    lb = lb > o ? lb : o;
  }

  u32 T = 0;
  for (int bit=31; bit>=0; --bit){
    u32 c2 = T | (1u<<bit);
    if (c2 <= lb){ T = c2; continue; }   // provable accept, no count
    int c = 0;
    #pragma unroll
    for (int s=0;s<NSW;++s) c += (int)__popcll(__ballot(key[s] >= c2));
    if (c >= TOPK){
      T = c2;
      if (c <= WCAP) break;
    }
  }
  if (lane == 0) wT[w] = T;
  {
    int myc = 0;
    #pragma unroll
    for (int s=0;s<NSW;++s) myc += (key[s] >= T) ? 1 : 0;
    int pre = myc;
    #pragma unroll
    for (int off=1; off<64; off<<=1){
      int n = __shfl_up(pre, off);
      if (lane >= off) pre += n;
    }
    int total = __shfl(pre, 63);
    int pos = pre - myc;
    if (lane == 0) wcnt[w] = (total < WCAP) ? total : WCAP;
    #pragma unroll
    for (int s=0;s<NSW;++s){
      if (key[s] >= T){
        if (pos < WCAP) wbuf[w][pos] = ((u64)key[s] << 32) | (u32)idx[s];
        ++pos;
      }
    }
  }
  __syncthreads();

  if (w == 0){
    const int NS2 = 4*WCAP/64;   // 12
    u32 k2[NS2]; int i2[NS2];
    #pragma unroll
    for (int s=0;s<NS2;++s){
      int e = lane + 64*s;
      int slot = e / WCAP, p = e - slot*WCAP;
      bool ok = p < wcnt[slot];
      u64 v = ok ? wbuf[slot][p] : 0ull;
      k2[s] = (u32)(v >> 32);
      i2[s] = ok ? (int)(u32)v : 0x7fffffff;
    }
    u32 lb2 = wT[0];
    lb2 = lb2 > wT[1] ? lb2 : wT[1];
    lb2 = lb2 > wT[2] ? lb2 : wT[2];
    lb2 = lb2 > wT[3] ? lb2 : wT[3];
    u32 T2 = 0;
    for (int bit=31; bit>=0; --bit){
      u32 c2 = T2 | (1u<<bit);
      if (c2 <= lb2){ T2 = c2; continue; }   // provable accept, exactness preserved
      int c = 0;
      #pragma unroll
      for (int s=0;s<NS2;++s) c += (int)__popcll(__ballot(k2[s] >= c2));
      if (c >= TOPK) T2 = c2;
    }
    int m = 0;
    #pragma unroll
    for (int s=0;s<NS2;++s) m += (int)__popcll(__ballot(k2[s] > T2));
    #pragma unroll
    for (int s=0;s<NS2;++s){
      if (k2[s] > T2){
        int p = atomicAdd(&cm, 1);
        sv[p] = unKey(k2[s]) * 0.0625f; si[p] = i2[s];
      } else if (k2[s] == T2 && i2[s] != 0x7fffffff){
        int q = atomicAdd(&eqc, 1);
        if (q < 256) eqi[q] = i2[s];
      }
    }
    if (lane == 0){
      int need = TOPK - m;
      int n = eqc < 256 ? eqc : 256;
      float tv = unKey(T2) * 0.0625f;
      for (int s2=0; s2<need; ++s2){
        int bi = s2;
        for (int j=s2+1;j<n;++j) if (eqi[j] < eqi[bi]) bi = j;
        int t2 = eqi[s2]; eqi[s2] = eqi[bi]; eqi[bi] = t2;
        sv[m+s2] = tv; si[m+s2] = eqi[s2];
      }
    }
  }
  __syncthreads();

  float v = (tid < TOPK) ? sv[tid] : -3.4e38f;
  float mx = v;
  #pragma unroll
  for (int off=1; off<64; off<<=1) mx = fmaxf(mx, __shfl_xor(mx, off));
  if ((tid&63)==0) fred[tid>>6] = mx;
  __syncthreads();
  mx = fmaxf(fred[0], fred[1]);
  float e = (tid < TOPK) ? expf(v - mx) : 0.f;
  float s = e;
  #pragma unroll
  for (int off=1; off<64; off<<=1) s += __shfl_xor(s, off);
  if ((tid&63)==0) fred[4 + (tid>>6)] = s;
  __syncthreads();
  s = fred[4] + fred[5];
  if (tid < TOPK){
    selw[(size_t)b*TOPK + tid]   = e / s;
    selidx[(size_t)b*TOPK + tid] = si[tid];
  }
}

// ---------- K4: gather + split-bf16 MFMA MLP1 + pooling + rho (512-thread / 8-wave) ----------
__global__ __launch_bounds__(512) void k_mlp(
    const float* __restrict__ x, const int* __restrict__ selidx, const float* __restrict__ selw,
    const u16* __restrict__ xiH, const u16* __restrict__ xiL,
    const u16* __restrict__ phiH, const u16* __restrict__ phiL,
    const float* __restrict__ phi_b1, const float* __restrict__ phi_w2, const float* __restrict__ phi_b2,
    const float* __restrict__ xi_b1,  const float* __restrict__ xi_w2,  const float* __restrict__ xi_b2,
    const float* __restrict__ rho_w1, const float* __restrict__ rho_b1,
    const float* __restrict__ rho_w2, const float* __restrict__ rho_b2,
    float* __restrict__ out)
{
  __shared__ __align__(16) u16 AFh[8][4][64][8];
  __shared__ __align__(16) u16 AFl[8][4][64][8];
  __shared__ int   sidx[TOPK];
  __shared__ float swp[TOPK], swd[TOPK];
  __shared__ float gpL[256], gsL[256];
  __shared__ float pooled[256], t1[256];
  __shared__ float pp[512];
  __shared__ float wsums[2];
  int b = blockIdx.x, tid = threadIdx.x;
  int w = tid >> 6, lane = tid & 63;

  if (tid < TOPK){
    int fl = selidx[(size_t)b*TOPK + tid];
    sidx[tid] = fl;
    float wv = selw[(size_t)b*TOPK + tid];
    bool dg = ((fl>>8) == (fl&255));
    swp[tid] = dg ? 0.f : wv;
    swd[tid] = dg ? wv  : 0.f;
  }
  __syncthreads();

  // wsums via 2 wave reductions (parallel with gather on other waves)
  if (w == 0){
    float a = swp[lane] + swp[64 + lane];
    #pragma unroll
    for (int off=1; off<64; off<<=1) a += __shfl_xor(a, off);
    if (lane == 0) wsums[0] = a;
  } else if (w == 1){
    float a = swd[lane] + swd[64 + lane];
    #pragma unroll
    for (int off=1; off<64; off<<=1) a += __shfl_xor(a, off);
    if (lane == 0) wsums[1] = a;
  }

  // gather: thread = (m, qq); qq selects 32 of the 128 concat dims
  {
    int m = tid >> 2, qq = tid & 3;
    int fl = sidx[m];
    int rc = (qq < 2) ? (fl >> 8) : (fl & 255);
    const float* src = x + ((size_t)b*L_SEQ + rc)*D_IN + (qq & 1)*32;
    int kt = m >> 4, l16 = m & 15;
    #pragma unroll
    for (int g=0; g<4; ++g){
      float v[8];
      *(float4*)&v[0] = *(const float4*)(src + g*8);
      *(float4*)&v[4] = *(const float4*)(src + g*8 + 4);
      u32 hp[4], lp[4];
      cvt8(v, hp, lp);
      *(uint4*)&AFh[kt][qq][l16 + 16*g][0] = make_uint4(hp[0],hp[1],hp[2],hp[3]);
      *(uint4*)&AFl[kt][qq][l16 + 16*g][0] = make_uint4(lp[0],lp[1],lp[2],lp[3]);
    }
  }
  __syncthreads();

  int lm = lane & 15, quad = lane >> 4;

  #pragma unroll
  for (int hi2=0; hi2<2; ++hi2){
    int ht = w + 8*hi2;
    int h  = ht*16 + lm;
    bf16x8 BXh[4], BXl[4], BPh[2], BPl[2];
    #pragma unroll
    for (int c=0;c<4;++c){
      BXh[c] = *(const bf16x8*)(xiH + h*128 + c*32 + quad*8);
      BXl[c] = *(const bf16x8*)(xiL + h*128 + c*32 + quad*8);
    }
    #pragma unroll
    for (int c=0;c<2;++c){
      BPh[c] = *(const bf16x8*)(phiH + h*64 + c*32 + quad*8);
      BPl[c] = *(const bf16x8*)(phiL + h*64 + c*32 + quad*8);
    }
    float bxi = xi_b1[h], bph = phi_b1[h];
    float gp = 0.f, gs = 0.f;
    for (int kt=0; kt<8; ++kt){
      bf16x8 Ah_[4], Al_[4];
      #pragma unroll
      for (int c=0;c<4;++c){
        Ah_[c] = *(const bf16x8*)&AFh[kt][c][lane][0];
        Al_[c] = *(const bf16x8*)&AFl[kt][c][lane][0];
      }
      f32x4 cx = {0.f,0.f,0.f,0.f}, cp = {0.f,0.f,0.f,0.f};
      #pragma unroll
      for (int c=0;c<4;++c){
        cx = __builtin_amdgcn_mfma_f32_16x16x32_bf16(Ah_[c], BXh[c], cx, 0,0,0);
        cx = __builtin_amdgcn_mfma_f32_16x16x32_bf16(Al_[c], BXh[c], cx, 0,0,0);
        cx = __builtin_amdgcn_mfma_f32_16x16x32_bf16(Ah_[c], BXl[c], cx, 0,0,0);
      }
      #pragma unroll
      for (int c=0;c<2;++c){
        cp = __builtin_amdgcn_mfma_f32_16x16x32_bf16(Ah_[c], BPh[c], cp, 0,0,0);
        cp = __builtin_amdgcn_mfma_f32_16x16x32_bf16(Al_[c], BPh[c], cp, 0,0,0);
        cp = __builtin_amdgcn_mfma_f32_16x16x32_bf16(Ah_[c], BPl[c], cp, 0,0,0);
      }
      #pragma unroll
      for (int r=0;r<4;++r){
        int kk = kt*16 + quad*4 + r;
        gp = fmaf(swp[kk], fmaxf(cx[r] + bxi, 0.f), gp);
        gs = fmaf(swd[kk], fmaxf(cp[r] + bph, 0.f), gs);
      }
    }
    gp += __shfl_xor(gp, 16); gp += __shfl_xor(gp, 32);
    gs += __shfl_xor(gs, 16); gs += __shfl_xor(gs, 32);
    if (quad == 0){ gpL[h] = gp; gsL[h] = gs; }
  }
  __syncthreads();

  // pooled: 2-way split over d
  {
    int h = tid & 255, half = tid >> 8;
    float wsp = wsums[0], wss = wsums[1];
    float po = (half == 0) ? (wsp*xi_b2[h] + wss*phi_b2[h]) : 0.f;
    int dd0 = half*128;
    for (int d=dd0; d<dd0+128; ++d){
      po = fmaf(gpL[d], xi_w2[d*HIDN + h], po);
      po = fmaf(gsL[d], phi_w2[d*HIDN + h], po);
    }
    pp[half*256 + h] = po;
  }
  __syncthreads();
  if (tid < 256) pooled[tid] = pp[tid] + pp[256 + tid];
  __syncthreads();
  // t1: 2-way split over d
  {
    int h = tid & 255, half = tid >> 8;
    float a = (half == 0) ? rho_b1[h] : 0.f;
    int dd0 = half*128;
    for (int d=dd0; d<dd0+128; ++d) a = fmaf(pooled[d], rho_w1[d*HIDN + h], a);
    pp[half*256 + h] = a;
  }
  __syncthreads();
  if (tid < 256) t1[tid] = fmaxf(pp[tid] + pp[256 + tid], 0.f);
  __syncthreads();
  // out: 4-way split over d
  {
    int h = tid & 127, part = tid >> 7;
    float o = (part == 0) ? rho_b2[h] : 0.f;
    int dd0 = part*64;
    for (int d=dd0; d<dd0+64; ++d) o = fmaf(t1[d], rho_w2[d*128 + h], o);
    pp[part*128 + h] = o;
  }
  __syncthreads();
  if (tid < 128)
    out[(size_t)b*128 + tid] = pp[tid] + pp[128+tid] + pp[256+tid] + pp[384+tid];
}

// ---------- host ----------
extern "C" void kernel_launch(void* const* d_in, const int* in_sizes, int n_in,
                              void* d_out, int out_size, void* d_ws, size_t ws_size,
                              hipStream_t stream)
{
  (void)in_sizes; (void)n_in; (void)out_size; (void)ws_size;
  const float* x      = (const float*)d_in[0];
  const float* Wq     = (const float*)d_in[1];
  const float* bq     = (const float*)d_in[2];
  const float* Wk     = (const float*)d_in[3];
  const float* bk     = (const float*)d_in[4];
  const float* phi_w1 = (const float*)d_in[5];
  const float* phi_b1 = (const float*)d_in[6];
  const float* phi_w2 = (const float*)d_in[7];
  const float* phi_b2 = (const float*)d_in[8];
  const float* xi_w1  = (const float*)d_in[9];
  const float* xi_b1  = (const float*)d_in[10];
  const float* xi_w2  = (const float*)d_in[11];
  const float* xi_b2  = (const float*)d_in[12];
  const float* rho_w1 = (const float*)d_in[13];
  const float* rho_b1 = (const float*)d_in[14];
  const float* rho_w2 = (const float*)d_in[15];
  const float* rho_b2 = (const float*)d_in[16];
  float* out = (float*)d_out;

  const size_t NX = (size_t)B_TOT*L_SEQ*D_IN;      // 8,388,608
  float* uvc    = (float*)d_ws;                    // 256
  float* st     = uvc + 256;                       // 2*512*256
  float* selw   = st + (size_t)2*B_TOT*L_SEQ;      // 512*128
  int*   selidx = (int*)(selw + (size_t)B_TOT*TOPK);
  int*   cand_n = selidx + (size_t)B_TOT*TOPK;     // 512*32
  u32*   uthr   = (u32*)(cand_n + (size_t)B_TOT*NWT); // 512*32
  u64*   cand   = (u64*)(uthr + (size_t)B_TOT*NWT);
  u16*   MtH    = (u16*)(cand + (size_t)B_TOT*NWT*CAP);
  u16*   MtL    = MtH + 64*64;
  u16*   xiH    = MtL + 64*64;
  u16*   xiL    = xiH + 256*128;
  u16*   phiH   = xiL + 256*128;
  u16*   phiL   = phiH + 256*64;
  u16*   xh     = phiL + 256*64;
  u16*   xl     = xh + NX;
  u16*   yh     = xl + NX;
  u16*   yl     = yh + NX;

  // deterministic per-device check (same result every call -> graph-safe)
  hipError_t aerr = hipFuncSetAttribute((const void*)k_fused,
                      hipFuncAttributeMaxDynamicSharedMemorySize, FLDS);

  k_wprep<<<dim3(256),  dim3(256), 0, stream>>>(Wq, bq, Wk, bk, xi_w1, phi_w1,
                                                MtH, MtL, uvc, xiH, xiL, phiH, phiL);
  if (aerr == hipSuccess){
    k_fused<<<dim3(B_TOT), dim3(1024), FLDS, stream>>>(x, MtH, MtL, uvc, cand, cand_n, uthr);
  } else {
    k_pre  <<<dim3(2048), dim3(256), 0, stream>>>(x, MtH, MtL, uvc, xh, xl, yh, yl, st);
    k_score<<<dim3(4096), dim3(256), 0, stream>>>(xh, xl, yh, yl, st, cand, cand_n, uthr);
  }
  k_merge<<<dim3(B_TOT), dim3(256), 0, stream>>>(cand, cand_n, uthr, selidx, selw);
  k_mlp  <<<dim3(B_TOT), dim3(512), 0, stream>>>(x, selidx, selw,
            xiH, xiL, phiH, phiL,
            phi_b1, phi_w2, phi_b2,
            xi_b1, xi_w2, xi_b2,
            rho_w1, rho_b1, rho_w2, rho_b2, out);
}

// Round 14
// 231.737 us; speedup vs baseline: 1.0470x; 1.0154x over previous
//
#include <hip/hip_runtime.h>

typedef unsigned short u16;
typedef unsigned int   u32;
typedef unsigned char  u8;
typedef unsigned long long u64;

#define B_TOT 512
#define L_SEQ 256
#define D_IN  64
#define HIDN  256
#define TOPK  128
#define CAP   160              // candidate cap per unit (even: u64 pairs never straddle units)
#define NWT   32               // units per batch
#define FLDS  76304            // fused dynamic LDS bytes (XH/XL + STS/STT/SUV; no Y bounce)

typedef float  f32x4  __attribute__((ext_vector_type(4)));
typedef __bf16 bf16x8 __attribute__((ext_vector_type(8)));

// ---------- helpers ----------
__device__ __forceinline__ u16 f2bf(float f){
  u32 u = __float_as_uint(f);
  u32 r = u + 0x7fffu + ((u>>16)&1u);   // RNE
  return (u16)(r>>16);
}
__device__ __forceinline__ u32 sortKey(float f){
  u32 b = __float_as_uint(f);
  return (b & 0x80000000u) ? ~b : (b | 0x80000000u);
}
__device__ __forceinline__ float unKey(u32 u){
  u32 b = (u & 0x80000000u) ? (u & 0x7fffffffu) : ~u;
  return __uint_as_float(b);
}
__device__ __forceinline__ void cvt8(const float* v, u32* hp, u32* lp){
  #pragma unroll
  for (int i=0;i<4;++i){
    float v0 = v[2*i], v1 = v[2*i+1];
    u16 h0 = f2bf(v0); float h0f = __uint_as_float(((u32)h0)<<16); u16 l0 = f2bf(v0 - h0f);
    u16 h1 = f2bf(v1); float h1f = __uint_as_float(((u32)h1)<<16); u16 l1 = f2bf(v1 - h1f);
    hp[i] = (u32)h0 | ((u32)h1<<16);
    lp[i] = (u32)l0 | ((u32)l1<<16);
  }
}

// ---------- K0: fused weight prep (uvc via wave reductions, no serial tails) ----------
__global__ __launch_bounds__(256) void k_wprep(
    const float* __restrict__ Wq, const float* __restrict__ bq,
    const float* __restrict__ Wk, const float* __restrict__ bk,
    const float* __restrict__ xi_w1, const float* __restrict__ phi_w1,
    u16* __restrict__ MtH, u16* __restrict__ MtL, float* __restrict__ uvc,
    u16* __restrict__ xiH, u16* __restrict__ xiL,
    u16* __restrict__ phiH, u16* __restrict__ phiL)
{
  int bid = blockIdx.x, tid = threadIdx.x;
  if (bid < 64){
    __shared__ float wq[HIDN];
    __shared__ float part[256];
    int a = bid;
    wq[tid] = Wq[a*HIDN + tid];
    __syncthreads();
    int bcol = tid & 63, q = tid >> 6;
    float s = 0.f;
    for (int h = q*64; h < q*64 + 64; ++h)
      s = fmaf(wq[h], Wk[bcol*HIDN + h], s);
    part[tid] = s;
    __syncthreads();
    if (tid < 64){
      float mv = part[tid] + part[64+tid] + part[128+tid] + part[192+tid];
      u16 hh = f2bf(mv); float hf = __uint_as_float(((u32)hh)<<16);
      u16 ll = f2bf(mv - hf);
      MtH[tid*64 + a] = hh;          // Mt[c][a] = M[a][c]
      MtL[tid*64 + a] = ll;
    }
    // uvc via per-wave shuffle reductions (4 elems/lane)
    int wv = tid >> 6, ln = tid & 63;
    if (wv == 0){
      float s2 = 0.f;
      #pragma unroll
      for (int i=0;i<4;++i){ int h = ln*4+i; s2 = fmaf(wq[h], bk[h], s2); }
      #pragma unroll
      for (int off=1; off<64; off<<=1) s2 += __shfl_xor(s2, off);
      if (ln == 0) uvc[a] = s2;
    } else if (wv == 1){
      float s2 = 0.f;
      #pragma unroll
      for (int i=0;i<4;++i){ int h = ln*4+i; s2 = fmaf(Wk[a*HIDN + h], bq[h], s2); }
      #pragma unroll
      for (int off=1; off<64; off<<=1) s2 += __shfl_xor(s2, off);
      if (ln == 0) uvc[64 + a] = s2;
    } else if (wv == 2 && a == 0){
      float s2 = 0.f;
      #pragma unroll
      for (int i=0;i<4;++i){ int h = ln*4+i; s2 = fmaf(bq[h], bk[h], s2); }
      #pragma unroll
      for (int off=1; off<64; off<<=1) s2 += __shfl_xor(s2, off);
      if (ln == 0) uvc[128] = s2;
    }
  } else {
    int t = (bid-64)*256 + tid;
    if (t < 256*128){
      int h = t >> 7, d = t & 127;
      float v = xi_w1[d*HIDN + h];
      u16 hh = f2bf(v); float hf = __uint_as_float(((u32)hh)<<16);
      u16 ll = f2bf(v - hf);
      xiH[h*128 + d] = hh; xiL[h*128 + d] = ll;
    } else {
      int t2 = t - 256*128;
      int h = t2 >> 6, d = t2 & 63;
      float v = phi_w1[d*HIDN + h];
      u16 hh = f2bf(v); float hf = __uint_as_float(((u32)hh)<<16);
      u16 ll = f2bf(v - hf);
      phiH[h*64 + d] = hh; phiL[h*64 + d] = ll;
    }
  }
}

// ---------- K-FUSED (1024 threads / 16 waves): split + y-MFMA + scoring + per-unit top-k ----------
// grid 512 (1 batch/block), ~76 KB LDS (no Y bounce; swapped-MFMA y with permuted Mt).
// Settled config (rounds 11/13, 234-235 us): u64 single-stream cand (round-12 split
// format regressed: partial-line u16 stores), single-class fast path, popc-offset
// emission. VGPR hard-pinned at 64 for 1024-thread blocks (rounds 6/8/10).
__global__ void __launch_bounds__(1024) __attribute__((amdgpu_waves_per_eu(4,4))) k_fused(
    const float* __restrict__ x, const u16* __restrict__ MtH, const u16* __restrict__ MtL,
    const float* __restrict__ uvc,
    u64* __restrict__ cand, int* __restrict__ cand_n, u32* __restrict__ uthr)
{
  extern __shared__ __align__(16) u16 smem[];
  u16* XH = smem;                       // [256][72]
  u16* XL = XH + 256*72;                // [256][72]
  float* STS = (float*)(XL + 256*72);   // [256] s_i + c (pad -> -1e38)
  float* STT = STS + 256;               // [256] t_j   (pad -> -1e38)
  float* SUV = STT + 256;               // [129]

  int tid = threadIdx.x;
  int b = blockIdx.x;
  const float* xb = x + (size_t)b*(L_SEQ*D_IN);

  if (tid < 129) SUV[tid] = uvc[tid];

  // ---- Phase A: load + split x into LDS (quarter-row per thread) ----
  int ar = tid >> 2, aq = tid & 3;
  float v[16];
  {
    const float* src = xb + (size_t)ar*D_IN + aq*16;
    #pragma unroll
    for (int i=0;i<4;++i) *(float4*)&v[i*4] = *(const float4*)(src + i*4);
    u32 hpA[4],lpA[4],hpB[4],lpB[4];
    cvt8(&v[0], hpA, lpA); cvt8(&v[8], hpB, lpB);
    u16* dh = XH + ar*72 + aq*16;
    u16* dl = XL + ar*72 + aq*16;
    *(uint4*)(dh)     = make_uint4(hpA[0],hpA[1],hpA[2],hpA[3]);
    *(uint4*)(dh + 8) = make_uint4(hpB[0],hpB[1],hpB[2],hpB[3]);
    *(uint4*)(dl)     = make_uint4(lpA[0],lpA[1],lpA[2],lpA[3]);
    *(uint4*)(dl + 8) = make_uint4(lpB[0],lpB[1],lpB[2],lpB[3]);
  }
  __syncthreads();   // SUV + XH/XL visible

  // ---- s_i, t_j, pad (4-lane group reduction) ----
  {
    float su=0.f, tv=0.f, pa=0.f;
    #pragma unroll
    for (int d=0; d<16; ++d){
      float xa = v[d];
      su = fmaf(xa, SUV[aq*16+d], su);
      tv = fmaf(xa, SUV[64+aq*16+d], tv);
      pa += fabsf(xa);
    }
    su += __shfl_xor(su,1); su += __shfl_xor(su,2);
    tv += __shfl_xor(tv,1); tv += __shfl_xor(tv,2);
    pa += __shfl_xor(pa,1); pa += __shfl_xor(pa,2);
    if (aq == 0){
      bool pad = (pa != 0.f);
      STS[ar] = pad ? (su + SUV[128]) : -1e38f;
      STT[ar] = pad ? tv : -1e38f;
    }
  }
  __syncthreads();   // STS/STT visible

  int w = tid >> 6, lane = tid & 63, lm = lane & 15, quad = lane >> 4;
  int u  = w;               // one row-unit per wave: rows [16u, 16u+16)
  int r0 = u*16;

  // ---- y = x M directly into scoring A-frag layout (swapped MFMA, permuted Mt) ----
  bf16x8 Yh0, Yh1, Yl0, Yl1;
  {
    const u16* xh_ = XH + (r0+lm)*72;
    const u16* xl_ = XL + (r0+lm)*72;
    bf16x8 Xh0 = *(const bf16x8*)(xh_ + quad*8);
    bf16x8 Xh1 = *(const bf16x8*)(xh_ + 32 + quad*8);
    bf16x8 Xl0 = *(const bf16x8*)(xl_ + quad*8);
    bf16x8 Xl1 = *(const bf16x8*)(xl_ + 32 + quad*8);
    u32 yh[8], yl[8];     // packed col-pairs; slot = (ct>>1)*4 + (ct&1)*2 + pr
    #pragma unroll
    for (int ct=0; ct<4; ++ct){
      int srow = 8*(lm>>2) + 4*(ct&1) + (lm&3) + 32*(ct>>1);   // sigma(ct,lm)
      const u16* mth = MtH + srow*64 + quad*8;
      const u16* mtl = MtL + srow*64 + quad*8;
      bf16x8 Mh0 = *(const bf16x8*)(mth);
      bf16x8 Mh1 = *(const bf16x8*)(mth + 32);
      bf16x8 Ml0 = *(const bf16x8*)(mtl);
      bf16x8 Ml1 = *(const bf16x8*)(mtl + 32);
      f32x4 a1 = {0.f,0.f,0.f,0.f}, a2 = {0.f,0.f,0.f,0.f};
      a1 = __builtin_amdgcn_mfma_f32_16x16x32_bf16(Mh0, Xh0, a1, 0,0,0);
      a2 = __builtin_amdgcn_mfma_f32_16x16x32_bf16(Mh1, Xh1, a2, 0,0,0);
      a1 = __builtin_amdgcn_mfma_f32_16x16x32_bf16(Ml0, Xh0, a1, 0,0,0);
      a2 = __builtin_amdgcn_mfma_f32_16x16x32_bf16(Ml1, Xh1, a2, 0,0,0);
      a1 = __builtin_amdgcn_mfma_f32_16x16x32_bf16(Mh0, Xl0, a1, 0,0,0);
      a2 = __builtin_amdgcn_mfma_f32_16x16x32_bf16(Mh1, Xl1, a2, 0,0,0);
      #pragma unroll
      for (int pr=0; pr<2; ++pr){
        float v0 = a1[2*pr]   + a2[2*pr];
        float v1 = a1[2*pr+1] + a2[2*pr+1];
        u16 h0 = f2bf(v0); u16 h1 = f2bf(v1);
        u16 l0 = f2bf(v0 - __uint_as_float(((u32)h0)<<16));
        u16 l1 = f2bf(v1 - __uint_as_float(((u32)h1)<<16));
        int slot = (ct>>1)*4 + (ct&1)*2 + pr;
        yh[slot] = (u32)h0 | ((u32)h1<<16);
        yl[slot] = (u32)l0 | ((u32)l1<<16);
      }
    }
    uint4 t0 = make_uint4(yh[0],yh[1],yh[2],yh[3]);
    uint4 t1 = make_uint4(yh[4],yh[5],yh[6],yh[7]);
    uint4 t2 = make_uint4(yl[0],yl[1],yl[2],yl[3]);
    uint4 t3 = make_uint4(yl[4],yl[5],yl[6],yl[7]);
    Yh0 = *(const bf16x8*)&t0;
    Yh1 = *(const bf16x8*)&t1;
    Yl0 = *(const bf16x8*)&t2;
    Yl1 = *(const bf16x8*)&t3;
  }

  float sr[4];
  #pragma unroll
  for (int r=0;r<4;++r) sr[r] = STS[r0 + quad*4 + r];

  // ---- two column-halves: score 16x128, select, emit (kv[32] per lane) ----
  for (int ch=0; ch<2; ++ch){
    int j0 = ch*128;
    u32 kv[32];
    #pragma unroll
    for (int ct=0; ct<8; ++ct){
      const u16* bh = XH + (j0 + ct*16+lm)*72;
      const u16* bl = XL + (j0 + ct*16+lm)*72;
      bf16x8 Bh0 = *(const bf16x8*)(bh + quad*8);
      bf16x8 Bh1 = *(const bf16x8*)(bh + 32 + quad*8);
      bf16x8 Bl0 = *(const bf16x8*)(bl + quad*8);
      bf16x8 Bl1 = *(const bf16x8*)(bl + 32 + quad*8);
      f32x4 a1 = {0.f,0.f,0.f,0.f}, a2 = {0.f,0.f,0.f,0.f};
      a1 = __builtin_amdgcn_mfma_f32_16x16x32_bf16(Yh0, Bh0, a1, 0,0,0);
      a2 = __builtin_amdgcn_mfma_f32_16x16x32_bf16(Yh1, Bh1, a2, 0,0,0);
      a1 = __builtin_amdgcn_mfma_f32_16x16x32_bf16(Yl0, Bh0, a1, 0,0,0);
      a2 = __builtin_amdgcn_mfma_f32_16x16x32_bf16(Yl1, Bh1, a2, 0,0,0);
      a1 = __builtin_amdgcn_mfma_f32_16x16x32_bf16(Yh0, Bl0, a1, 0,0,0);
      a2 = __builtin_amdgcn_mfma_f32_16x16x32_bf16(Yh1, Bl1, a2, 0,0,0);
      float tc = STT[j0 + ct*16 + lm];
      #pragma unroll
      for (int r=0;r<4;++r)
        kv[ct*4 + r] = sortKey(a1[r] + a2[r] + sr[r] + tc);
    }

    // 16-bit-prefix threshold (top-128 of 2048), early-exit in [TOPK, CAP];
    // two independent popcount accumulators halve the serial SALU chain.
    u32 T = 0;
    int cfin = -1;                 // >=0 iff early-exit fired (count known <= CAP)
    for (int bit=15; bit>=0; --bit){
      u32 th2 = (T | (1u<<bit)) << 16;
      int c0 = 0, c1 = 0;
      #pragma unroll
      for (int i=0;i<32;i+=2){
        c0 += (int)__popcll(__ballot(kv[i]   >= th2));
        c1 += (int)__popcll(__ballot(kv[i+1] >= th2));
      }
      int c = c0 + c1;
      if (c >= TOPK){
        T |= (1u<<bit);
        if (c <= CAP){ cfin = c; break; }
      }
    }
    u32 thr = T << 16;

    int wt = u*2 + ch;
    size_t base = ((size_t)b*NWT + wt)*CAP;
    // hoisted emission row bases: flat = rb[r] + (i>>2)*16
    int rb0 = (r0 + quad*4 + 0)*L_SEQ + j0 + lm;
    int rb1 = rb0 + L_SEQ, rb2 = rb1 + L_SEQ, rb3 = rb2 + L_SEQ;

    if (cfin >= 0){
      // ---- fast path (dominant): everything >= thr fits; single mask + single scan ----
      u32 m = 0;
      #pragma unroll
      for (int i=0;i<32;++i) m |= (kv[i] >= thr ? 1u : 0u) << i;
      int n = __popc(m);
      int p = n;
      #pragma unroll
      for (int off=1; off<64; off<<=1){
        int a = __shfl_up(p, off); if (lane >= off) p += a;
      }
      int pos = p - n;
      if (lane == 0){
        cand_n[b*NWT + wt] = cfin;    // ballot count, wave-uniform, <= CAP
        uthr[b*NWT + wt] = thr;
      }
      #pragma unroll
      for (int i=0;i<32;++i){
        if ((m >> i) & 1u){
          int pp2 = pos + __popc(m & ((1u<<i)-1u));   // within-lane offset, no serial chain
          int flat = ((i&3)==0 ? rb0 : (i&3)==1 ? rb1 : (i&3)==2 ? rb2 : rb3) + (i>>2)*16;
          cand[base + pp2] = ((u64)kv[i] << 32) | (u32)flat;
        }
      }
    } else {
      // ---- rare fallback: count at final T may exceed CAP; two-class priority emission ----
      u32 up  = (T < 0xffffu) ? ((T+1u) << 16) : 0xffffffffu;
      u32 m1 = 0, m2 = 0;
      #pragma unroll
      for (int i=0;i<32;++i){
        bool ge = kv[i] >= thr;
        bool c1 = ge && (kv[i] >= up);
        m1 |= (c1 ? 1u : 0u) << i;
        m2 |= ((ge && !c1) ? 1u : 0u) << i;
      }
      int n1 = __popc(m1), n2 = __popc(m2);
      int p1 = n1, p2 = n2;
      #pragma unroll
      for (int off=1; off<64; off<<=1){
        int a = __shfl_up(p1, off); if (lane >= off) p1 += a;
        int c = __shfl_up(p2, off); if (lane >= off) p2 += c;
      }
      int tot1 = __shfl(p1, 63), tot2 = __shfl(p2, 63);
      int pos1 = p1 - n1;
      int pos2 = tot1 + (p2 - n2);
      int total = tot1 + tot2;
      if (lane == 0){
        cand_n[b*NWT + wt] = (total < CAP) ? total : CAP;
        uthr[b*NWT + wt] = thr;
      }
      int o1=0, o2=0;
      #pragma unroll
      for (int i=0;i<32;++i){
        bool c1 = (m1 >> i) & 1u, c2v = (m2 >> i) & 1u;
        if (c1 | c2v){
          int p = c1 ? (pos1 + o1) : (pos2 + o2);
          int flat = ((i&3)==0 ? rb0 : (i&3)==1 ? rb1 : (i&3)==2 ? rb2 : rb3) + (i>>2)*16;
          if (p < CAP) cand[base + p] = ((u64)kv[i] << 32) | (u32)flat;
        }
        o1 += c1; o2 += c2v;
      }
    }
  }
}

// ---------- FALLBACK K1: split x; st; y via MFMA ----------
__global__ __launch_bounds__(256) void k_pre(
    const float* __restrict__ x, const u16* __restrict__ MtH, const u16* __restrict__ MtL,
    const float* __restrict__ uvc,
    u16* __restrict__ xh, u16* __restrict__ xl,
    u16* __restrict__ yh, u16* __restrict__ yl,
    float* __restrict__ st)
{
  __shared__ __align__(16) u16 sh[64][72];
  __shared__ __align__(16) u16 sl[64][72];
  __shared__ float sUV[132];
  int tid = threadIdx.x;
  int g0 = blockIdx.x * 64;
  int b  = g0 >> 8, l0 = g0 & 255;
  int r = tid >> 2, q = tid & 3;

  if (tid < 129) sUV[tid] = uvc[tid];

  float v[16];
  {
    const float* xr = x + (size_t)(g0 + r)*D_IN + q*16;
    #pragma unroll
    for (int i=0;i<4;++i) *(float4*)&v[i*4] = *(const float4*)(xr + i*4);
  }
  {
    u32 hpA[4],lpA[4],hpB[4],lpB[4];
    cvt8(&v[0], hpA, lpA); cvt8(&v[8], hpB, lpB);
    size_t xo = (size_t)(g0 + r)*D_IN + q*16;
    *(uint4*)(xh + xo)     = make_uint4(hpA[0],hpA[1],hpA[2],hpA[3]);
    *(uint4*)(xh + xo + 8) = make_uint4(hpB[0],hpB[1],hpB[2],hpB[3]);
    *(uint4*)(xl + xo)     = make_uint4(lpA[0],lpA[1],lpA[2],lpA[3]);
    *(uint4*)(xl + xo + 8) = make_uint4(lpB[0],lpB[1],lpB[2],lpB[3]);
    *(uint4*)&sh[r][q*16]   = make_uint4(hpA[0],hpA[1],hpA[2],hpA[3]);
    *(uint4*)&sh[r][q*16+8] = make_uint4(hpB[0],hpB[1],hpB[2],hpB[3]);
    *(uint4*)&sl[r][q*16]   = make_uint4(lpA[0],lpA[1],lpA[2],lpA[3]);
    *(uint4*)&sl[r][q*16+8] = make_uint4(lpB[0],lpB[1],lpB[2],lpB[3]);
  }
  __syncthreads();

  {
    float su=0.f, tv=0.f, pa=0.f;
    #pragma unroll
    for (int d=0; d<16; ++d){
      float xa = v[d];
      su = fmaf(xa, sUV[q*16+d], su);
      tv = fmaf(xa, sUV[64+q*16+d], tv);
      pa += fabsf(xa);
    }
    su += __shfl_xor(su,1); su += __shfl_xor(su,2);
    tv += __shfl_xor(tv,1); tv += __shfl_xor(tv,2);
    pa += __shfl_xor(pa,1); pa += __shfl_xor(pa,2);
    if (q == 0){
      bool pad = (pa != 0.f);
      st[(size_t)b*L_SEQ + l0 + r]          = pad ? (su + sUV[128]) : -1e38f;
      st[(size_t)(B_TOT+b)*L_SEQ + l0 + r]  = pad ? tv : -1e38f;
    }
  }

  int w = tid >> 6, lane = tid & 63, lm = lane & 15, quad = lane >> 4;
  bf16x8 Ah0 = *(const bf16x8*)&sh[w*16+lm][quad*8];
  bf16x8 Ah1 = *(const bf16x8*)&sh[w*16+lm][32 + quad*8];
  bf16x8 Al0 = *(const bf16x8*)&sl[w*16+lm][quad*8];
  bf16x8 Al1 = *(const bf16x8*)&sl[w*16+lm][32 + quad*8];
  #pragma unroll
  for (int ct=0; ct<4; ++ct){
    const u16* mth = MtH + (ct*16+lm)*64 + quad*8;
    const u16* mtl = MtL + (ct*16+lm)*64 + quad*8;
    bf16x8 Bh0 = *(const bf16x8*)(mth);
    bf16x8 Bh1 = *(const bf16x8*)(mth + 32);
    bf16x8 Bl0 = *(const bf16x8*)(mtl);
    bf16x8 Bl1 = *(const bf16x8*)(mtl + 32);
    f32x4 a1 = {0.f,0.f,0.f,0.f}, a2 = {0.f,0.f,0.f,0.f};
    a1 = __builtin_amdgcn_mfma_f32_16x16x32_bf16(Ah0, Bh0, a1, 0,0,0);
    a2 = __builtin_amdgcn_mfma_f32_16x16x32_bf16(Ah1, Bh1, a2, 0,0,0);
    a1 = __builtin_amdgcn_mfma_f32_16x16x32_bf16(Al0, Bh0, a1, 0,0,0);
    a2 = __builtin_amdgcn_mfma_f32_16x16x32_bf16(Al1, Bh1, a2, 0,0,0);
    a1 = __builtin_amdgcn_mfma_f32_16x16x32_bf16(Ah0, Bl0, a1, 0,0,0);
    a2 = __builtin_amdgcn_mfma_f32_16x16x32_bf16(Ah1, Bl1, a2, 0,0,0);
    #pragma unroll
    for (int rg=0; rg<4; ++rg){
      float vy = a1[rg] + a2[rg];
      u16 hh = f2bf(vy); float hf = __uint_as_float(((u32)hh)<<16);
      u16 ll = f2bf(vy - hf);
      sh[w*16 + quad*4 + rg][ct*16 + lm] = hh;
      sl[w*16 + quad*4 + rg][ct*16 + lm] = ll;
    }
  }
  {
    size_t yo = (size_t)(g0 + r)*D_IN + q*16;
    *(uint4*)(yh + yo)     = *(uint4*)&sh[r][q*16];
    *(uint4*)(yh + yo + 8) = *(uint4*)&sh[r][q*16+8];
    *(uint4*)(yl + yo)     = *(uint4*)&sl[r][q*16];
    *(uint4*)(yl + yo + 8) = *(uint4*)&sl[r][q*16+8];
  }
}

// ---------- FALLBACK K2: k_score ----------
__global__ __launch_bounds__(256) void k_score(
    const u16* __restrict__ xh, const u16* __restrict__ xl,
    const u16* __restrict__ yh, const u16* __restrict__ yl,
    const float* __restrict__ st,
    u64* __restrict__ cand, int* __restrict__ cand_n, u32* __restrict__ uthr)
{
  int tid = threadIdx.x;
  int lin = blockIdx.x;
  int b    = ((lin >> 6) << 3) | (lin & 7);
  int tile = (lin >> 3) & 7;
  int cb = tile & 1, rb = tile >> 1;
  int r0 = rb*64, j0 = cb*128;
  int w = tid >> 6, lane = tid & 63, lm = lane & 15, quad = lane >> 4;

  size_t rowA = ((size_t)b*L_SEQ + r0 + w*16 + lm)*D_IN;
  bf16x8 A_h0 = *(const bf16x8*)(yh + rowA + quad*8);
  bf16x8 A_h1 = *(const bf16x8*)(yh + rowA + 32 + quad*8);
  bf16x8 A_l0 = *(const bf16x8*)(yl + rowA + quad*8);
  bf16x8 A_l1 = *(const bf16x8*)(yl + rowA + 32 + quad*8);

  float4 s4 = *(const float4*)(st + (size_t)b*L_SEQ + r0 + w*16 + quad*4);
  float sr[4] = {s4.x, s4.y, s4.z, s4.w};
  float tc[8];
  #pragma unroll
  for (int ct=0;ct<8;++ct)
    tc[ct] = st[(size_t)(B_TOT + b)*L_SEQ + j0 + ct*16 + lm];

  u32 kv[32];
  #pragma unroll
  for (int ct=0; ct<8; ++ct){
    size_t rowB = ((size_t)b*L_SEQ + j0 + ct*16 + lm)*D_IN;
    bf16x8 B_h0 = *(const bf16x8*)(xh + rowB + quad*8);
    bf16x8 B_h1 = *(const bf16x8*)(xh + rowB + 32 + quad*8);
    bf16x8 B_l0 = *(const bf16x8*)(xl + rowB + quad*8);
    bf16x8 B_l1 = *(const bf16x8*)(xl + rowB + 32 + quad*8);
    f32x4 a1 = {0.f,0.f,0.f,0.f}, a2 = {0.f,0.f,0.f,0.f};
    a1 = __builtin_amdgcn_mfma_f32_16x16x32_bf16(A_h0, B_h0, a1, 0,0,0);
    a2 = __builtin_amdgcn_mfma_f32_16x16x32_bf16(A_h1, B_h1, a2, 0,0,0);
    a1 = __builtin_amdgcn_mfma_f32_16x16x32_bf16(A_l0, B_h0, a1, 0,0,0);
    a2 = __builtin_amdgcn_mfma_f32_16x16x32_bf16(A_l1, B_h1, a2, 0,0,0);
    a1 = __builtin_amdgcn_mfma_f32_16x16x32_bf16(A_h0, B_l0, a1, 0,0,0);
    a2 = __builtin_amdgcn_mfma_f32_16x16x32_bf16(A_h1, B_l1, a2, 0,0,0);
    #pragma unroll
    for (int r=0;r<4;++r)
      kv[ct*4 + r] = sortKey(a1[r] + a2[r] + sr[r] + tc[ct]);
  }

  u32 T = 0;
  for (int bit=15; bit>=0; --bit){
    u32 th2 = (T | (1u<<bit)) << 16;
    int c = 0;
    #pragma unroll
    for (int i=0;i<32;++i)
      c += (int)__popcll(__ballot(kv[i] >= th2));
    if (c >= TOPK){
      T |= (1u<<bit);
      if (c <= CAP) break;
    }
  }
  u32 thr = T << 16;

  u32 hm = 0;
  #pragma unroll
  for (int i=0;i<32;++i) hm |= (kv[i] >= thr ? 1u : 0u) << i;
  int myc = __popc(hm);
  int pre = myc;
  #pragma unroll
  for (int off=1; off<64; off<<=1){
    int n = __shfl_up(pre, off);
    if (lane >= off) pre += n;
  }
  int total = __shfl(pre, 63);
  int pos = pre - myc;
  int wt = tile*4 + w;
  size_t base = ((size_t)b*NWT + wt)*CAP;
  if (lane == 0){
    cand_n[b*NWT + wt] = (total < CAP) ? total : CAP;
    uthr[b*NWT + wt] = thr;
  }
  while (hm){
    int i = __ffs(hm) - 1; hm &= hm - 1;
    if (pos < CAP){
      int r = i & 3, ct = i >> 2;
      int flat = (r0 + w*16 + quad*4 + r)*L_SEQ + (j0 + ct*16 + lm);
      cand[base + pos] = ((u64)kv[i] << 32) | (u32)flat;
    }
    ++pos;
  }
}

// ---------- K3: two-stage ballot merge -> exact top-128 + softmax ----------
// LB trick: any candidate threshold <= max(per-unit thr) provably has count >= TOPK.
// Kept as a SEPARATE 256-thread kernel (rounds 7/9: fusing serializes it at low
// occupancy; standalone, small LDS lets many blocks/CU hide scattered cand reads).
// NEW: cand load as 10 unconditional 16B uint4 loads/lane (was 20 predicated 8B) --
// CAP even => pairs never straddle unit boundaries; garbage beyond cand_n is masked
// post-load to the identical key=0/idx-sentinel values the predicated path produced.
__global__ __launch_bounds__(256) void k_merge(
    const u64* __restrict__ cand, const int* __restrict__ cand_n, const u32* __restrict__ uthr,
    int* __restrict__ selidx, float* __restrict__ selw)
{
  const int SL   = NWT/4;           // 8 slots per wave
  const int NSW  = SL*CAP/64;       // 20 keys per lane
  const int WCAP = 192;
  __shared__ u64 wbuf[4][WCAP];
  __shared__ int wcnt[4];
  __shared__ int scnt[NWT];
  __shared__ u32 wT[4];
  __shared__ int cm, eqc;
  __shared__ int eqi[256];
  __shared__ float sv[TOPK]; __shared__ int si[TOPK];
  __shared__ float fred[8];
  int b = blockIdx.x, tid = threadIdx.x;
  int w = tid >> 6, lane = tid & 63;
  if (tid < NWT) scnt[tid] = cand_n[b*NWT + tid];
  if (tid == 0){ cm = 0; eqc = 0; }
  __syncthreads();

  u32 key[NSW]; int idx[NSW];
  size_t bb = (size_t)b*NWT*CAP + (size_t)(w*SL)*CAP;
  #pragma unroll
  for (int s=0;s<NSW/2;++s){
    int e = 2*lane + 128*s;              // even; pair stays within one unit (CAP even)
    uint4 qv = *(const uint4*)(cand + bb + e);   // 16B aligned: (bb+e) even
    int slot = e / CAP, p = e - slot*CAP;
    int cc = scnt[w*SL + slot];
    bool ok0 = p < cc, ok1 = (p+1) < cc;
    key[2*s]   = ok0 ? qv.y : 0u;
    idx[2*s]   = ok0 ? (int)qv.x : 0x7fffffff;
    key[2*s+1] = ok1 ? qv.w : 0u;
    idx[2*s+1] = ok1 ? (int)qv.z : 0x7fffffff;
  }

  // wave lower bound = max over this wave's 8 unit thresholds
  u32 lb = uthr[b*NWT + w*SL + (lane & 7)];
  #pragma unroll
  for (int off=1; off<8; off<<=1){
    u32 o = (u32)__shfl_xor((int)lb, off);
    lb = lb > o ? lb : o;
  }

  u32 T = 0;
  for (int bit=31; bit>=0; --bit){
    u32 c2 = T | (1u<<bit);
    if (c2 <= lb){ T = c2; continue; }   // provable accept, no count
    int c = 0;
    #pragma unroll
    for (int s=0;s<NSW;++s) c += (int)__popcll(__ballot(key[s] >= c2));
    if (c >= TOPK){
      T = c2;
      if (c <= WCAP) break;
    }
  }
  if (lane == 0) wT[w] = T;
  {
    int myc = 0;
    #pragma unroll
    for (int s=0;s<NSW;++s) myc += (key[s] >= T) ? 1 : 0;
    int pre = myc;
    #pragma unroll
    for (int off=1; off<64; off<<=1){
      int n = __shfl_up(pre, off);
      if (lane >= off) pre += n;
    }
    int total = __shfl(pre, 63);
    int pos = pre - myc;
    if (lane == 0) wcnt[w] = (total < WCAP) ? total : WCAP;
    #pragma unroll
    for (int s=0;s<NSW;++s){
      if (key[s] >= T){
        if (pos < WCAP) wbuf[w][pos] = ((u64)key[s] << 32) | (u32)idx[s];
        ++pos;
      }
    }
  }
  __syncthreads();

  if (w == 0){
    const int NS2 = 4*WCAP/64;   // 12
    u32 k2[NS2]; int i2[NS2];
    #pragma unroll
    for (int s=0;s<NS2;++s){
      int e = lane + 64*s;
      int slot = e / WCAP, p = e - slot*WCAP;
      bool ok = p < wcnt[slot];
      u64 v = ok ? wbuf[slot][p] : 0ull;
      k2[s] = (u32)(v >> 32);
      i2[s] = ok ? (int)(u32)v : 0x7fffffff;
    }
    u32 lb2 = wT[0];
    lb2 = lb2 > wT[1] ? lb2 : wT[1];
    lb2 = lb2 > wT[2] ? lb2 : wT[2];
    lb2 = lb2 > wT[3] ? lb2 : wT[3];
    u32 T2 = 0;
    for (int bit=31; bit>=0; --bit){
      u32 c2 = T2 | (1u<<bit);
      if (c2 <= lb2){ T2 = c2; continue; }   // provable accept, exactness preserved
      int c = 0;
      #pragma unroll
      for (int s=0;s<NS2;++s) c += (int)__popcll(__ballot(k2[s] >= c2));
      if (c >= TOPK) T2 = c2;
    }
    int m = 0;
    #pragma unroll
    for (int s=0;s<NS2;++s) m += (int)__popcll(__ballot(k2[s] > T2));
    #pragma unroll
    for (int s=0;s<NS2;++s){
      if (k2[s] > T2){
        int p = atomicAdd(&cm, 1);
        sv[p] = unKey(k2[s]) * 0.0625f; si[p] = i2[s];
      } else if (k2[s] == T2 && i2[s] != 0x7fffffff){
        int q = atomicAdd(&eqc, 1);
        if (q < 256) eqi[q] = i2[s];
      }
    }
    if (lane == 0){
      int need = TOPK - m;
      int n = eqc < 256 ? eqc : 256;
      float tv = unKey(T2) * 0.0625f;
      for (int s2=0; s2<need; ++s2){
        int bi = s2;
        for (int j=s2+1;j<n;++j) if (eqi[j] < eqi[bi]) bi = j;
        int t2 = eqi[s2]; eqi[s2] = eqi[bi]; eqi[bi] = t2;
        sv[m+s2] = tv; si[m+s2] = eqi[s2];
      }
    }
  }
  __syncthreads();

  float v = (tid < TOPK) ? sv[tid] : -3.4e38f;
  float mx = v;
  #pragma unroll
  for (int off=1; off<64; off<<=1) mx = fmaxf(mx, __shfl_xor(mx, off));
  if ((tid&63)==0) fred[tid>>6] = mx;
  __syncthreads();
  mx = fmaxf(fred[0], fred[1]);
  float e = (tid < TOPK) ? expf(v - mx) : 0.f;
  float s = e;
  #pragma unroll
  for (int off=1; off<64; off<<=1) s += __shfl_xor(s, off);
  if ((tid&63)==0) fred[4 + (tid>>6)] = s;
  __syncthreads();
  s = fred[4] + fred[5];
  if (tid < TOPK){
    selw[(size_t)b*TOPK + tid]   = e / s;
    selidx[(size_t)b*TOPK + tid] = si[tid];
  }
}

// ---------- K4: gather + split-bf16 MFMA MLP1 + pooling + rho (512-thread / 8-wave) ----------
__global__ __launch_bounds__(512) void k_mlp(
    const float* __restrict__ x, const int* __restrict__ selidx, const float* __restrict__ selw,
    const u16* __restrict__ xiH, const u16* __restrict__ xiL,
    const u16* __restrict__ phiH, const u16* __restrict__ phiL,
    const float* __restrict__ phi_b1, const float* __restrict__ phi_w2, const float* __restrict__ phi_b2,
    const float* __restrict__ xi_b1,  const float* __restrict__ xi_w2,  const float* __restrict__ xi_b2,
    const float* __restrict__ rho_w1, const float* __restrict__ rho_b1,
    const float* __restrict__ rho_w2, const float* __restrict__ rho_b2,
    float* __restrict__ out)
{
  __shared__ __align__(16) u16 AFh[8][4][64][8];
  __shared__ __align__(16) u16 AFl[8][4][64][8];
  __shared__ int   sidx[TOPK];
  __shared__ float swp[TOPK], swd[TOPK];
  __shared__ float gpL[256], gsL[256];
  __shared__ float pooled[256], t1[256];
  __shared__ float pp[512];
  __shared__ float wsums[2];
  int b = blockIdx.x, tid = threadIdx.x;
  int w = tid >> 6, lane = tid & 63;

  if (tid < TOPK){
    int fl = selidx[(size_t)b*TOPK + tid];
    sidx[tid] = fl;
    float wv = selw[(size_t)b*TOPK + tid];
    bool dg = ((fl>>8) == (fl&255));
    swp[tid] = dg ? 0.f : wv;
    swd[tid] = dg ? wv  : 0.f;
  }
  __syncthreads();

  // wsums via 2 wave reductions (parallel with gather on other waves)
  if (w == 0){
    float a = swp[lane] + swp[64 + lane];
    #pragma unroll
    for (int off=1; off<64; off<<=1) a += __shfl_xor(a, off);
    if (lane == 0) wsums[0] = a;
  } else if (w == 1){
    float a = swd[lane] + swd[64 + lane];
    #pragma unroll
    for (int off=1; off<64; off<<=1) a += __shfl_xor(a, off);
    if (lane == 0) wsums[1] = a;
  }

  // gather: thread = (m, qq); qq selects 32 of the 128 concat dims
  {
    int m = tid >> 2, qq = tid & 3;
    int fl = sidx[m];
    int rc = (qq < 2) ? (fl >> 8) : (fl & 255);
    const float* src = x + ((size_t)b*L_SEQ + rc)*D_IN + (qq & 1)*32;
    int kt = m >> 4, l16 = m & 15;
    #pragma unroll
    for (int g=0; g<4; ++g){
      float v[8];
      *(float4*)&v[0] = *(const float4*)(src + g*8);
      *(float4*)&v[4] = *(const float4*)(src + g*8 + 4);
      u32 hp[4], lp[4];
      cvt8(v, hp, lp);
      *(uint4*)&AFh[kt][qq][l16 + 16*g][0] = make_uint4(hp[0],hp[1],hp[2],hp[3]);
      *(uint4*)&AFl[kt][qq][l16 + 16*g][0] = make_uint4(lp[0],lp[1],lp[2],lp[3]);
    }
  }
  __syncthreads();

  int lm = lane & 15, quad = lane >> 4;

  #pragma unroll
  for (int hi2=0; hi2<2; ++hi2){
    int ht = w + 8*hi2;
    int h  = ht*16 + lm;
    bf16x8 BXh[4], BXl[4], BPh[2], BPl[2];
    #pragma unroll
    for (int c=0;c<4;++c){
      BXh[c] = *(const bf16x8*)(xiH + h*128 + c*32 + quad*8);
      BXl[c] = *(const bf16x8*)(xiL + h*128 + c*32 + quad*8);
    }
    #pragma unroll
    for (int c=0;c<2;++c){
      BPh[c] = *(const bf16x8*)(phiH + h*64 + c*32 + quad*8);
      BPl[c] = *(const bf16x8*)(phiL + h*64 + c*32 + quad*8);
    }
    float bxi = xi_b1[h], bph = phi_b1[h];
    float gp = 0.f, gs = 0.f;
    for (int kt=0; kt<8; ++kt){
      bf16x8 Ah_[4], Al_[4];
      #pragma unroll
      for (int c=0;c<4;++c){
        Ah_[c] = *(const bf16x8*)&AFh[kt][c][lane][0];
        Al_[c] = *(const bf16x8*)&AFl[kt][c][lane][0];
      }
      f32x4 cx = {0.f,0.f,0.f,0.f}, cp = {0.f,0.f,0.f,0.f};
      #pragma unroll
      for (int c=0;c<4;++c){
        cx = __builtin_amdgcn_mfma_f32_16x16x32_bf16(Ah_[c], BXh[c], cx, 0,0,0);
        cx = __builtin_amdgcn_mfma_f32_16x16x32_bf16(Al_[c], BXh[c], cx, 0,0,0);
        cx = __builtin_amdgcn_mfma_f32_16x16x32_bf16(Ah_[c], BXl[c], cx, 0,0,0);
      }
      #pragma unroll
      for (int c=0;c<2;++c){
        cp = __builtin_amdgcn_mfma_f32_16x16x32_bf16(Ah_[c], BPh[c], cp, 0,0,0);
        cp = __builtin_amdgcn_mfma_f32_16x16x32_bf16(Al_[c], BPh[c], cp, 0,0,0);
        cp = __builtin_amdgcn_mfma_f32_16x16x32_bf16(Ah_[c], BPl[c], cp, 0,0,0);
      }
      #pragma unroll
      for (int r=0;r<4;++r){
        int kk = kt*16 + quad*4 + r;
        gp = fmaf(swp[kk], fmaxf(cx[r] + bxi, 0.f), gp);
        gs = fmaf(swd[kk], fmaxf(cp[r] + bph, 0.f), gs);
      }
    }
    gp += __shfl_xor(gp, 16); gp += __shfl_xor(gp, 32);
    gs += __shfl_xor(gs, 16); gs += __shfl_xor(gs, 32);
    if (quad == 0){ gpL[h] = gp; gsL[h] = gs; }
  }
  __syncthreads();

  // pooled: 2-way split over d
  {
    int h = tid & 255, half = tid >> 8;
    float wsp = wsums[0], wss = wsums[1];
    float po = (half == 0) ? (wsp*xi_b2[h] + wss*phi_b2[h]) : 0.f;
    int dd0 = half*128;
    for (int d=dd0; d<dd0+128; ++d){
      po = fmaf(gpL[d], xi_w2[d*HIDN + h], po);
      po = fmaf(gsL[d], phi_w2[d*HIDN + h], po);
    }
    pp[half*256 + h] = po;
  }
  __syncthreads();
  if (tid < 256) pooled[tid] = pp[tid] + pp[256 + tid];
  __syncthreads();
  // t1: 2-way split over d
  {
    int h = tid & 255, half = tid >> 8;
    float a = (half == 0) ? rho_b1[h] : 0.f;
    int dd0 = half*128;
    for (int d=dd0; d<dd0+128; ++d) a = fmaf(pooled[d], rho_w1[d*HIDN + h], a);
    pp[half*256 + h] = a;
  }
  __syncthreads();
  if (tid < 256) t1[tid] = fmaxf(pp[tid] + pp[256 + tid], 0.f);
  __syncthreads();
  // out: 4-way split over d
  {
    int h = tid & 127, part = tid >> 7;
    float o = (part == 0) ? rho_b2[h] : 0.f;
    int dd0 = part*64;
    for (int d=dd0; d<dd0+64; ++d) o = fmaf(t1[d], rho_w2[d*128 + h], o);
    pp[part*128 + h] = o;
  }
  __syncthreads();
  if (tid < 128)
    out[(size_t)b*128 + tid] = pp[tid] + pp[128+tid] + pp[256+tid] + pp[384+tid];
}

// ---------- host ----------
extern "C" void kernel_launch(void* const* d_in, const int* in_sizes, int n_in,
                              void* d_out, int out_size, void* d_ws, size_t ws_size,
                              hipStream_t stream)
{
  (void)in_sizes; (void)n_in; (void)out_size; (void)ws_size;
  const float* x      = (const float*)d_in[0];
  const float* Wq     = (const float*)d_in[1];
  const float* bq     = (const float*)d_in[2];
  const float* Wk     = (const float*)d_in[3];
  const float* bk     = (const float*)d_in[4];
  const float* phi_w1 = (const float*)d_in[5];
  const float* phi_b1 = (const float*)d_in[6];
  const float* phi_w2 = (const float*)d_in[7];
  const float* phi_b2 = (const float*)d_in[8];
  const float* xi_w1  = (const float*)d_in[9];
  const float* xi_b1  = (const float*)d_in[10];
  const float* xi_w2  = (const float*)d_in[11];
  const float* xi_b2  = (const float*)d_in[12];
  const float* rho_w1 = (const float*)d_in[13];
  const float* rho_b1 = (const float*)d_in[14];
  const float* rho_w2 = (const float*)d_in[15];
  const float* rho_b2 = (const float*)d_in[16];
  float* out = (float*)d_out;

  const size_t NX = (size_t)B_TOT*L_SEQ*D_IN;      // 8,388,608
  float* uvc    = (float*)d_ws;                    // 256
  float* st     = uvc + 256;                       // 2*512*256
  float* selw   = st + (size_t)2*B_TOT*L_SEQ;      // 512*128
  int*   selidx = (int*)(selw + (size_t)B_TOT*TOPK);
  int*   cand_n = selidx + (size_t)B_TOT*TOPK;     // 512*32
  u32*   uthr   = (u32*)(cand_n + (size_t)B_TOT*NWT); // 512*32
  u64*   cand   = (u64*)(uthr + (size_t)B_TOT*NWT);
  u16*   MtH    = (u16*)(cand + (size_t)B_TOT*NWT*CAP);
  u16*   MtL    = MtH + 64*64;
  u16*   xiH    = MtL + 64*64;
  u16*   xiL    = xiH + 256*128;
  u16*   phiH   = xiL + 256*128;
  u16*   phiL   = phiH + 256*64;
  u16*   xh     = phiL + 256*64;
  u16*   xl     = xh + NX;
  u16*   yh     = xl + NX;
  u16*   yl     = yh + NX;

  // deterministic per-device check (same result every call -> graph-safe)
  hipError_t aerr = hipFuncSetAttribute((const void*)k_fused,
                      hipFuncAttributeMaxDynamicSharedMemorySize, FLDS);

  k_wprep<<<dim3(256),  dim3(256), 0, stream>>>(Wq, bq, Wk, bk, xi_w1, phi_w1,
                                                MtH, MtL, uvc, xiH, xiL, phiH, phiL);
  if (aerr == hipSuccess){
    k_fused<<<dim3(B_TOT), dim3(1024), FLDS, stream>>>(x, MtH, MtL, uvc, cand, cand_n, uthr);
  } else {
    k_pre  <<<dim3(2048), dim3(256), 0, stream>>>(x, MtH, MtL, uvc, xh, xl, yh, yl, st);
    k_score<<<dim3(4096), dim3(256), 0, stream>>>(xh, xl, yh, yl, st, cand, cand_n, uthr);
  }
  k_merge<<<dim3(B_TOT), dim3(256), 0, stream>>>(cand, cand_n, uthr, selidx, selw);
  k_mlp  <<<dim3(B_TOT), dim3(512), 0, stream>>>(x, selidx, selw,
            xiH, xiL, phiH, phiL,
            phi_b1, phi_w2, phi_b2,
            xi_b1, xi_w2, xi_b2,
            rho_w1, rho_b1, rho_w2, rho_b2, out);
}

// Round 15
// 226.974 us; speedup vs baseline: 1.0690x; 1.0210x over previous
//
#include <hip/hip_runtime.h>

typedef unsigned short u16;
typedef unsigned int   u32;
typedef unsigned char  u8;
typedef unsigned long long u64;

#define B_TOT 512
#define L_SEQ 256
#define D_IN  64
#define HIDN  256
#define TOPK  128
#define CAP   144              // candidate cap per unit (even, mult of 16: u64 pairs never straddle units; NSW=18)
#define NWT   32               // units per batch
#define FLDS  76304            // fused dynamic LDS bytes (XH/XL + STS/STT/SUV; no Y bounce)

typedef float  f32x4  __attribute__((ext_vector_type(4)));
typedef __bf16 bf16x8 __attribute__((ext_vector_type(8)));

// ---------- helpers ----------
__device__ __forceinline__ u16 f2bf(float f){
  u32 u = __float_as_uint(f);
  u32 r = u + 0x7fffu + ((u>>16)&1u);   // RNE
  return (u16)(r>>16);
}
__device__ __forceinline__ u32 sortKey(float f){
  u32 b = __float_as_uint(f);
  return (b & 0x80000000u) ? ~b : (b | 0x80000000u);
}
__device__ __forceinline__ float unKey(u32 u){
  u32 b = (u & 0x80000000u) ? (u & 0x7fffffffu) : ~u;
  return __uint_as_float(b);
}
__device__ __forceinline__ void cvt8(const float* v, u32* hp, u32* lp){
  #pragma unroll
  for (int i=0;i<4;++i){
    float v0 = v[2*i], v1 = v[2*i+1];
    u16 h0 = f2bf(v0); float h0f = __uint_as_float(((u32)h0)<<16); u16 l0 = f2bf(v0 - h0f);
    u16 h1 = f2bf(v1); float h1f = __uint_as_float(((u32)h1)<<16); u16 l1 = f2bf(v1 - h1f);
    hp[i] = (u32)h0 | ((u32)h1<<16);
    lp[i] = (u32)l0 | ((u32)l1<<16);
  }
}

// ---------- K0: fused weight prep (uvc via wave reductions, no serial tails) ----------
__global__ __launch_bounds__(256) void k_wprep(
    const float* __restrict__ Wq, const float* __restrict__ bq,
    const float* __restrict__ Wk, const float* __restrict__ bk,
    const float* __restrict__ xi_w1, const float* __restrict__ phi_w1,
    u16* __restrict__ MtH, u16* __restrict__ MtL, float* __restrict__ uvc,
    u16* __restrict__ xiH, u16* __restrict__ xiL,
    u16* __restrict__ phiH, u16* __restrict__ phiL)
{
  int bid = blockIdx.x, tid = threadIdx.x;
  if (bid < 64){
    __shared__ float wq[HIDN];
    __shared__ float part[256];
    int a = bid;
    wq[tid] = Wq[a*HIDN + tid];
    __syncthreads();
    int bcol = tid & 63, q = tid >> 6;
    float s = 0.f;
    for (int h = q*64; h < q*64 + 64; ++h)
      s = fmaf(wq[h], Wk[bcol*HIDN + h], s);
    part[tid] = s;
    __syncthreads();
    if (tid < 64){
      float mv = part[tid] + part[64+tid] + part[128+tid] + part[192+tid];
      u16 hh = f2bf(mv); float hf = __uint_as_float(((u32)hh)<<16);
      u16 ll = f2bf(mv - hf);
      MtH[tid*64 + a] = hh;          // Mt[c][a] = M[a][c]
      MtL[tid*64 + a] = ll;
    }
    // uvc via per-wave shuffle reductions (4 elems/lane)
    int wv = tid >> 6, ln = tid & 63;
    if (wv == 0){
      float s2 = 0.f;
      #pragma unroll
      for (int i=0;i<4;++i){ int h = ln*4+i; s2 = fmaf(wq[h], bk[h], s2); }
      #pragma unroll
      for (int off=1; off<64; off<<=1) s2 += __shfl_xor(s2, off);
      if (ln == 0) uvc[a] = s2;
    } else if (wv == 1){
      float s2 = 0.f;
      #pragma unroll
      for (int i=0;i<4;++i){ int h = ln*4+i; s2 = fmaf(Wk[a*HIDN + h], bq[h], s2); }
      #pragma unroll
      for (int off=1; off<64; off<<=1) s2 += __shfl_xor(s2, off);
      if (ln == 0) uvc[64 + a] = s2;
    } else if (wv == 2 && a == 0){
      float s2 = 0.f;
      #pragma unroll
      for (int i=0;i<4;++i){ int h = ln*4+i; s2 = fmaf(bq[h], bk[h], s2); }
      #pragma unroll
      for (int off=1; off<64; off<<=1) s2 += __shfl_xor(s2, off);
      if (ln == 0) uvc[128] = s2;
    }
  } else {
    int t = (bid-64)*256 + tid;
    if (t < 256*128){
      int h = t >> 7, d = t & 127;
      float v = xi_w1[d*HIDN + h];
      u16 hh = f2bf(v); float hf = __uint_as_float(((u32)hh)<<16);
      u16 ll = f2bf(v - hf);
      xiH[h*128 + d] = hh; xiL[h*128 + d] = ll;
    } else {
      int t2 = t - 256*128;
      int h = t2 >> 6, d = t2 & 63;
      float v = phi_w1[d*HIDN + h];
      u16 hh = f2bf(v); float hf = __uint_as_float(((u32)hh)<<16);
      u16 ll = f2bf(v - hf);
      phiH[h*64 + d] = hh; phiL[h*64 + d] = ll;
    }
  }
}

// ---------- K-FUSED (1024 threads / 16 waves): split + y-MFMA + scoring + per-unit top-k ----------
// grid 512 (1 batch/block), ~76 KB LDS (no Y bounce; swapped-MFMA y with permuted Mt).
// Settled config (rounds 11/13/14): u64 single-stream cand, single-class fast path,
// popc-offset emission. VGPR hard-pinned at 64 for 1024-thread blocks (rounds 6/8/10).
__global__ void __launch_bounds__(1024) __attribute__((amdgpu_waves_per_eu(4,4))) k_fused(
    const float* __restrict__ x, const u16* __restrict__ MtH, const u16* __restrict__ MtL,
    const float* __restrict__ uvc,
    u64* __restrict__ cand, int* __restrict__ cand_n, u32* __restrict__ uthr)
{
  extern __shared__ __align__(16) u16 smem[];
  u16* XH = smem;                       // [256][72]
  u16* XL = XH + 256*72;                // [256][72]
  float* STS = (float*)(XL + 256*72);   // [256] s_i + c (pad -> -1e38)
  float* STT = STS + 256;               // [256] t_j   (pad -> -1e38)
  float* SUV = STT + 256;               // [129]

  int tid = threadIdx.x;
  int b = blockIdx.x;
  const float* xb = x + (size_t)b*(L_SEQ*D_IN);

  if (tid < 129) SUV[tid] = uvc[tid];

  // ---- Phase A: load + split x into LDS (quarter-row per thread) ----
  int ar = tid >> 2, aq = tid & 3;
  float v[16];
  {
    const float* src = xb + (size_t)ar*D_IN + aq*16;
    #pragma unroll
    for (int i=0;i<4;++i) *(float4*)&v[i*4] = *(const float4*)(src + i*4);
    u32 hpA[4],lpA[4],hpB[4],lpB[4];
    cvt8(&v[0], hpA, lpA); cvt8(&v[8], hpB, lpB);
    u16* dh = XH + ar*72 + aq*16;
    u16* dl = XL + ar*72 + aq*16;
    *(uint4*)(dh)     = make_uint4(hpA[0],hpA[1],hpA[2],hpA[3]);
    *(uint4*)(dh + 8) = make_uint4(hpB[0],hpB[1],hpB[2],hpB[3]);
    *(uint4*)(dl)     = make_uint4(lpA[0],lpA[1],lpA[2],lpA[3]);
    *(uint4*)(dl + 8) = make_uint4(lpB[0],lpB[1],lpB[2],lpB[3]);
  }
  __syncthreads();   // SUV + XH/XL visible

  // ---- s_i, t_j, pad (4-lane group reduction) ----
  {
    float su=0.f, tv=0.f, pa=0.f;
    #pragma unroll
    for (int d=0; d<16; ++d){
      float xa = v[d];
      su = fmaf(xa, SUV[aq*16+d], su);
      tv = fmaf(xa, SUV[64+aq*16+d], tv);
      pa += fabsf(xa);
    }
    su += __shfl_xor(su,1); su += __shfl_xor(su,2);
    tv += __shfl_xor(tv,1); tv += __shfl_xor(tv,2);
    pa += __shfl_xor(pa,1); pa += __shfl_xor(pa,2);
    if (aq == 0){
      bool pad = (pa != 0.f);
      STS[ar] = pad ? (su + SUV[128]) : -1e38f;
      STT[ar] = pad ? tv : -1e38f;
    }
  }
  __syncthreads();   // STS/STT visible

  int w = tid >> 6, lane = tid & 63, lm = lane & 15, quad = lane >> 4;
  int u  = w;               // one row-unit per wave: rows [16u, 16u+16)
  int r0 = u*16;

  // ---- y = x M directly into scoring A-frag layout (swapped MFMA, permuted Mt) ----
  bf16x8 Yh0, Yh1, Yl0, Yl1;
  {
    const u16* xh_ = XH + (r0+lm)*72;
    const u16* xl_ = XL + (r0+lm)*72;
    bf16x8 Xh0 = *(const bf16x8*)(xh_ + quad*8);
    bf16x8 Xh1 = *(const bf16x8*)(xh_ + 32 + quad*8);
    bf16x8 Xl0 = *(const bf16x8*)(xl_ + quad*8);
    bf16x8 Xl1 = *(const bf16x8*)(xl_ + 32 + quad*8);
    u32 yh[8], yl[8];     // packed col-pairs; slot = (ct>>1)*4 + (ct&1)*2 + pr
    #pragma unroll
    for (int ct=0; ct<4; ++ct){
      int srow = 8*(lm>>2) + 4*(ct&1) + (lm&3) + 32*(ct>>1);   // sigma(ct,lm)
      const u16* mth = MtH + srow*64 + quad*8;
      const u16* mtl = MtL + srow*64 + quad*8;
      bf16x8 Mh0 = *(const bf16x8*)(mth);
      bf16x8 Mh1 = *(const bf16x8*)(mth + 32);
      bf16x8 Ml0 = *(const bf16x8*)(mtl);
      bf16x8 Ml1 = *(const bf16x8*)(mtl + 32);
      f32x4 a1 = {0.f,0.f,0.f,0.f}, a2 = {0.f,0.f,0.f,0.f};
      a1 = __builtin_amdgcn_mfma_f32_16x16x32_bf16(Mh0, Xh0, a1, 0,0,0);
      a2 = __builtin_amdgcn_mfma_f32_16x16x32_bf16(Mh1, Xh1, a2, 0,0,0);
      a1 = __builtin_amdgcn_mfma_f32_16x16x32_bf16(Ml0, Xh0, a1, 0,0,0);
      a2 = __builtin_amdgcn_mfma_f32_16x16x32_bf16(Ml1, Xh1, a2, 0,0,0);
      a1 = __builtin_amdgcn_mfma_f32_16x16x32_bf16(Mh0, Xl0, a1, 0,0,0);
      a2 = __builtin_amdgcn_mfma_f32_16x16x32_bf16(Mh1, Xl1, a2, 0,0,0);
      #pragma unroll
      for (int pr=0; pr<2; ++pr){
        float v0 = a1[2*pr]   + a2[2*pr];
        float v1 = a1[2*pr+1] + a2[2*pr+1];
        u16 h0 = f2bf(v0); u16 h1 = f2bf(v1);
        u16 l0 = f2bf(v0 - __uint_as_float(((u32)h0)<<16));
        u16 l1 = f2bf(v1 - __uint_as_float(((u32)h1)<<16));
        int slot = (ct>>1)*4 + (ct&1)*2 + pr;
        yh[slot] = (u32)h0 | ((u32)h1<<16);
        yl[slot] = (u32)l0 | ((u32)l1<<16);
      }
    }
    uint4 t0 = make_uint4(yh[0],yh[1],yh[2],yh[3]);
    uint4 t1 = make_uint4(yh[4],yh[5],yh[6],yh[7]);
    uint4 t2 = make_uint4(yl[0],yl[1],yl[2],yl[3]);
    uint4 t3 = make_uint4(yl[4],yl[5],yl[6],yl[7]);
    Yh0 = *(const bf16x8*)&t0;
    Yh1 = *(const bf16x8*)&t1;
    Yl0 = *(const bf16x8*)&t2;
    Yl1 = *(const bf16x8*)&t3;
  }

  float sr[4];
  #pragma unroll
  for (int r=0;r<4;++r) sr[r] = STS[r0 + quad*4 + r];

  // ---- two column-halves: score 16x128, select, emit (kv[32] per lane) ----
  for (int ch=0; ch<2; ++ch){
    int j0 = ch*128;
    u32 kv[32];
    #pragma unroll
    for (int ct=0; ct<8; ++ct){
      const u16* bh = XH + (j0 + ct*16+lm)*72;
      const u16* bl = XL + (j0 + ct*16+lm)*72;
      bf16x8 Bh0 = *(const bf16x8*)(bh + quad*8);
      bf16x8 Bh1 = *(const bf16x8*)(bh + 32 + quad*8);
      bf16x8 Bl0 = *(const bf16x8*)(bl + quad*8);
      bf16x8 Bl1 = *(const bf16x8*)(bl + 32 + quad*8);
      f32x4 a1 = {0.f,0.f,0.f,0.f}, a2 = {0.f,0.f,0.f,0.f};
      a1 = __builtin_amdgcn_mfma_f32_16x16x32_bf16(Yh0, Bh0, a1, 0,0,0);
      a2 = __builtin_amdgcn_mfma_f32_16x16x32_bf16(Yh1, Bh1, a2, 0,0,0);
      a1 = __builtin_amdgcn_mfma_f32_16x16x32_bf16(Yl0, Bh0, a1, 0,0,0);
      a2 = __builtin_amdgcn_mfma_f32_16x16x32_bf16(Yl1, Bh1, a2, 0,0,0);
      a1 = __builtin_amdgcn_mfma_f32_16x16x32_bf16(Yh0, Bl0, a1, 0,0,0);
      a2 = __builtin_amdgcn_mfma_f32_16x16x32_bf16(Yh1, Bl1, a2, 0,0,0);
      float tc = STT[j0 + ct*16 + lm];
      #pragma unroll
      for (int r=0;r<4;++r)
        kv[ct*4 + r] = sortKey(a1[r] + a2[r] + sr[r] + tc);
    }

    // 16-bit-prefix threshold (top-128 of 2048), early-exit in [TOPK, CAP];
    // two independent popcount accumulators halve the serial SALU chain.
    u32 T = 0;
    int cfin = -1;                 // >=0 iff early-exit fired (count known <= CAP)
    for (int bit=15; bit>=0; --bit){
      u32 th2 = (T | (1u<<bit)) << 16;
      int c0 = 0, c1 = 0;
      #pragma unroll
      for (int i=0;i<32;i+=2){
        c0 += (int)__popcll(__ballot(kv[i]   >= th2));
        c1 += (int)__popcll(__ballot(kv[i+1] >= th2));
      }
      int c = c0 + c1;
      if (c >= TOPK){
        T |= (1u<<bit);
        if (c <= CAP){ cfin = c; break; }
      }
    }
    u32 thr = T << 16;

    int wt = u*2 + ch;
    size_t base = ((size_t)b*NWT + wt)*CAP;
    // hoisted emission row bases: flat = rb[r] + (i>>2)*16
    int rb0 = (r0 + quad*4 + 0)*L_SEQ + j0 + lm;
    int rb1 = rb0 + L_SEQ, rb2 = rb1 + L_SEQ, rb3 = rb2 + L_SEQ;

    if (cfin >= 0){
      // ---- fast path (dominant): everything >= thr fits; single mask + single scan ----
      u32 m = 0;
      #pragma unroll
      for (int i=0;i<32;++i) m |= (kv[i] >= thr ? 1u : 0u) << i;
      int n = __popc(m);
      int p = n;
      #pragma unroll
      for (int off=1; off<64; off<<=1){
        int a = __shfl_up(p, off); if (lane >= off) p += a;
      }
      int pos = p - n;
      if (lane == 0){
        cand_n[b*NWT + wt] = cfin;    // ballot count, wave-uniform, <= CAP
        uthr[b*NWT + wt] = thr;
      }
      #pragma unroll
      for (int i=0;i<32;++i){
        if ((m >> i) & 1u){
          int pp2 = pos + __popc(m & ((1u<<i)-1u));   // within-lane offset, no serial chain
          int flat = ((i&3)==0 ? rb0 : (i&3)==1 ? rb1 : (i&3)==2 ? rb2 : rb3) + (i>>2)*16;
          cand[base + pp2] = ((u64)kv[i] << 32) | (u32)flat;
        }
      }
    } else {
      // ---- rare fallback: count at final T may exceed CAP; two-class priority emission ----
      u32 up  = (T < 0xffffu) ? ((T+1u) << 16) : 0xffffffffu;
      u32 m1 = 0, m2 = 0;
      #pragma unroll
      for (int i=0;i<32;++i){
        bool ge = kv[i] >= thr;
        bool c1 = ge && (kv[i] >= up);
        m1 |= (c1 ? 1u : 0u) << i;
        m2 |= ((ge && !c1) ? 1u : 0u) << i;
      }
      int n1 = __popc(m1), n2 = __popc(m2);
      int p1 = n1, p2 = n2;
      #pragma unroll
      for (int off=1; off<64; off<<=1){
        int a = __shfl_up(p1, off); if (lane >= off) p1 += a;
        int c = __shfl_up(p2, off); if (lane >= off) p2 += c;
      }
      int tot1 = __shfl(p1, 63), tot2 = __shfl(p2, 63);
      int pos1 = p1 - n1;
      int pos2 = tot1 + (p2 - n2);
      int total = tot1 + tot2;
      if (lane == 0){
        cand_n[b*NWT + wt] = (total < CAP) ? total : CAP;
        uthr[b*NWT + wt] = thr;
      }
      int o1=0, o2=0;
      #pragma unroll
      for (int i=0;i<32;++i){
        bool c1 = (m1 >> i) & 1u, c2v = (m2 >> i) & 1u;
        if (c1 | c2v){
          int p = c1 ? (pos1 + o1) : (pos2 + o2);
          int flat = ((i&3)==0 ? rb0 : (i&3)==1 ? rb1 : (i&3)==2 ? rb2 : rb3) + (i>>2)*16;
          if (p < CAP) cand[base + p] = ((u64)kv[i] << 32) | (u32)flat;
        }
        o1 += c1; o2 += c2v;
      }
    }
  }
}

// ---------- FALLBACK K1: split x; st; y via MFMA ----------
__global__ __launch_bounds__(256) void k_pre(
    const float* __restrict__ x, const u16* __restrict__ MtH, const u16* __restrict__ MtL,
    const float* __restrict__ uvc,
    u16* __restrict__ xh, u16* __restrict__ xl,
    u16* __restrict__ yh, u16* __restrict__ yl,
    float* __restrict__ st)
{
  __shared__ __align__(16) u16 sh[64][72];
  __shared__ __align__(16) u16 sl[64][72];
  __shared__ float sUV[132];
  int tid = threadIdx.x;
  int g0 = blockIdx.x * 64;
  int b  = g0 >> 8, l0 = g0 & 255;
  int r = tid >> 2, q = tid & 3;

  if (tid < 129) sUV[tid] = uvc[tid];

  float v[16];
  {
    const float* xr = x + (size_t)(g0 + r)*D_IN + q*16;
    #pragma unroll
    for (int i=0;i<4;++i) *(float4*)&v[i*4] = *(const float4*)(xr + i*4);
  }
  {
    u32 hpA[4],lpA[4],hpB[4],lpB[4];
    cvt8(&v[0], hpA, lpA); cvt8(&v[8], hpB, lpB);
    size_t xo = (size_t)(g0 + r)*D_IN + q*16;
    *(uint4*)(xh + xo)     = make_uint4(hpA[0],hpA[1],hpA[2],hpA[3]);
    *(uint4*)(xh + xo + 8) = make_uint4(hpB[0],hpB[1],hpB[2],hpB[3]);
    *(uint4*)(xl + xo)     = make_uint4(lpA[0],lpA[1],lpA[2],lpA[3]);
    *(uint4*)(xl + xo + 8) = make_uint4(lpB[0],lpB[1],lpB[2],lpB[3]);
    *(uint4*)&sh[r][q*16]   = make_uint4(hpA[0],hpA[1],hpA[2],hpA[3]);
    *(uint4*)&sh[r][q*16+8] = make_uint4(hpB[0],hpB[1],hpB[2],hpB[3]);
    *(uint4*)&sl[r][q*16]   = make_uint4(lpA[0],lpA[1],lpA[2],lpA[3]);
    *(uint4*)&sl[r][q*16+8] = make_uint4(lpB[0],lpB[1],lpB[2],lpB[3]);
  }
  __syncthreads();

  {
    float su=0.f, tv=0.f, pa=0.f;
    #pragma unroll
    for (int d=0; d<16; ++d){
      float xa = v[d];
      su = fmaf(xa, sUV[q*16+d], su);
      tv = fmaf(xa, sUV[64+q*16+d], tv);
      pa += fabsf(xa);
    }
    su += __shfl_xor(su,1); su += __shfl_xor(su,2);
    tv += __shfl_xor(tv,1); tv += __shfl_xor(tv,2);
    pa += __shfl_xor(pa,1); pa += __shfl_xor(pa,2);
    if (q == 0){
      bool pad = (pa != 0.f);
      st[(size_t)b*L_SEQ + l0 + r]          = pad ? (su + sUV[128]) : -1e38f;
      st[(size_t)(B_TOT+b)*L_SEQ + l0 + r]  = pad ? tv : -1e38f;
    }
  }

  int w = tid >> 6, lane = tid & 63, lm = lane & 15, quad = lane >> 4;
  bf16x8 Ah0 = *(const bf16x8*)&sh[w*16+lm][quad*8];
  bf16x8 Ah1 = *(const bf16x8*)&sh[w*16+lm][32 + quad*8];
  bf16x8 Al0 = *(const bf16x8*)&sl[w*16+lm][quad*8];
  bf16x8 Al1 = *(const bf16x8*)&sl[w*16+lm][32 + quad*8];
  #pragma unroll
  for (int ct=0; ct<4; ++ct){
    const u16* mth = MtH + (ct*16+lm)*64 + quad*8;
    const u16* mtl = MtL + (ct*16+lm)*64 + quad*8;
    bf16x8 Bh0 = *(const bf16x8*)(mth);
    bf16x8 Bh1 = *(const bf16x8*)(mth + 32);
    bf16x8 Bl0 = *(const bf16x8*)(mtl);
    bf16x8 Bl1 = *(const bf16x8*)(mtl + 32);
    f32x4 a1 = {0.f,0.f,0.f,0.f}, a2 = {0.f,0.f,0.f,0.f};
    a1 = __builtin_amdgcn_mfma_f32_16x16x32_bf16(Ah0, Bh0, a1, 0,0,0);
    a2 = __builtin_amdgcn_mfma_f32_16x16x32_bf16(Ah1, Bh1, a2, 0,0,0);
    a1 = __builtin_amdgcn_mfma_f32_16x16x32_bf16(Al0, Bh0, a1, 0,0,0);
    a2 = __builtin_amdgcn_mfma_f32_16x16x32_bf16(Al1, Bh1, a2, 0,0,0);
    a1 = __builtin_amdgcn_mfma_f32_16x16x32_bf16(Ah0, Bl0, a1, 0,0,0);
    a2 = __builtin_amdgcn_mfma_f32_16x16x32_bf16(Ah1, Bl1, a2, 0,0,0);
    #pragma unroll
    for (int rg=0; rg<4; ++rg){
      float vy = a1[rg] + a2[rg];
      u16 hh = f2bf(vy); float hf = __uint_as_float(((u32)hh)<<16);
      u16 ll = f2bf(vy - hf);
      sh[w*16 + quad*4 + rg][ct*16 + lm] = hh;
      sl[w*16 + quad*4 + rg][ct*16 + lm] = ll;
    }
  }
  {
    size_t yo = (size_t)(g0 + r)*D_IN + q*16;
    *(uint4*)(yh + yo)     = *(uint4*)&sh[r][q*16];
    *(uint4*)(yh + yo + 8) = *(uint4*)&sh[r][q*16+8];
    *(uint4*)(yl + yo)     = *(uint4*)&sl[r][q*16];
    *(uint4*)(yl + yo + 8) = *(uint4*)&sl[r][q*16+8];
  }
}

// ---------- FALLBACK K2: k_score ----------
__global__ __launch_bounds__(256) void k_score(
    const u16* __restrict__ xh, const u16* __restrict__ xl,
    const u16* __restrict__ yh, const u16* __restrict__ yl,
    const float* __restrict__ st,
    u64* __restrict__ cand, int* __restrict__ cand_n, u32* __restrict__ uthr)
{
  int tid = threadIdx.x;
  int lin = blockIdx.x;
  int b    = ((lin >> 6) << 3) | (lin & 7);
  int tile = (lin >> 3) & 7;
  int cb = tile & 1, rb = tile >> 1;
  int r0 = rb*64, j0 = cb*128;
  int w = tid >> 6, lane = tid & 63, lm = lane & 15, quad = lane >> 4;

  size_t rowA = ((size_t)b*L_SEQ + r0 + w*16 + lm)*D_IN;
  bf16x8 A_h0 = *(const bf16x8*)(yh + rowA + quad*8);
  bf16x8 A_h1 = *(const bf16x8*)(yh + rowA + 32 + quad*8);
  bf16x8 A_l0 = *(const bf16x8*)(yl + rowA + quad*8);
  bf16x8 A_l1 = *(const bf16x8*)(yl + rowA + 32 + quad*8);

  float4 s4 = *(const float4*)(st + (size_t)b*L_SEQ + r0 + w*16 + quad*4);
  float sr[4] = {s4.x, s4.y, s4.z, s4.w};
  float tc[8];
  #pragma unroll
  for (int ct=0;ct<8;++ct)
    tc[ct] = st[(size_t)(B_TOT + b)*L_SEQ + j0 + ct*16 + lm];

  u32 kv[32];
  #pragma unroll
  for (int ct=0; ct<8; ++ct){
    size_t rowB = ((size_t)b*L_SEQ + j0 + ct*16 + lm)*D_IN;
    bf16x8 B_h0 = *(const bf16x8*)(xh + rowB + quad*8);
    bf16x8 B_h1 = *(const bf16x8*)(xh + rowB + 32 + quad*8);
    bf16x8 B_l0 = *(const bf16x8*)(xl + rowB + quad*8);
    bf16x8 B_l1 = *(const bf16x8*)(xl + rowB + 32 + quad*8);
    f32x4 a1 = {0.f,0.f,0.f,0.f}, a2 = {0.f,0.f,0.f,0.f};
    a1 = __builtin_amdgcn_mfma_f32_16x16x32_bf16(A_h0, B_h0, a1, 0,0,0);
    a2 = __builtin_amdgcn_mfma_f32_16x16x32_bf16(A_h1, B_h1, a2, 0,0,0);
    a1 = __builtin_amdgcn_mfma_f32_16x16x32_bf16(A_l0, B_h0, a1, 0,0,0);
    a2 = __builtin_amdgcn_mfma_f32_16x16x32_bf16(A_l1, B_h1, a2, 0,0,0);
    a1 = __builtin_amdgcn_mfma_f32_16x16x32_bf16(A_h0, B_l0, a1, 0,0,0);
    a2 = __builtin_amdgcn_mfma_f32_16x16x32_bf16(A_h1, B_l1, a2, 0,0,0);
    #pragma unroll
    for (int r=0;r<4;++r)
      kv[ct*4 + r] = sortKey(a1[r] + a2[r] + sr[r] + tc[ct]);
  }

  u32 T = 0;
  for (int bit=15; bit>=0; --bit){
    u32 th2 = (T | (1u<<bit)) << 16;
    int c = 0;
    #pragma unroll
    for (int i=0;i<32;++i)
      c += (int)__popcll(__ballot(kv[i] >= th2));
    if (c >= TOPK){
      T |= (1u<<bit);
      if (c <= CAP) break;
    }
  }
  u32 thr = T << 16;

  u32 hm = 0;
  #pragma unroll
  for (int i=0;i<32;++i) hm |= (kv[i] >= thr ? 1u : 0u) << i;
  int myc = __popc(hm);
  int pre = myc;
  #pragma unroll
  for (int off=1; off<64; off<<=1){
    int n = __shfl_up(pre, off);
    if (lane >= off) pre += n;
  }
  int total = __shfl(pre, 63);
  int pos = pre - myc;
  int wt = tile*4 + w;
  size_t base = ((size_t)b*NWT + wt)*CAP;
  if (lane == 0){
    cand_n[b*NWT + wt] = (total < CAP) ? total : CAP;
    uthr[b*NWT + wt] = thr;
  }
  while (hm){
    int i = __ffs(hm) - 1; hm &= hm - 1;
    if (pos < CAP){
      int r = i & 3, ct = i >> 2;
      int flat = (r0 + w*16 + quad*4 + r)*L_SEQ + (j0 + ct*16 + lm);
      cand[base + pos] = ((u64)kv[i] << 32) | (u32)flat;
    }
    ++pos;
  }
}

// ---------- K3: two-stage ballot merge -> exact top-128 + softmax ----------
// LB trick: any candidate threshold <= max(per-unit thr) provably has count >= TOPK.
// Kept as a SEPARATE 256-thread kernel (rounds 7/9: fusing serializes it at low
// occupancy). cand load as NSW/2=9 unconditional 16B uint4 loads/lane (round 14:
// -3.5 us); CAP even => pairs never straddle unit boundaries; garbage beyond cand_n
// is masked post-load to the identical key=0/idx-sentinel values.
__global__ __launch_bounds__(256) void k_merge(
    const u64* __restrict__ cand, const int* __restrict__ cand_n, const u32* __restrict__ uthr,
    int* __restrict__ selidx, float* __restrict__ selw)
{
  const int SL   = NWT/4;           // 8 slots per wave
  const int NSW  = SL*CAP/64;       // 18 keys per lane (CAP=144)
  const int WCAP = 192;
  __shared__ u64 wbuf[4][WCAP];
  __shared__ int wcnt[4];
  __shared__ int scnt[NWT];
  __shared__ u32 wT[4];
  __shared__ int cm, eqc;
  __shared__ int eqi[256];
  __shared__ float sv[TOPK]; __shared__ int si[TOPK];
  __shared__ float fred[8];
  int b = blockIdx.x, tid = threadIdx.x;
  int w = tid >> 6, lane = tid & 63;
  if (tid < NWT) scnt[tid] = cand_n[b*NWT + tid];
  if (tid == 0){ cm = 0; eqc = 0; }
  __syncthreads();

  u32 key[NSW]; int idx[NSW];
  size_t bb = (size_t)b*NWT*CAP + (size_t)(w*SL)*CAP;
  #pragma unroll
  for (int s=0;s<NSW/2;++s){
    int e = 2*lane + 128*s;              // even; pair stays within one unit (CAP even)
    uint4 qv = *(const uint4*)(cand + bb + e);   // 16B aligned: (bb+e) even
    int slot = e / CAP, p = e - slot*CAP;
    int cc = scnt[w*SL + slot];
    bool ok0 = p < cc, ok1 = (p+1) < cc;
    key[2*s]   = ok0 ? qv.y : 0u;
    idx[2*s]   = ok0 ? (int)qv.x : 0x7fffffff;
    key[2*s+1] = ok1 ? qv.w : 0u;
    idx[2*s+1] = ok1 ? (int)qv.z : 0x7fffffff;
  }

  // wave lower bound = max over this wave's 8 unit thresholds
  u32 lb = uthr[b*NWT + w*SL + (lane & 7)];
  #pragma unroll
  for (int off=1; off<8; off<<=1){
    u32 o = (u32)__shfl_xor((int)lb, off);
    lb = lb > o ? lb : o;
  }

  u32 T = 0;
  for (int bit=31; bit>=0; --bit){
    u32 c2 = T | (1u<<bit);
    if (c2 <= lb){ T = c2; continue; }   // provable accept, no count
    int c = 0;
    #pragma unroll
    for (int s=0;s<NSW;++s) c += (int)__popcll(__ballot(key[s] >= c2));
    if (c >= TOPK){
      T = c2;
      if (c <= WCAP) break;
    }
  }
  if (lane == 0) wT[w] = T;
  {
    int myc = 0;
    #pragma unroll
    for (int s=0;s<NSW;++s) myc += (key[s] >= T) ? 1 : 0;
    int pre = myc;
    #pragma unroll
    for (int off=1; off<64; off<<=1){
      int n = __shfl_up(pre, off);
      if (lane >= off) pre += n;
    }
    int total = __shfl(pre, 63);
    int pos = pre - myc;
    if (lane == 0) wcnt[w] = (total < WCAP) ? total : WCAP;
    #pragma unroll
    for (int s=0;s<NSW;++s){
      if (key[s] >= T){
        if (pos < WCAP) wbuf[w][pos] = ((u64)key[s] << 32) | (u32)idx[s];
        ++pos;
      }
    }
  }
  __syncthreads();

  if (w == 0){
    const int NS2 = 4*WCAP/64;   // 12
    u32 k2[NS2]; int i2[NS2];
    #pragma unroll
    for (int s=0;s<NS2;++s){
      int e = lane + 64*s;
      int slot = e / WCAP, p = e - slot*WCAP;
      bool ok = p < wcnt[slot];
      u64 v = ok ? wbuf[slot][p] : 0ull;
      k2[s] = (u32)(v >> 32);
      i2[s] = ok ? (int)(u32)v : 0x7fffffff;
    }
    u32 lb2 = wT[0];
    lb2 = lb2 > wT[1] ? lb2 : wT[1];
    lb2 = lb2 > wT[2] ? lb2 : wT[2];
    lb2 = lb2 > wT[3] ? lb2 : wT[3];
    u32 T2 = 0;
    for (int bit=31; bit>=0; --bit){
      u32 c2 = T2 | (1u<<bit);
      if (c2 <= lb2){ T2 = c2; continue; }   // provable accept, exactness preserved
      int c = 0;
      #pragma unroll
      for (int s=0;s<NS2;++s) c += (int)__popcll(__ballot(k2[s] >= c2));
      if (c >= TOPK) T2 = c2;
    }
    int m = 0;
    #pragma unroll
    for (int s=0;s<NS2;++s) m += (int)__popcll(__ballot(k2[s] > T2));
    #pragma unroll
    for (int s=0;s<NS2;++s){
      if (k2[s] > T2){
        int p = atomicAdd(&cm, 1);
        sv[p] = unKey(k2[s]) * 0.0625f; si[p] = i2[s];
      } else if (k2[s] == T2 && i2[s] != 0x7fffffff){
        int q = atomicAdd(&eqc, 1);
        if (q < 256) eqi[q] = i2[s];
      }
    }
    if (lane == 0){
      int need = TOPK - m;
      int n = eqc < 256 ? eqc : 256;
      float tv = unKey(T2) * 0.0625f;
      for (int s2=0; s2<need; ++s2){
        int bi = s2;
        for (int j=s2+1;j<n;++j) if (eqi[j] < eqi[bi]) bi = j;
        int t2 = eqi[s2]; eqi[s2] = eqi[bi]; eqi[bi] = t2;
        sv[m+s2] = tv; si[m+s2] = eqi[s2];
      }
    }
  }
  __syncthreads();

  float v = (tid < TOPK) ? sv[tid] : -3.4e38f;
  float mx = v;
  #pragma unroll
  for (int off=1; off<64; off<<=1) mx = fmaxf(mx, __shfl_xor(mx, off));
  if ((tid&63)==0) fred[tid>>6] = mx;
  __syncthreads();
  mx = fmaxf(fred[0], fred[1]);
  float e = (tid < TOPK) ? expf(v - mx) : 0.f;
  float s = e;
  #pragma unroll
  for (int off=1; off<64; off<<=1) s += __shfl_xor(s, off);
  if ((tid&63)==0) fred[4 + (tid>>6)] = s;
  __syncthreads();
  s = fred[4] + fred[5];
  if (tid < TOPK){
    selw[(size_t)b*TOPK + tid]   = e / s;
    selidx[(size_t)b*TOPK + tid] = si[tid];
  }
}

// ---------- K4: gather + split-bf16 MFMA MLP1 + pooling + rho (512-thread / 8-wave) ----------
// NEW: tail GEMVs use 4 (pooled/t1) / 2 (out) independent accumulators -- the prior
// single-accumulator fmaf chains (256/128/64 dependent ops at ~4cy each) were the
// serial floor; strict FP order prevents compiler reassociation, so split manually
// (reassociation delta ~1e-6, far below the bf16-dominated 0.0049 absmax).
__global__ __launch_bounds__(512) void k_mlp(
    const float* __restrict__ x, const int* __restrict__ selidx, const float* __restrict__ selw,
    const u16* __restrict__ xiH, const u16* __restrict__ xiL,
    const u16* __restrict__ phiH, const u16* __restrict__ phiL,
    const float* __restrict__ phi_b1, const float* __restrict__ phi_w2, const float* __restrict__ phi_b2,
    const float* __restrict__ xi_b1,  const float* __restrict__ xi_w2,  const float* __restrict__ xi_b2,
    const float* __restrict__ rho_w1, const float* __restrict__ rho_b1,
    const float* __restrict__ rho_w2, const float* __restrict__ rho_b2,
    float* __restrict__ out)
{
  __shared__ __align__(16) u16 AFh[8][4][64][8];
  __shared__ __align__(16) u16 AFl[8][4][64][8];
  __shared__ int   sidx[TOPK];
  __shared__ float swp[TOPK], swd[TOPK];
  __shared__ float gpL[256], gsL[256];
  __shared__ float pooled[256], t1[256];
  __shared__ float pp[512];
  __shared__ float wsums[2];
  int b = blockIdx.x, tid = threadIdx.x;
  int w = tid >> 6, lane = tid & 63;

  if (tid < TOPK){
    int fl = selidx[(size_t)b*TOPK + tid];
    sidx[tid] = fl;
    float wv = selw[(size_t)b*TOPK + tid];
    bool dg = ((fl>>8) == (fl&255));
    swp[tid] = dg ? 0.f : wv;
    swd[tid] = dg ? wv  : 0.f;
  }
  __syncthreads();

  // wsums via 2 wave reductions (parallel with gather on other waves)
  if (w == 0){
    float a = swp[lane] + swp[64 + lane];
    #pragma unroll
    for (int off=1; off<64; off<<=1) a += __shfl_xor(a, off);
    if (lane == 0) wsums[0] = a;
  } else if (w == 1){
    float a = swd[lane] + swd[64 + lane];
    #pragma unroll
    for (int off=1; off<64; off<<=1) a += __shfl_xor(a, off);
    if (lane == 0) wsums[1] = a;
  }

  // gather: thread = (m, qq); qq selects 32 of the 128 concat dims
  {
    int m = tid >> 2, qq = tid & 3;
    int fl = sidx[m];
    int rc = (qq < 2) ? (fl >> 8) : (fl & 255);
    const float* src = x + ((size_t)b*L_SEQ + rc)*D_IN + (qq & 1)*32;
    int kt = m >> 4, l16 = m & 15;
    #pragma unroll
    for (int g=0; g<4; ++g){
      float v[8];
      *(float4*)&v[0] = *(const float4*)(src + g*8);
      *(float4*)&v[4] = *(const float4*)(src + g*8 + 4);
      u32 hp[4], lp[4];
      cvt8(v, hp, lp);
      *(uint4*)&AFh[kt][qq][l16 + 16*g][0] = make_uint4(hp[0],hp[1],hp[2],hp[3]);
      *(uint4*)&AFl[kt][qq][l16 + 16*g][0] = make_uint4(lp[0],lp[1],lp[2],lp[3]);
    }
  }
  __syncthreads();

  int lm = lane & 15, quad = lane >> 4;

  #pragma unroll
  for (int hi2=0; hi2<2; ++hi2){
    int ht = w + 8*hi2;
    int h  = ht*16 + lm;
    bf16x8 BXh[4], BXl[4], BPh[2], BPl[2];
    #pragma unroll
    for (int c=0;c<4;++c){
      BXh[c] = *(const bf16x8*)(xiH + h*128 + c*32 + quad*8);
      BXl[c] = *(const bf16x8*)(xiL + h*128 + c*32 + quad*8);
    }
    #pragma unroll
    for (int c=0;c<2;++c){
      BPh[c] = *(const bf16x8*)(phiH + h*64 + c*32 + quad*8);
      BPl[c] = *(const bf16x8*)(phiL + h*64 + c*32 + quad*8);
    }
    float bxi = xi_b1[h], bph = phi_b1[h];
    float gp = 0.f, gs = 0.f;
    for (int kt=0; kt<8; ++kt){
      bf16x8 Ah_[4], Al_[4];
      #pragma unroll
      for (int c=0;c<4;++c){
        Ah_[c] = *(const bf16x8*)&AFh[kt][c][lane][0];
        Al_[c] = *(const bf16x8*)&AFl[kt][c][lane][0];
      }
      f32x4 cx = {0.f,0.f,0.f,0.f}, cp = {0.f,0.f,0.f,0.f};
      #pragma unroll
      for (int c=0;c<4;++c){
        cx = __builtin_amdgcn_mfma_f32_16x16x32_bf16(Ah_[c], BXh[c], cx, 0,0,0);
        cx = __builtin_amdgcn_mfma_f32_16x16x32_bf16(Al_[c], BXh[c], cx, 0,0,0);
        cx = __builtin_amdgcn_mfma_f32_16x16x32_bf16(Ah_[c], BXl[c], cx, 0,0,0);
      }
      #pragma unroll
      for (int c=0;c<2;++c){
        cp = __builtin_amdgcn_mfma_f32_16x16x32_bf16(Ah_[c], BPh[c], cp, 0,0,0);
        cp = __builtin_amdgcn_mfma_f32_16x16x32_bf16(Al_[c], BPh[c], cp, 0,0,0);
        cp = __builtin_amdgcn_mfma_f32_16x16x32_bf16(Ah_[c], BPl[c], cp, 0,0,0);
      }
      #pragma unroll
      for (int r=0;r<4;++r){
        int kk = kt*16 + quad*4 + r;
        gp = fmaf(swp[kk], fmaxf(cx[r] + bxi, 0.f), gp);
        gs = fmaf(swd[kk], fmaxf(cp[r] + bph, 0.f), gs);
      }
    }
    gp += __shfl_xor(gp, 16); gp += __shfl_xor(gp, 32);
    gs += __shfl_xor(gs, 16); gs += __shfl_xor(gs, 32);
    if (quad == 0){ gpL[h] = gp; gsL[h] = gs; }
  }
  __syncthreads();

  // pooled: 2-way split over d, 4 independent accumulators (chain 256 -> 64)
  {
    int h = tid & 255, half = tid >> 8;
    float wsp = wsums[0], wss = wsums[1];
    float p0 = (half == 0) ? (wsp*xi_b2[h] + wss*phi_b2[h]) : 0.f;
    float p1 = 0.f, p2 = 0.f, p3 = 0.f;
    int dd0 = half*128;
    for (int d=dd0; d<dd0+128; d+=4){
      p0 = fmaf(gpL[d  ], xi_w2[(d  )*HIDN + h], p0);
      p1 = fmaf(gpL[d+1], xi_w2[(d+1)*HIDN + h], p1);
      p2 = fmaf(gpL[d+2], xi_w2[(d+2)*HIDN + h], p2);
      p3 = fmaf(gpL[d+3], xi_w2[(d+3)*HIDN + h], p3);
      p0 = fmaf(gsL[d  ], phi_w2[(d  )*HIDN + h], p0);
      p1 = fmaf(gsL[d+1], phi_w2[(d+1)*HIDN + h], p1);
      p2 = fmaf(gsL[d+2], phi_w2[(d+2)*HIDN + h], p2);
      p3 = fmaf(gsL[d+3], phi_w2[(d+3)*HIDN + h], p3);
    }
    pp[half*256 + h] = (p0 + p1) + (p2 + p3);
  }
  __syncthreads();
  if (tid < 256) pooled[tid] = pp[tid] + pp[256 + tid];
  __syncthreads();
  // t1: 2-way split over d, 4 independent accumulators (chain 128 -> 32)
  {
    int h = tid & 255, half = tid >> 8;
    float a0 = (half == 0) ? rho_b1[h] : 0.f;
    float a1 = 0.f, a2 = 0.f, a3 = 0.f;
    int dd0 = half*128;
    for (int d=dd0; d<dd0+128; d+=4){
      a0 = fmaf(pooled[d  ], rho_w1[(d  )*HIDN + h], a0);
      a1 = fmaf(pooled[d+1], rho_w1[(d+1)*HIDN + h], a1);
      a2 = fmaf(pooled[d+2], rho_w1[(d+2)*HIDN + h], a2);
      a3 = fmaf(pooled[d+3], rho_w1[(d+3)*HIDN + h], a3);
    }
    pp[half*256 + h] = (a0 + a1) + (a2 + a3);
  }
  __syncthreads();
  if (tid < 256) t1[tid] = fmaxf(pp[tid] + pp[256 + tid], 0.f);
  __syncthreads();
  // out: 4-way split over d, 2 independent accumulators (chain 64 -> 32)
  {
    int h = tid & 127, part = tid >> 7;
    float o0 = (part == 0) ? rho_b2[h] : 0.f;
    float o1 = 0.f;
    int dd0 = part*64;
    for (int d=dd0; d<dd0+64; d+=2){
      o0 = fmaf(t1[d  ], rho_w2[(d  )*128 + h], o0);
      o1 = fmaf(t1[d+1], rho_w2[(d+1)*128 + h], o1);
    }
    pp[part*128 + h] = o0 + o1;
  }
  __syncthreads();
  if (tid < 128)
    out[(size_t)b*128 + tid] = pp[tid] + pp[128+tid] + pp[256+tid] + pp[384+tid];
}

// ---------- host ----------
extern "C" void kernel_launch(void* const* d_in, const int* in_sizes, int n_in,
                              void* d_out, int out_size, void* d_ws, size_t ws_size,
                              hipStream_t stream)
{
  (void)in_sizes; (void)n_in; (void)out_size; (void)ws_size;
  const float* x      = (const float*)d_in[0];
  const float* Wq     = (const float*)d_in[1];
  const float* bq     = (const float*)d_in[2];
  const float* Wk     = (const float*)d_in[3];
  const float* bk     = (const float*)d_in[4];
  const float* phi_w1 = (const float*)d_in[5];
  const float* phi_b1 = (const float*)d_in[6];
  const float* phi_w2 = (const float*)d_in[7];
  const float* phi_b2 = (const float*)d_in[8];
  const float* xi_w1  = (const float*)d_in[9];
  const float* xi_b1  = (const float*)d_in[10];
  const float* xi_w2  = (const float*)d_in[11];
  const float* xi_b2  = (const float*)d_in[12];
  const float* rho_w1 = (const float*)d_in[13];
  const float* rho_b1 = (const float*)d_in[14];
  const float* rho_w2 = (const float*)d_in[15];
  const float* rho_b2 = (const float*)d_in[16];
  float* out = (float*)d_out;

  const size_t NX = (size_t)B_TOT*L_SEQ*D_IN;      // 8,388,608
  float* uvc    = (float*)d_ws;                    // 256
  float* st     = uvc + 256;                       // 2*512*256
  float* selw   = st + (size_t)2*B_TOT*L_SEQ;      // 512*128
  int*   selidx = (int*)(selw + (size_t)B_TOT*TOPK);
  int*   cand_n = selidx + (size_t)B_TOT*TOPK;     // 512*32
  u32*   uthr   = (u32*)(cand_n + (size_t)B_TOT*NWT); // 512*32
  u64*   cand   = (u64*)(uthr + (size_t)B_TOT*NWT);
  u16*   MtH    = (u16*)(cand + (size_t)B_TOT*NWT*CAP);
  u16*   MtL    = MtH + 64*64;
  u16*   xiH    = MtL + 64*64;
  u16*   xiL    = xiH + 256*128;
  u16*   phiH   = xiL + 256*128;
  u16*   phiL   = phiH + 256*64;
  u16*   xh     = phiL + 256*64;
  u16*   xl     = xh + NX;
  u16*   yh     = xl + NX;
  u16*   yl     = yh + NX;

  // deterministic per-device check (same result every call -> graph-safe)
  hipError_t aerr = hipFuncSetAttribute((const void*)k_fused,
                      hipFuncAttributeMaxDynamicSharedMemorySize, FLDS);

  k_wprep<<<dim3(256),  dim3(256), 0, stream>>>(Wq, bq, Wk, bk, xi_w1, phi_w1,
                                                MtH, MtL, uvc, xiH, xiL, phiH, phiL);
  if (aerr == hipSuccess){
    k_fused<<<dim3(B_TOT), dim3(1024), FLDS, stream>>>(x, MtH, MtL, uvc, cand, cand_n, uthr);
  } else {
    k_pre  <<<dim3(2048), dim3(256), 0, stream>>>(x, MtH, MtL, uvc, xh, xl, yh, yl, st);
    k_score<<<dim3(4096), dim3(256), 0, stream>>>(xh, xl, yh, yl, st, cand, cand_n, uthr);
  }
  k_merge<<<dim3(B_TOT), dim3(256), 0, stream>>>(cand, cand_n, uthr, selidx, selw);
  k_mlp  <<<dim3(B_TOT), dim3(512), 0, stream>>>(x, selidx, selw,
            xiH, xiL, phiH, phiL,
            phi_b1, phi_w2, phi_b2,
            xi_b1, xi_w2, xi_b2,
            rho_w1, rho_b1, rho_w2, rho_b2, out);
}

// Round 16
// 222.299 us; speedup vs baseline: 1.0914x; 1.0210x over previous
//
#include <hip/hip_runtime.h>

typedef unsigned short u16;
typedef unsigned int   u32;
typedef unsigned char  u8;
typedef unsigned long long u64;

#define B_TOT 512
#define L_SEQ 256
#define D_IN  64
#define HIDN  256
#define TOPK  128
#define CAP   144              // logical candidate cap per unit (mult of 16 -> NSW=18 even)
#define CSTRIDE 160            // physical stride of cand units (decoupled: round-14 store addressing)
#define NWT   32               // units per batch
#define FLDS  76304            // fused dynamic LDS bytes (XH/XL + STS/STT/SUV; no Y bounce)

typedef float  f32x4  __attribute__((ext_vector_type(4)));
typedef __bf16 bf16x8 __attribute__((ext_vector_type(8)));

// ---------- helpers ----------
__device__ __forceinline__ u16 f2bf(float f){
  u32 u = __float_as_uint(f);
  u32 r = u + 0x7fffu + ((u>>16)&1u);   // RNE
  return (u16)(r>>16);
}
__device__ __forceinline__ u32 sortKey(float f){
  u32 b = __float_as_uint(f);
  return (b & 0x80000000u) ? ~b : (b | 0x80000000u);
}
__device__ __forceinline__ float unKey(u32 u){
  u32 b = (u & 0x80000000u) ? (u & 0x7fffffffu) : ~u;
  return __uint_as_float(b);
}
__device__ __forceinline__ void cvt8(const float* v, u32* hp, u32* lp){
  #pragma unroll
  for (int i=0;i<4;++i){
    float v0 = v[2*i], v1 = v[2*i+1];
    u16 h0 = f2bf(v0); float h0f = __uint_as_float(((u32)h0)<<16); u16 l0 = f2bf(v0 - h0f);
    u16 h1 = f2bf(v1); float h1f = __uint_as_float(((u32)h1)<<16); u16 l1 = f2bf(v1 - h1f);
    hp[i] = (u32)h0 | ((u32)h1<<16);
    lp[i] = (u32)l0 | ((u32)l1<<16);
  }
}

// ---------- K0: fused weight prep (uvc via wave reductions, no serial tails) ----------
__global__ __launch_bounds__(256) void k_wprep(
    const float* __restrict__ Wq, const float* __restrict__ bq,
    const float* __restrict__ Wk, const float* __restrict__ bk,
    const float* __restrict__ xi_w1, const float* __restrict__ phi_w1,
    u16* __restrict__ MtH, u16* __restrict__ MtL, float* __restrict__ uvc,
    u16* __restrict__ xiH, u16* __restrict__ xiL,
    u16* __restrict__ phiH, u16* __restrict__ phiL)
{
  int bid = blockIdx.x, tid = threadIdx.x;
  if (bid < 64){
    __shared__ float wq[HIDN];
    __shared__ float part[256];
    int a = bid;
    wq[tid] = Wq[a*HIDN + tid];
    __syncthreads();
    int bcol = tid & 63, q = tid >> 6;
    float s = 0.f;
    for (int h = q*64; h < q*64 + 64; ++h)
      s = fmaf(wq[h], Wk[bcol*HIDN + h], s);
    part[tid] = s;
    __syncthreads();
    if (tid < 64){
      float mv = part[tid] + part[64+tid] + part[128+tid] + part[192+tid];
      u16 hh = f2bf(mv); float hf = __uint_as_float(((u32)hh)<<16);
      u16 ll = f2bf(mv - hf);
      MtH[tid*64 + a] = hh;          // Mt[c][a] = M[a][c]
      MtL[tid*64 + a] = ll;
    }
    // uvc via per-wave shuffle reductions (4 elems/lane)
    int wv = tid >> 6, ln = tid & 63;
    if (wv == 0){
      float s2 = 0.f;
      #pragma unroll
      for (int i=0;i<4;++i){ int h = ln*4+i; s2 = fmaf(wq[h], bk[h], s2); }
      #pragma unroll
      for (int off=1; off<64; off<<=1) s2 += __shfl_xor(s2, off);
      if (ln == 0) uvc[a] = s2;
    } else if (wv == 1){
      float s2 = 0.f;
      #pragma unroll
      for (int i=0;i<4;++i){ int h = ln*4+i; s2 = fmaf(Wk[a*HIDN + h], bq[h], s2); }
      #pragma unroll
      for (int off=1; off<64; off<<=1) s2 += __shfl_xor(s2, off);
      if (ln == 0) uvc[64 + a] = s2;
    } else if (wv == 2 && a == 0){
      float s2 = 0.f;
      #pragma unroll
      for (int i=0;i<4;++i){ int h = ln*4+i; s2 = fmaf(bq[h], bk[h], s2); }
      #pragma unroll
      for (int off=1; off<64; off<<=1) s2 += __shfl_xor(s2, off);
      if (ln == 0) uvc[128] = s2;
    }
  } else {
    int t = (bid-64)*256 + tid;
    if (t < 256*128){
      int h = t >> 7, d = t & 127;
      float v = xi_w1[d*HIDN + h];
      u16 hh = f2bf(v); float hf = __uint_as_float(((u32)hh)<<16);
      u16 ll = f2bf(v - hf);
      xiH[h*128 + d] = hh; xiL[h*128 + d] = ll;
    } else {
      int t2 = t - 256*128;
      int h = t2 >> 6, d = t2 & 63;
      float v = phi_w1[d*HIDN + h];
      u16 hh = f2bf(v); float hf = __uint_as_float(((u32)hh)<<16);
      u16 ll = f2bf(v - hf);
      phiH[h*64 + d] = hh; phiL[h*64 + d] = ll;
    }
  }
}

// ---------- K-FUSED (1024 threads / 16 waves): split + y-MFMA + scoring + per-unit top-k ----------
// grid 512 (1 batch/block), ~76 KB LDS (no Y bounce; swapped-MFMA y with permuted Mt).
// Settled config (rounds 11/13/14): u64 single-stream cand, single-class fast path,
// popc-offset emission. VGPR hard-pinned at 64 for 1024-thread blocks (rounds 6/8/10).
// Round 16: cand storage stride restored to 160 (round-14 addressing) while the
// logical cap stays 144 -- A/B for round-15's +3us k_fused anomaly.
__global__ void __launch_bounds__(1024) __attribute__((amdgpu_waves_per_eu(4,4))) k_fused(
    const float* __restrict__ x, const u16* __restrict__ MtH, const u16* __restrict__ MtL,
    const float* __restrict__ uvc,
    u64* __restrict__ cand, int* __restrict__ cand_n, u32* __restrict__ uthr)
{
  extern __shared__ __align__(16) u16 smem[];
  u16* XH = smem;                       // [256][72]
  u16* XL = XH + 256*72;                // [256][72]
  float* STS = (float*)(XL + 256*72);   // [256] s_i + c (pad -> -1e38)
  float* STT = STS + 256;               // [256] t_j   (pad -> -1e38)
  float* SUV = STT + 256;               // [129]

  int tid = threadIdx.x;
  int b = blockIdx.x;
  const float* xb = x + (size_t)b*(L_SEQ*D_IN);

  if (tid < 129) SUV[tid] = uvc[tid];

  // ---- Phase A: load + split x into LDS (quarter-row per thread) ----
  int ar = tid >> 2, aq = tid & 3;
  float v[16];
  {
    const float* src = xb + (size_t)ar*D_IN + aq*16;
    #pragma unroll
    for (int i=0;i<4;++i) *(float4*)&v[i*4] = *(const float4*)(src + i*4);
    u32 hpA[4],lpA[4],hpB[4],lpB[4];
    cvt8(&v[0], hpA, lpA); cvt8(&v[8], hpB, lpB);
    u16* dh = XH + ar*72 + aq*16;
    u16* dl = XL + ar*72 + aq*16;
    *(uint4*)(dh)     = make_uint4(hpA[0],hpA[1],hpA[2],hpA[3]);
    *(uint4*)(dh + 8) = make_uint4(hpB[0],hpB[1],hpB[2],hpB[3]);
    *(uint4*)(dl)     = make_uint4(lpA[0],lpA[1],lpA[2],lpA[3]);
    *(uint4*)(dl + 8) = make_uint4(lpB[0],lpB[1],lpB[2],lpB[3]);
  }
  __syncthreads();   // SUV + XH/XL visible

  // ---- s_i, t_j, pad (4-lane group reduction) ----
  {
    float su=0.f, tv=0.f, pa=0.f;
    #pragma unroll
    for (int d=0; d<16; ++d){
      float xa = v[d];
      su = fmaf(xa, SUV[aq*16+d], su);
      tv = fmaf(xa, SUV[64+aq*16+d], tv);
      pa += fabsf(xa);
    }
    su += __shfl_xor(su,1); su += __shfl_xor(su,2);
    tv += __shfl_xor(tv,1); tv += __shfl_xor(tv,2);
    pa += __shfl_xor(pa,1); pa += __shfl_xor(pa,2);
    if (aq == 0){
      bool pad = (pa != 0.f);
      STS[ar] = pad ? (su + SUV[128]) : -1e38f;
      STT[ar] = pad ? tv : -1e38f;
    }
  }
  __syncthreads();   // STS/STT visible

  int w = tid >> 6, lane = tid & 63, lm = lane & 15, quad = lane >> 4;
  int u  = w;               // one row-unit per wave: rows [16u, 16u+16)
  int r0 = u*16;

  // ---- y = x M directly into scoring A-frag layout (swapped MFMA, permuted Mt) ----
  bf16x8 Yh0, Yh1, Yl0, Yl1;
  {
    const u16* xh_ = XH + (r0+lm)*72;
    const u16* xl_ = XL + (r0+lm)*72;
    bf16x8 Xh0 = *(const bf16x8*)(xh_ + quad*8);
    bf16x8 Xh1 = *(const bf16x8*)(xh_ + 32 + quad*8);
    bf16x8 Xl0 = *(const bf16x8*)(xl_ + quad*8);
    bf16x8 Xl1 = *(const bf16x8*)(xl_ + 32 + quad*8);
    u32 yh[8], yl[8];     // packed col-pairs; slot = (ct>>1)*4 + (ct&1)*2 + pr
    #pragma unroll
    for (int ct=0; ct<4; ++ct){
      int srow = 8*(lm>>2) + 4*(ct&1) + (lm&3) + 32*(ct>>1);   // sigma(ct,lm)
      const u16* mth = MtH + srow*64 + quad*8;
      const u16* mtl = MtL + srow*64 + quad*8;
      bf16x8 Mh0 = *(const bf16x8*)(mth);
      bf16x8 Mh1 = *(const bf16x8*)(mth + 32);
      bf16x8 Ml0 = *(const bf16x8*)(mtl);
      bf16x8 Ml1 = *(const bf16x8*)(mtl + 32);
      f32x4 a1 = {0.f,0.f,0.f,0.f}, a2 = {0.f,0.f,0.f,0.f};
      a1 = __builtin_amdgcn_mfma_f32_16x16x32_bf16(Mh0, Xh0, a1, 0,0,0);
      a2 = __builtin_amdgcn_mfma_f32_16x16x32_bf16(Mh1, Xh1, a2, 0,0,0);
      a1 = __builtin_amdgcn_mfma_f32_16x16x32_bf16(Ml0, Xh0, a1, 0,0,0);
      a2 = __builtin_amdgcn_mfma_f32_16x16x32_bf16(Ml1, Xh1, a2, 0,0,0);
      a1 = __builtin_amdgcn_mfma_f32_16x16x32_bf16(Mh0, Xl0, a1, 0,0,0);
      a2 = __builtin_amdgcn_mfma_f32_16x16x32_bf16(Mh1, Xl1, a2, 0,0,0);
      #pragma unroll
      for (int pr=0; pr<2; ++pr){
        float v0 = a1[2*pr]   + a2[2*pr];
        float v1 = a1[2*pr+1] + a2[2*pr+1];
        u16 h0 = f2bf(v0); u16 h1 = f2bf(v1);
        u16 l0 = f2bf(v0 - __uint_as_float(((u32)h0)<<16));
        u16 l1 = f2bf(v1 - __uint_as_float(((u32)h1)<<16));
        int slot = (ct>>1)*4 + (ct&1)*2 + pr;
        yh[slot] = (u32)h0 | ((u32)h1<<16);
        yl[slot] = (u32)l0 | ((u32)l1<<16);
      }
    }
    uint4 t0 = make_uint4(yh[0],yh[1],yh[2],yh[3]);
    uint4 t1 = make_uint4(yh[4],yh[5],yh[6],yh[7]);
    uint4 t2 = make_uint4(yl[0],yl[1],yl[2],yl[3]);
    uint4 t3 = make_uint4(yl[4],yl[5],yl[6],yl[7]);
    Yh0 = *(const bf16x8*)&t0;
    Yh1 = *(const bf16x8*)&t1;
    Yl0 = *(const bf16x8*)&t2;
    Yl1 = *(const bf16x8*)&t3;
  }

  float sr[4];
  #pragma unroll
  for (int r=0;r<4;++r) sr[r] = STS[r0 + quad*4 + r];

  // ---- two column-halves: score 16x128, select, emit (kv[32] per lane) ----
  for (int ch=0; ch<2; ++ch){
    int j0 = ch*128;
    u32 kv[32];
    #pragma unroll
    for (int ct=0; ct<8; ++ct){
      const u16* bh = XH + (j0 + ct*16+lm)*72;
      const u16* bl = XL + (j0 + ct*16+lm)*72;
      bf16x8 Bh0 = *(const bf16x8*)(bh + quad*8);
      bf16x8 Bh1 = *(const bf16x8*)(bh + 32 + quad*8);
      bf16x8 Bl0 = *(const bf16x8*)(bl + quad*8);
      bf16x8 Bl1 = *(const bf16x8*)(bl + 32 + quad*8);
      f32x4 a1 = {0.f,0.f,0.f,0.f}, a2 = {0.f,0.f,0.f,0.f};
      a1 = __builtin_amdgcn_mfma_f32_16x16x32_bf16(Yh0, Bh0, a1, 0,0,0);
      a2 = __builtin_amdgcn_mfma_f32_16x16x32_bf16(Yh1, Bh1, a2, 0,0,0);
      a1 = __builtin_amdgcn_mfma_f32_16x16x32_bf16(Yl0, Bh0, a1, 0,0,0);
      a2 = __builtin_amdgcn_mfma_f32_16x16x32_bf16(Yl1, Bh1, a2, 0,0,0);
      a1 = __builtin_amdgcn_mfma_f32_16x16x32_bf16(Yh0, Bl0, a1, 0,0,0);
      a2 = __builtin_amdgcn_mfma_f32_16x16x32_bf16(Yh1, Bl1, a2, 0,0,0);
      float tc = STT[j0 + ct*16 + lm];
      #pragma unroll
      for (int r=0;r<4;++r)
        kv[ct*4 + r] = sortKey(a1[r] + a2[r] + sr[r] + tc);
    }

    // 16-bit-prefix threshold (top-128 of 2048), early-exit in [TOPK, CAP];
    // two independent popcount accumulators halve the serial SALU chain.
    u32 T = 0;
    int cfin = -1;                 // >=0 iff early-exit fired (count known <= CAP)
    for (int bit=15; bit>=0; --bit){
      u32 th2 = (T | (1u<<bit)) << 16;
      int c0 = 0, c1 = 0;
      #pragma unroll
      for (int i=0;i<32;i+=2){
        c0 += (int)__popcll(__ballot(kv[i]   >= th2));
        c1 += (int)__popcll(__ballot(kv[i+1] >= th2));
      }
      int c = c0 + c1;
      if (c >= TOPK){
        T |= (1u<<bit);
        if (c <= CAP){ cfin = c; break; }
      }
    }
    u32 thr = T << 16;

    int wt = u*2 + ch;
    size_t base = ((size_t)b*NWT + wt)*CSTRIDE;
    // hoisted emission row bases: flat = rb[r] + (i>>2)*16
    int rb0 = (r0 + quad*4 + 0)*L_SEQ + j0 + lm;
    int rb1 = rb0 + L_SEQ, rb2 = rb1 + L_SEQ, rb3 = rb2 + L_SEQ;

    if (cfin >= 0){
      // ---- fast path (dominant): everything >= thr fits; single mask + single scan ----
      u32 m = 0;
      #pragma unroll
      for (int i=0;i<32;++i) m |= (kv[i] >= thr ? 1u : 0u) << i;
      int n = __popc(m);
      int p = n;
      #pragma unroll
      for (int off=1; off<64; off<<=1){
        int a = __shfl_up(p, off); if (lane >= off) p += a;
      }
      int pos = p - n;
      if (lane == 0){
        cand_n[b*NWT + wt] = cfin;    // ballot count, wave-uniform, <= CAP
        uthr[b*NWT + wt] = thr;
      }
      #pragma unroll
      for (int i=0;i<32;++i){
        if ((m >> i) & 1u){
          int pp2 = pos + __popc(m & ((1u<<i)-1u));   // within-lane offset, no serial chain
          int flat = ((i&3)==0 ? rb0 : (i&3)==1 ? rb1 : (i&3)==2 ? rb2 : rb3) + (i>>2)*16;
          cand[base + pp2] = ((u64)kv[i] << 32) | (u32)flat;
        }
      }
    } else {
      // ---- rare fallback: count at final T may exceed CAP; two-class priority emission ----
      u32 up  = (T < 0xffffu) ? ((T+1u) << 16) : 0xffffffffu;
      u32 m1 = 0, m2 = 0;
      #pragma unroll
      for (int i=0;i<32;++i){
        bool ge = kv[i] >= thr;
        bool c1 = ge && (kv[i] >= up);
        m1 |= (c1 ? 1u : 0u) << i;
        m2 |= ((ge && !c1) ? 1u : 0u) << i;
      }
      int n1 = __popc(m1), n2 = __popc(m2);
      int p1 = n1, p2 = n2;
      #pragma unroll
      for (int off=1; off<64; off<<=1){
        int a = __shfl_up(p1, off); if (lane >= off) p1 += a;
        int c = __shfl_up(p2, off); if (lane >= off) p2 += c;
      }
      int tot1 = __shfl(p1, 63), tot2 = __shfl(p2, 63);
      int pos1 = p1 - n1;
      int pos2 = tot1 + (p2 - n2);
      int total = tot1 + tot2;
      if (lane == 0){
        cand_n[b*NWT + wt] = (total < CAP) ? total : CAP;
        uthr[b*NWT + wt] = thr;
      }
      int o1=0, o2=0;
      #pragma unroll
      for (int i=0;i<32;++i){
        bool c1 = (m1 >> i) & 1u, c2v = (m2 >> i) & 1u;
        if (c1 | c2v){
          int p = c1 ? (pos1 + o1) : (pos2 + o2);
          int flat = ((i&3)==0 ? rb0 : (i&3)==1 ? rb1 : (i&3)==2 ? rb2 : rb3) + (i>>2)*16;
          if (p < CAP) cand[base + p] = ((u64)kv[i] << 32) | (u32)flat;
        }
        o1 += c1; o2 += c2v;
      }
    }
  }
}

// ---------- FALLBACK K1: split x; st; y via MFMA ----------
__global__ __launch_bounds__(256) void k_pre(
    const float* __restrict__ x, const u16* __restrict__ MtH, const u16* __restrict__ MtL,
    const float* __restrict__ uvc,
    u16* __restrict__ xh, u16* __restrict__ xl,
    u16* __restrict__ yh, u16* __restrict__ yl,
    float* __restrict__ st)
{
  __shared__ __align__(16) u16 sh[64][72];
  __shared__ __align__(16) u16 sl[64][72];
  __shared__ float sUV[132];
  int tid = threadIdx.x;
  int g0 = blockIdx.x * 64;
  int b  = g0 >> 8, l0 = g0 & 255;
  int r = tid >> 2, q = tid & 3;

  if (tid < 129) sUV[tid] = uvc[tid];

  float v[16];
  {
    const float* xr = x + (size_t)(g0 + r)*D_IN + q*16;
    #pragma unroll
    for (int i=0;i<4;++i) *(float4*)&v[i*4] = *(const float4*)(xr + i*4);
  }
  {
    u32 hpA[4],lpA[4],hpB[4],lpB[4];
    cvt8(&v[0], hpA, lpA); cvt8(&v[8], hpB, lpB);
    size_t xo = (size_t)(g0 + r)*D_IN + q*16;
    *(uint4*)(xh + xo)     = make_uint4(hpA[0],hpA[1],hpA[2],hpA[3]);
    *(uint4*)(xh + xo + 8) = make_uint4(hpB[0],hpB[1],hpB[2],hpB[3]);
    *(uint4*)(xl + xo)     = make_uint4(lpA[0],lpA[1],lpA[2],lpA[3]);
    *(uint4*)(xl + xo + 8) = make_uint4(lpB[0],lpB[1],lpB[2],lpB[3]);
    *(uint4*)&sh[r][q*16]   = make_uint4(hpA[0],hpA[1],hpA[2],hpA[3]);
    *(uint4*)&sh[r][q*16+8] = make_uint4(hpB[0],hpB[1],hpB[2],hpB[3]);
    *(uint4*)&sl[r][q*16]   = make_uint4(lpA[0],lpA[1],lpA[2],lpA[3]);
    *(uint4*)&sl[r][q*16+8] = make_uint4(lpB[0],lpB[1],lpB[2],lpB[3]);
  }
  __syncthreads();

  {
    float su=0.f, tv=0.f, pa=0.f;
    #pragma unroll
    for (int d=0; d<16; ++d){
      float xa = v[d];
      su = fmaf(xa, sUV[q*16+d], su);
      tv = fmaf(xa, sUV[64+q*16+d], tv);
      pa += fabsf(xa);
    }
    su += __shfl_xor(su,1); su += __shfl_xor(su,2);
    tv += __shfl_xor(tv,1); tv += __shfl_xor(tv,2);
    pa += __shfl_xor(pa,1); pa += __shfl_xor(pa,2);
    if (q == 0){
      bool pad = (pa != 0.f);
      st[(size_t)b*L_SEQ + l0 + r]          = pad ? (su + sUV[128]) : -1e38f;
      st[(size_t)(B_TOT+b)*L_SEQ + l0 + r]  = pad ? tv : -1e38f;
    }
  }

  int w = tid >> 6, lane = tid & 63, lm = lane & 15, quad = lane >> 4;
  bf16x8 Ah0 = *(const bf16x8*)&sh[w*16+lm][quad*8];
  bf16x8 Ah1 = *(const bf16x8*)&sh[w*16+lm][32 + quad*8];
  bf16x8 Al0 = *(const bf16x8*)&sl[w*16+lm][quad*8];
  bf16x8 Al1 = *(const bf16x8*)&sl[w*16+lm][32 + quad*8];
  #pragma unroll
  for (int ct=0; ct<4; ++ct){
    const u16* mth = MtH + (ct*16+lm)*64 + quad*8;
    const u16* mtl = MtL + (ct*16+lm)*64 + quad*8;
    bf16x8 Bh0 = *(const bf16x8*)(mth);
    bf16x8 Bh1 = *(const bf16x8*)(mth + 32);
    bf16x8 Bl0 = *(const bf16x8*)(mtl);
    bf16x8 Bl1 = *(const bf16x8*)(mtl + 32);
    f32x4 a1 = {0.f,0.f,0.f,0.f}, a2 = {0.f,0.f,0.f,0.f};
    a1 = __builtin_amdgcn_mfma_f32_16x16x32_bf16(Ah0, Bh0, a1, 0,0,0);
    a2 = __builtin_amdgcn_mfma_f32_16x16x32_bf16(Ah1, Bh1, a2, 0,0,0);
    a1 = __builtin_amdgcn_mfma_f32_16x16x32_bf16(Al0, Bh0, a1, 0,0,0);
    a2 = __builtin_amdgcn_mfma_f32_16x16x32_bf16(Al1, Bh1, a2, 0,0,0);
    a1 = __builtin_amdgcn_mfma_f32_16x16x32_bf16(Ah0, Bl0, a1, 0,0,0);
    a2 = __builtin_amdgcn_mfma_f32_16x16x32_bf16(Ah1, Bl1, a2, 0,0,0);
    #pragma unroll
    for (int rg=0; rg<4; ++rg){
      float vy = a1[rg] + a2[rg];
      u16 hh = f2bf(vy); float hf = __uint_as_float(((u32)hh)<<16);
      u16 ll = f2bf(vy - hf);
      sh[w*16 + quad*4 + rg][ct*16 + lm] = hh;
      sl[w*16 + quad*4 + rg][ct*16 + lm] = ll;
    }
  }
  {
    size_t yo = (size_t)(g0 + r)*D_IN + q*16;
    *(uint4*)(yh + yo)     = *(uint4*)&sh[r][q*16];
    *(uint4*)(yh + yo + 8) = *(uint4*)&sh[r][q*16+8];
    *(uint4*)(yl + yo)     = *(uint4*)&sl[r][q*16];
    *(uint4*)(yl + yo + 8) = *(uint4*)&sl[r][q*16+8];
  }
}

// ---------- FALLBACK K2: k_score ----------
__global__ __launch_bounds__(256) void k_score(
    const u16* __restrict__ xh, const u16* __restrict__ xl,
    const u16* __restrict__ yh, const u16* __restrict__ yl,
    const float* __restrict__ st,
    u64* __restrict__ cand, int* __restrict__ cand_n, u32* __restrict__ uthr)
{
  int tid = threadIdx.x;
  int lin = blockIdx.x;
  int b    = ((lin >> 6) << 3) | (lin & 7);
  int tile = (lin >> 3) & 7;
  int cb = tile & 1, rb = tile >> 1;
  int r0 = rb*64, j0 = cb*128;
  int w = tid >> 6, lane = tid & 63, lm = lane & 15, quad = lane >> 4;

  size_t rowA = ((size_t)b*L_SEQ + r0 + w*16 + lm)*D_IN;
  bf16x8 A_h0 = *(const bf16x8*)(yh + rowA + quad*8);
  bf16x8 A_h1 = *(const bf16x8*)(yh + rowA + 32 + quad*8);
  bf16x8 A_l0 = *(const bf16x8*)(yl + rowA + quad*8);
  bf16x8 A_l1 = *(const bf16x8*)(yl + rowA + 32 + quad*8);

  float4 s4 = *(const float4*)(st + (size_t)b*L_SEQ + r0 + w*16 + quad*4);
  float sr[4] = {s4.x, s4.y, s4.z, s4.w};
  float tc[8];
  #pragma unroll
  for (int ct=0;ct<8;++ct)
    tc[ct] = st[(size_t)(B_TOT + b)*L_SEQ + j0 + ct*16 + lm];

  u32 kv[32];
  #pragma unroll
  for (int ct=0; ct<8; ++ct){
    size_t rowB = ((size_t)b*L_SEQ + j0 + ct*16 + lm)*D_IN;
    bf16x8 B_h0 = *(const bf16x8*)(xh + rowB + quad*8);
    bf16x8 B_h1 = *(const bf16x8*)(xh + rowB + 32 + quad*8);
    bf16x8 B_l0 = *(const bf16x8*)(xl + rowB + quad*8);
    bf16x8 B_l1 = *(const bf16x8*)(xl + rowB + 32 + quad*8);
    f32x4 a1 = {0.f,0.f,0.f,0.f}, a2 = {0.f,0.f,0.f,0.f};
    a1 = __builtin_amdgcn_mfma_f32_16x16x32_bf16(A_h0, B_h0, a1, 0,0,0);
    a2 = __builtin_amdgcn_mfma_f32_16x16x32_bf16(A_h1, B_h1, a2, 0,0,0);
    a1 = __builtin_amdgcn_mfma_f32_16x16x32_bf16(A_l0, B_h0, a1, 0,0,0);
    a2 = __builtin_amdgcn_mfma_f32_16x16x32_bf16(A_l1, B_h1, a2, 0,0,0);
    a1 = __builtin_amdgcn_mfma_f32_16x16x32_bf16(A_h0, B_l0, a1, 0,0,0);
    a2 = __builtin_amdgcn_mfma_f32_16x16x32_bf16(A_h1, B_l1, a2, 0,0,0);
    #pragma unroll
    for (int r=0;r<4;++r)
      kv[ct*4 + r] = sortKey(a1[r] + a2[r] + sr[r] + tc[ct]);
  }

  u32 T = 0;
  for (int bit=15; bit>=0; --bit){
    u32 th2 = (T | (1u<<bit)) << 16;
    int c = 0;
    #pragma unroll
    for (int i=0;i<32;++i)
      c += (int)__popcll(__ballot(kv[i] >= th2));
    if (c >= TOPK){
      T |= (1u<<bit);
      if (c <= CAP) break;
    }
  }
  u32 thr = T << 16;

  u32 hm = 0;
  #pragma unroll
  for (int i=0;i<32;++i) hm |= (kv[i] >= thr ? 1u : 0u) << i;
  int myc = __popc(hm);
  int pre = myc;
  #pragma unroll
  for (int off=1; off<64; off<<=1){
    int n = __shfl_up(pre, off);
    if (lane >= off) pre += n;
  }
  int total = __shfl(pre, 63);
  int pos = pre - myc;
  int wt = tile*4 + w;
  size_t base = ((size_t)b*NWT + wt)*CSTRIDE;
  if (lane == 0){
    cand_n[b*NWT + wt] = (total < CAP) ? total : CAP;
    uthr[b*NWT + wt] = thr;
  }
  while (hm){
    int i = __ffs(hm) - 1; hm &= hm - 1;
    if (pos < CAP){
      int r = i & 3, ct = i >> 2;
      int flat = (r0 + w*16 + quad*4 + r)*L_SEQ + (j0 + ct*16 + lm);
      cand[base + pos] = ((u64)kv[i] << 32) | (u32)flat;
    }
    ++pos;
  }
}

// ---------- K3: two-stage ballot merge -> exact top-128 + softmax ----------
// LB trick: any candidate threshold <= max(per-unit thr) provably has count >= TOPK.
// Kept as a SEPARATE 256-thread kernel (rounds 7/9: fusing serializes it at low
// occupancy). cand load as NSW/2=9 unconditional 16B uint4 loads/lane; logical index
// e over CAP-packed slots mapped to physical address with CSTRIDE (both even ->
// pairs never straddle units, 16B alignment holds); garbage beyond cand_n masked
// post-load to the identical key=0/idx-sentinel values.
__global__ __launch_bounds__(256) void k_merge(
    const u64* __restrict__ cand, const int* __restrict__ cand_n, const u32* __restrict__ uthr,
    int* __restrict__ selidx, float* __restrict__ selw)
{
  const int SL   = NWT/4;           // 8 slots per wave
  const int NSW  = SL*CAP/64;       // 18 keys per lane (CAP=144)
  const int WCAP = 192;
  __shared__ u64 wbuf[4][WCAP];
  __shared__ int wcnt[4];
  __shared__ int scnt[NWT];
  __shared__ u32 wT[4];
  __shared__ int cm, eqc;
  __shared__ int eqi[256];
  __shared__ float sv[TOPK]; __shared__ int si[TOPK];
  __shared__ float fred[8];
  int b = blockIdx.x, tid = threadIdx.x;
  int w = tid >> 6, lane = tid & 63;
  if (tid < NWT) scnt[tid] = cand_n[b*NWT + tid];
  if (tid == 0){ cm = 0; eqc = 0; }
  __syncthreads();

  u32 key[NSW]; int idx[NSW];
  size_t bb = ((size_t)b*NWT + (size_t)(w*SL))*CSTRIDE;
  #pragma unroll
  for (int s=0;s<NSW/2;++s){
    int e = 2*lane + 128*s;              // even logical index over CAP-packed slots
    int slot = e / CAP, p = e - slot*CAP;    // p even (CAP even)
    uint4 qv = *(const uint4*)(cand + bb + slot*CSTRIDE + p);   // 16B aligned (all even)
    int cc = scnt[w*SL + slot];
    bool ok0 = p < cc, ok1 = (p+1) < cc;
    key[2*s]   = ok0 ? qv.y : 0u;
    idx[2*s]   = ok0 ? (int)qv.x : 0x7fffffff;
    key[2*s+1] = ok1 ? qv.w : 0u;
    idx[2*s+1] = ok1 ? (int)qv.z : 0x7fffffff;
  }

  // wave lower bound = max over this wave's 8 unit thresholds
  u32 lb = uthr[b*NWT + w*SL + (lane & 7)];
  #pragma unroll
  for (int off=1; off<8; off<<=1){
    u32 o = (u32)__shfl_xor((int)lb, off);
    lb = lb > o ? lb : o;
  }

  u32 T = 0;
  for (int bit=31; bit>=0; --bit){
    u32 c2 = T | (1u<<bit);
    if (c2 <= lb){ T = c2; continue; }   // provable accept, no count
    int c = 0;
    #pragma unroll
    for (int s=0;s<NSW;++s) c += (int)__popcll(__ballot(key[s] >= c2));
    if (c >= TOPK){
      T = c2;
      if (c <= WCAP) break;
    }
  }
  if (lane == 0) wT[w] = T;
  {
    int myc = 0;
    #pragma unroll
    for (int s=0;s<NSW;++s) myc += (key[s] >= T) ? 1 : 0;
    int pre = myc;
    #pragma unroll
    for (int off=1; off<64; off<<=1){
      int n = __shfl_up(pre, off);
      if (lane >= off) pre += n;
    }
    int total = __shfl(pre, 63);
    int pos = pre - myc;
    if (lane == 0) wcnt[w] = (total < WCAP) ? total : WCAP;
    #pragma unroll
    for (int s=0;s<NSW;++s){
      if (key[s] >= T){
        if (pos < WCAP) wbuf[w][pos] = ((u64)key[s] << 32) | (u32)idx[s];
        ++pos;
      }
    }
  }
  __syncthreads();

  if (w == 0){
    const int NS2 = 4*WCAP/64;   // 12
    u32 k2[NS2]; int i2[NS2];
    #pragma unroll
    for (int s=0;s<NS2;++s){
      int e = lane + 64*s;
      int slot = e / WCAP, p = e - slot*WCAP;
      bool ok = p < wcnt[slot];
      u64 v = ok ? wbuf[slot][p] : 0ull;
      k2[s] = (u32)(v >> 32);
      i2[s] = ok ? (int)(u32)v : 0x7fffffff;
    }
    u32 lb2 = wT[0];
    lb2 = lb2 > wT[1] ? lb2 : wT[1];
    lb2 = lb2 > wT[2] ? lb2 : wT[2];
    lb2 = lb2 > wT[3] ? lb2 : wT[3];
    u32 T2 = 0;
    for (int bit=31; bit>=0; --bit){
      u32 c2 = T2 | (1u<<bit);
      if (c2 <= lb2){ T2 = c2; continue; }   // provable accept, exactness preserved
      int c = 0;
      #pragma unroll
      for (int s=0;s<NS2;++s) c += (int)__popcll(__ballot(k2[s] >= c2));
      if (c >= TOPK) T2 = c2;
    }
    int m = 0;
    #pragma unroll
    for (int s=0;s<NS2;++s) m += (int)__popcll(__ballot(k2[s] > T2));
    #pragma unroll
    for (int s=0;s<NS2;++s){
      if (k2[s] > T2){
        int p = atomicAdd(&cm, 1);
        sv[p] = unKey(k2[s]) * 0.0625f; si[p] = i2[s];
      } else if (k2[s] == T2 && i2[s] != 0x7fffffff){
        int q = atomicAdd(&eqc, 1);
        if (q < 256) eqi[q] = i2[s];
      }
    }
    if (lane == 0){
      int need = TOPK - m;
      int n = eqc < 256 ? eqc : 256;
      float tv = unKey(T2) * 0.0625f;
      for (int s2=0; s2<need; ++s2){
        int bi = s2;
        for (int j=s2+1;j<n;++j) if (eqi[j] < eqi[bi]) bi = j;
        int t2 = eqi[s2]; eqi[s2] = eqi[bi]; eqi[bi] = t2;
        sv[m+s2] = tv; si[m+s2] = eqi[s2];
      }
    }
  }
  __syncthreads();

  float v = (tid < TOPK) ? sv[tid] : -3.4e38f;
  float mx = v;
  #pragma unroll
  for (int off=1; off<64; off<<=1) mx = fmaxf(mx, __shfl_xor(mx, off));
  if ((tid&63)==0) fred[tid>>6] = mx;
  __syncthreads();
  mx = fmaxf(fred[0], fred[1]);
  float e = (tid < TOPK) ? expf(v - mx) : 0.f;
  float s = e;
  #pragma unroll
  for (int off=1; off<64; off<<=1) s += __shfl_xor(s, off);
  if ((tid&63)==0) fred[4 + (tid>>6)] = s;
  __syncthreads();
  s = fred[4] + fred[5];
  if (tid < TOPK){
    selw[(size_t)b*TOPK + tid]   = e / s;
    selidx[(size_t)b*TOPK + tid] = si[tid];
  }
}

// ---------- K4: gather + split-bf16 MFMA MLP1 + pooling + rho (512-thread / 8-wave) ----------
// Tail GEMVs use 4 (pooled/t1) / 2 (out) independent accumulators (round 15: breaks
// the serial fmaf chains; reassociation delta ~1e-6, below the bf16 0.0049 absmax).
__global__ __launch_bounds__(512) void k_mlp(
    const float* __restrict__ x, const int* __restrict__ selidx, const float* __restrict__ selw,
    const u16* __restrict__ xiH, const u16* __restrict__ xiL,
    const u16* __restrict__ phiH, const u16* __restrict__ phiL,
    const float* __restrict__ phi_b1, const float* __restrict__ phi_w2, const float* __restrict__ phi_b2,
    const float* __restrict__ xi_b1,  const float* __restrict__ xi_w2,  const float* __restrict__ xi_b2,
    const float* __restrict__ rho_w1, const float* __restrict__ rho_b1,
    const float* __restrict__ rho_w2, const float* __restrict__ rho_b2,
    float* __restrict__ out)
{
  __shared__ __align__(16) u16 AFh[8][4][64][8];
  __shared__ __align__(16) u16 AFl[8][4][64][8];
  __shared__ int   sidx[TOPK];
  __shared__ float swp[TOPK], swd[TOPK];
  __shared__ float gpL[256], gsL[256];
  __shared__ float pooled[256], t1[256];
  __shared__ float pp[512];
  __shared__ float wsums[2];
  int b = blockIdx.x, tid = threadIdx.x;
  int w = tid >> 6, lane = tid & 63;

  if (tid < TOPK){
    int fl = selidx[(size_t)b*TOPK + tid];
    sidx[tid] = fl;
    float wv = selw[(size_t)b*TOPK + tid];
    bool dg = ((fl>>8) == (fl&255));
    swp[tid] = dg ? 0.f : wv;
    swd[tid] = dg ? wv  : 0.f;
  }
  __syncthreads();

  // wsums via 2 wave reductions (parallel with gather on other waves)
  if (w == 0){
    float a = swp[lane] + swp[64 + lane];
    #pragma unroll
    for (int off=1; off<64; off<<=1) a += __shfl_xor(a, off);
    if (lane == 0) wsums[0] = a;
  } else if (w == 1){
    float a = swd[lane] + swd[64 + lane];
    #pragma unroll
    for (int off=1; off<64; off<<=1) a += __shfl_xor(a, off);
    if (lane == 0) wsums[1] = a;
  }

  // gather: thread = (m, qq); qq selects 32 of the 128 concat dims
  {
    int m = tid >> 2, qq = tid & 3;
    int fl = sidx[m];
    int rc = (qq < 2) ? (fl >> 8) : (fl & 255);
    const float* src = x + ((size_t)b*L_SEQ + rc)*D_IN + (qq & 1)*32;
    int kt = m >> 4, l16 = m & 15;
    #pragma unroll
    for (int g=0; g<4; ++g){
      float v[8];
      *(float4*)&v[0] = *(const float4*)(src + g*8);
      *(float4*)&v[4] = *(const float4*)(src + g*8 + 4);
      u32 hp[4], lp[4];
      cvt8(v, hp, lp);
      *(uint4*)&AFh[kt][qq][l16 + 16*g][0] = make_uint4(hp[0],hp[1],hp[2],hp[3]);
      *(uint4*)&AFl[kt][qq][l16 + 16*g][0] = make_uint4(lp[0],lp[1],lp[2],lp[3]);
    }
  }
  __syncthreads();

  int lm = lane & 15, quad = lane >> 4;

  #pragma unroll
  for (int hi2=0; hi2<2; ++hi2){
    int ht = w + 8*hi2;
    int h  = ht*16 + lm;
    bf16x8 BXh[4], BXl[4], BPh[2], BPl[2];
    #pragma unroll
    for (int c=0;c<4;++c){
      BXh[c] = *(const bf16x8*)(xiH + h*128 + c*32 + quad*8);
      BXl[c] = *(const bf16x8*)(xiL + h*128 + c*32 + quad*8);
    }
    #pragma unroll
    for (int c=0;c<2;++c){
      BPh[c] = *(const bf16x8*)(phiH + h*64 + c*32 + quad*8);
      BPl[c] = *(const bf16x8*)(phiL + h*64 + c*32 + quad*8);
    }
    float bxi = xi_b1[h], bph = phi_b1[h];
    float gp = 0.f, gs = 0.f;
    for (int kt=0; kt<8; ++kt){
      bf16x8 Ah_[4], Al_[4];
      #pragma unroll
      for (int c=0;c<4;++c){
        Ah_[c] = *(const bf16x8*)&AFh[kt][c][lane][0];
        Al_[c] = *(const bf16x8*)&AFl[kt][c][lane][0];
      }
      f32x4 cx = {0.f,0.f,0.f,0.f}, cp = {0.f,0.f,0.f,0.f};
      #pragma unroll
      for (int c=0;c<4;++c){
        cx = __builtin_amdgcn_mfma_f32_16x16x32_bf16(Ah_[c], BXh[c], cx, 0,0,0);
        cx = __builtin_amdgcn_mfma_f32_16x16x32_bf16(Al_[c], BXh[c], cx, 0,0,0);
        cx = __builtin_amdgcn_mfma_f32_16x16x32_bf16(Ah_[c], BXl[c], cx, 0,0,0);
      }
      #pragma unroll
      for (int c=0;c<2;++c){
        cp = __builtin_amdgcn_mfma_f32_16x16x32_bf16(Ah_[c], BPh[c], cp, 0,0,0);
        cp = __builtin_amdgcn_mfma_f32_16x16x32_bf16(Al_[c], BPh[c], cp, 0,0,0);
        cp = __builtin_amdgcn_mfma_f32_16x16x32_bf16(Ah_[c], BPl[c], cp, 0,0,0);
      }
      #pragma unroll
      for (int r=0;r<4;++r){
        int kk = kt*16 + quad*4 + r;
        gp = fmaf(swp[kk], fmaxf(cx[r] + bxi, 0.f), gp);
        gs = fmaf(swd[kk], fmaxf(cp[r] + bph, 0.f), gs);
      }
    }
    gp += __shfl_xor(gp, 16); gp += __shfl_xor(gp, 32);
    gs += __shfl_xor(gs, 16); gs += __shfl_xor(gs, 32);
    if (quad == 0){ gpL[h] = gp; gsL[h] = gs; }
  }
  __syncthreads();

  // pooled: 2-way split over d, 4 independent accumulators (chain 256 -> 64)
  {
    int h = tid & 255, half = tid >> 8;
    float wsp = wsums[0], wss = wsums[1];
    float p0 = (half == 0) ? (wsp*xi_b2[h] + wss*phi_b2[h]) : 0.f;
    float p1 = 0.f, p2 = 0.f, p3 = 0.f;
    int dd0 = half*128;
    for (int d=dd0; d<dd0+128; d+=4){
      p0 = fmaf(gpL[d  ], xi_w2[(d  )*HIDN + h], p0);
      p1 = fmaf(gpL[d+1], xi_w2[(d+1)*HIDN + h], p1);
      p2 = fmaf(gpL[d+2], xi_w2[(d+2)*HIDN + h], p2);
      p3 = fmaf(gpL[d+3], xi_w2[(d+3)*HIDN + h], p3);
      p0 = fmaf(gsL[d  ], phi_w2[(d  )*HIDN + h], p0);
      p1 = fmaf(gsL[d+1], phi_w2[(d+1)*HIDN + h], p1);
      p2 = fmaf(gsL[d+2], phi_w2[(d+2)*HIDN + h], p2);
      p3 = fmaf(gsL[d+3], phi_w2[(d+3)*HIDN + h], p3);
    }
    pp[half*256 + h] = (p0 + p1) + (p2 + p3);
  }
  __syncthreads();
  if (tid < 256) pooled[tid] = pp[tid] + pp[256 + tid];
  __syncthreads();
  // t1: 2-way split over d, 4 independent accumulators (chain 128 -> 32)
  {
    int h = tid & 255, half = tid >> 8;
    float a0 = (half == 0) ? rho_b1[h] : 0.f;
    float a1 = 0.f, a2 = 0.f, a3 = 0.f;
    int dd0 = half*128;
    for (int d=dd0; d<dd0+128; d+=4){
      a0 = fmaf(pooled[d  ], rho_w1[(d  )*HIDN + h], a0);
      a1 = fmaf(pooled[d+1], rho_w1[(d+1)*HIDN + h], a1);
      a2 = fmaf(pooled[d+2], rho_w1[(d+2)*HIDN + h], a2);
      a3 = fmaf(pooled[d+3], rho_w1[(d+3)*HIDN + h], a3);
    }
    pp[half*256 + h] = (a0 + a1) + (a2 + a3);
  }
  __syncthreads();
  if (tid < 256) t1[tid] = fmaxf(pp[tid] + pp[256 + tid], 0.f);
  __syncthreads();
  // out: 4-way split over d, 2 independent accumulators (chain 64 -> 32)
  {
    int h = tid & 127, part = tid >> 7;
    float o0 = (part == 0) ? rho_b2[h] : 0.f;
    float o1 = 0.f;
    int dd0 = part*64;
    for (int d=dd0; d<dd0+64; d+=2){
      o0 = fmaf(t1[d  ], rho_w2[(d  )*128 + h], o0);
      o1 = fmaf(t1[d+1], rho_w2[(d+1)*128 + h], o1);
    }
    pp[part*128 + h] = o0 + o1;
  }
  __syncthreads();
  if (tid < 128)
    out[(size_t)b*128 + tid] = pp[tid] + pp[128+tid] + pp[256+tid] + pp[384+tid];
}

// ---------- host ----------
extern "C" void kernel_launch(void* const* d_in, const int* in_sizes, int n_in,
                              void* d_out, int out_size, void* d_ws, size_t ws_size,
                              hipStream_t stream)
{
  (void)in_sizes; (void)n_in; (void)out_size; (void)ws_size;
  const float* x      = (const float*)d_in[0];
  const float* Wq     = (const float*)d_in[1];
  const float* bq     = (const float*)d_in[2];
  const float* Wk     = (const float*)d_in[3];
  const float* bk     = (const float*)d_in[4];
  const float* phi_w1 = (const float*)d_in[5];
  const float* phi_b1 = (const float*)d_in[6];
  const float* phi_w2 = (const float*)d_in[7];
  const float* phi_b2 = (const float*)d_in[8];
  const float* xi_w1  = (const float*)d_in[9];
  const float* xi_b1  = (const float*)d_in[10];
  const float* xi_w2  = (const float*)d_in[11];
  const float* xi_b2  = (const float*)d_in[12];
  const float* rho_w1 = (const float*)d_in[13];
  const float* rho_b1 = (const float*)d_in[14];
  const float* rho_w2 = (const float*)d_in[15];
  const float* rho_b2 = (const float*)d_in[16];
  float* out = (float*)d_out;

  const size_t NX = (size_t)B_TOT*L_SEQ*D_IN;      // 8,388,608
  float* uvc    = (float*)d_ws;                    // 256
  float* st     = uvc + 256;                       // 2*512*256
  float* selw   = st + (size_t)2*B_TOT*L_SEQ;      // 512*128
  int*   selidx = (int*)(selw + (size_t)B_TOT*TOPK);
  int*   cand_n = selidx + (size_t)B_TOT*TOPK;     // 512*32
  u32*   uthr   = (u32*)(cand_n + (size_t)B_TOT*NWT); // 512*32
  u64*   cand   = (u64*)(uthr + (size_t)B_TOT*NWT);
  u16*   MtH    = (u16*)(cand + (size_t)B_TOT*NWT*CSTRIDE);
  u16*   MtL    = MtH + 64*64;
  u16*   xiH    = MtL + 64*64;
  u16*   xiL    = xiH + 256*128;
  u16*   phiH   = xiL + 256*128;
  u16*   phiL   = phiH + 256*64;
  u16*   xh     = phiL + 256*64;
  u16*   xl     = xh + NX;
  u16*   yh     = xl + NX;
  u16*   yl     = yh + NX;

  // deterministic per-device check (same result every call -> graph-safe)
  hipError_t aerr = hipFuncSetAttribute((const void*)k_fused,
                      hipFuncAttributeMaxDynamicSharedMemorySize, FLDS);

  k_wprep<<<dim3(256),  dim3(256), 0, stream>>>(Wq, bq, Wk, bk, xi_w1, phi_w1,
                                                MtH, MtL, uvc, xiH, xiL, phiH, phiL);
  if (aerr == hipSuccess){
    k_fused<<<dim3(B_TOT), dim3(1024), FLDS, stream>>>(x, MtH, MtL, uvc, cand, cand_n, uthr);
  } else {
    k_pre  <<<dim3(2048), dim3(256), 0, stream>>>(x, MtH, MtL, uvc, xh, xl, yh, yl, st);
    k_score<<<dim3(4096), dim3(256), 0, stream>>>(xh, xl, yh, yl, st, cand, cand_n, uthr);
  }
  k_merge<<<dim3(B_TOT), dim3(256), 0, stream>>>(cand, cand_n, uthr, selidx, selw);
  k_mlp  <<<dim3(B_TOT), dim3(512), 0, stream>>>(x, selidx, selw,
            xiH, xiL, phiH, phiL,
            phi_b1, phi_w2, phi_b2,
            xi_b1, xi_w2, xi_b2,
            rho_w1, rho_b1, rho_w2, rho_b2, out);
}